// Round 8
// baseline (5989.445 us; speedup 1.0000x reference)
//
#include <hip/hip_runtime.h>
#include <hip/hip_bf16.h>
#include <math.h>

typedef __hip_bfloat16 bf16;
typedef __attribute__((ext_vector_type(2))) float f2v;
typedef __attribute__((ext_vector_type(8))) short bf16x8;
typedef __attribute__((ext_vector_type(4))) float f32x4;

#define NB 4
#define NS 4096
#define NE 512
#define NH 8
#define NL 4
#define NA 3
#define ND 64
#define NC 64
#define NW 64
#define NF 2048
#define NVOC 17
#define NTOK (NB * NS)   // 16384
#define WPLANE 3145728ull   // elems per split plane per layer: 4*512*512 + 2*512*2048

__device__ __forceinline__ float b2f(bf16 v) { return __bfloat162float(v); }
__device__ __forceinline__ float u2f(unsigned short u) { return __uint_as_float((unsigned)u << 16); }
__device__ __forceinline__ float ldw(const void* p, size_t i, int f32) {
  return f32 ? ((const float*)p)[i] : b2f(((const bf16*)p)[i]);
}
__device__ __forceinline__ unsigned short f2bf(float f) {   // RNE fp32->bf16
  unsigned u = __float_as_uint(f);
  return (unsigned short)((u + 0x7FFFu + ((u >> 16) & 1u)) >> 16);
}
// 3-way bf16 split: a ~= h + m + l, |a-h-m-l| <= 2^-24 |a|
__device__ __forceinline__ void split3(float a, unsigned short& h, unsigned short& m,
                                       unsigned short& l) {
  h = f2bf(a);
  float r = a - u2f(h);
  m = f2bf(r);
  float s = r - u2f(m);
  l = f2bf(s);
}

// ---------------- diagnostic fill (ws_size too small) ----------------
__global__ __launch_bounds__(256) void fill_out_kernel(float* __restrict__ out, int n, float val) {
  int i = blockIdx.x * 256 + threadIdx.x;
  if (i < n) out[i] = val;
}

// ---------------- zero fill ----------------
__global__ __launch_bounds__(256) void zero_kernel(float* __restrict__ p, int n) {
  int i = blockIdx.x * 256 + threadIdx.x;
  if (i < n) p[i] = 0.f;
}

// ---------------- embeddings + shift-right ----------------
__global__ __launch_bounds__(256) void embed_kernel(
    const int* __restrict__ value, const int* __restrict__ depth, const int* __restrict__ pos,
    const void* __restrict__ sos, const void* __restrict__ tok_emb,
    const void* __restrict__ depth_emb, const void* __restrict__ pos_emb,
    float* __restrict__ x, int f32) {
  int i = blockIdx.x * 256 + threadIdx.x;
  if (i >= NTOK * NE) return;
  int e = i & (NE - 1);
  int bs = i >> 9;
  int s = bs & (NS - 1);
  int b = bs >> 12;
  float v;
  if (s == 0) {
    v = ldw(sos, e, f32);
  } else {
    int src = b * NS + (s - 1);
    float acc = ldw(tok_emb, (size_t)value[src] * NE + e, f32)
              + ldw(depth_emb, (size_t)depth[src] * NE + e, f32);
#pragma unroll
    for (int a = 0; a < NA; a++)
      acc += ldw(pos_emb, ((size_t)a * 65 + pos[src * NA + a]) * NE + e, f32);
    v = acc;
  }
  x[i] = v;
}

// ---------------- layer norm, one wave per row ----------------
__global__ __launch_bounds__(256) void ln_kernel(
    const float* __restrict__ x, const void* __restrict__ gam, const void* __restrict__ bet,
    size_t off, float* __restrict__ out, int f32) {
  int row = blockIdx.x * 4 + (threadIdx.x >> 6);
  int lane = threadIdx.x & 63;
  const float* xr = x + (size_t)row * NE;
  float v[8];
#pragma unroll
  for (int i = 0; i < 8; i++) v[i] = xr[lane + i * 64];
  float s = 0.f;
#pragma unroll
  for (int i = 0; i < 8; i++) s += v[i];
#pragma unroll
  for (int o = 32; o; o >>= 1) s += __shfl_xor(s, o);
  float m = s * (1.0f / NE);
  float sq = 0.f;
#pragma unroll
  for (int i = 0; i < 8; i++) { float d = v[i] - m; sq += d * d; }
#pragma unroll
  for (int o = 32; o; o >>= 1) sq += __shfl_xor(sq, o);
  float rs = 1.0f / sqrtf(sq * (1.0f / NE) + 1e-5f);
  float* orow = out + (size_t)row * NE;
#pragma unroll
  for (int i = 0; i < 8; i++) {
    int e = lane + i * 64;
    orow[e] = (v[i] - m) * rs * ldw(gam, off + e, f32) + ldw(bet, off + e, f32);
  }
}

// ---------------- fp32 vector GEMM core (bf16-input fallback path) ----------------
template <int ACT>
__device__ __forceinline__ void gemm_body(
    const float* __restrict__ A, const void* __restrict__ Bw, size_t bwoff, int ldb,
    const void* bias, size_t biasoff, const float* resid, float* C,
    int N, int K, int f32, int bm, int bn) {
  __shared__ float As[32][132];
  __shared__ float Bs[32][132];
  int tid = threadIdx.x;
  int ty = tid >> 4, tx = tid & 15;
  f2v acc2[8][4];
#pragma unroll
  for (int i = 0; i < 8; i++)
#pragma unroll
    for (int j = 0; j < 4; j++) acc2[i][j] = (f2v){0.f, 0.f};
  int arow = tid >> 1;
  int acol = (tid & 1) << 4;
  int brow = tid >> 3;
  int bcol = (tid & 7) << 4;

  const float* Aptr = A + (size_t)(bm + arow) * K + acol;
  float4 pa[4];
  float4 pb[4];
  uint4 pbu[2];
#pragma unroll
  for (int j = 0; j < 4; j++) pa[j] = *(const float4*)(Aptr + 4 * j);
  {
    size_t boff = bwoff + (size_t)brow * ldb + bn + bcol;
    if (f32) {
#pragma unroll
      for (int j = 0; j < 4; j++) pb[j] = *(const float4*)((const float*)Bw + boff + 4 * j);
    } else {
      pbu[0] = *(const uint4*)((const bf16*)Bw + boff);
      pbu[1] = *(const uint4*)((const bf16*)Bw + boff + 8);
    }
  }

  for (int k0 = 0; k0 < K; k0 += 32) {
#pragma unroll
    for (int j = 0; j < 4; j++) {
      As[acol + 4 * j + 0][arow] = pa[j].x;
      As[acol + 4 * j + 1][arow] = pa[j].y;
      As[acol + 4 * j + 2][arow] = pa[j].z;
      As[acol + 4 * j + 3][arow] = pa[j].w;
    }
    if (f32) {
#pragma unroll
      for (int j = 0; j < 4; j++) {
        Bs[brow][bcol + 4 * j + 0] = pb[j].x;
        Bs[brow][bcol + 4 * j + 1] = pb[j].y;
        Bs[brow][bcol + 4 * j + 2] = pb[j].z;
        Bs[brow][bcol + 4 * j + 3] = pb[j].w;
      }
    } else {
      union { uint4 u; unsigned short s[8]; } r0, r1;
      r0.u = pbu[0]; r1.u = pbu[1];
#pragma unroll
      for (int j = 0; j < 8; j++) Bs[brow][bcol + j] = u2f(r0.s[j]);
#pragma unroll
      for (int j = 0; j < 8; j++) Bs[brow][bcol + 8 + j] = u2f(r1.s[j]);
    }
    __syncthreads();
    if (k0 + 32 < K) {
#pragma unroll
      for (int j = 0; j < 4; j++) pa[j] = *(const float4*)(Aptr + k0 + 32 + 4 * j);
      size_t boff = bwoff + (size_t)(k0 + 32 + brow) * ldb + bn + bcol;
      if (f32) {
#pragma unroll
        for (int j = 0; j < 4; j++) pb[j] = *(const float4*)((const float*)Bw + boff + 4 * j);
      } else {
        pbu[0] = *(const uint4*)((const bf16*)Bw + boff);
        pbu[1] = *(const uint4*)((const bf16*)Bw + boff + 8);
      }
    }
#pragma unroll
    for (int kk = 0; kk < 32; kk++) {
      float4 aA = *(const float4*)&As[kk][ty << 3];
      float4 aB = *(const float4*)&As[kk][(ty << 3) + 4];
      float4 bA = *(const float4*)&Bs[kk][tx << 2];
      float4 bB = *(const float4*)&Bs[kk][64 + (tx << 2)];
      float av[8] = {aA.x, aA.y, aA.z, aA.w, aB.x, aB.y, aB.z, aB.w};
      f2v bv[4];
      bv[0] = (f2v){bA.x, bA.y};
      bv[1] = (f2v){bA.z, bA.w};
      bv[2] = (f2v){bB.x, bB.y};
      bv[3] = (f2v){bB.z, bB.w};
#pragma unroll
      for (int i = 0; i < 8; i++)
#pragma unroll
        for (int j = 0; j < 4; j++)
          acc2[i][j] += bv[j] * av[i];
    }
    __syncthreads();
  }
#pragma unroll
  for (int i = 0; i < 8; i++) {
    int row = bm + (ty << 3) + i;
    int c0 = bn + (tx << 2);
    int c1 = bn + 64 + (tx << 2);
    const float* ap = (const float*)&acc2[i][0];
    float o0[4], o1[4];
#pragma unroll
    for (int j = 0; j < 4; j++) { o0[j] = ap[j]; o1[j] = ap[4 + j]; }
    if (bias) {
#pragma unroll
      for (int j = 0; j < 4; j++) {
        o0[j] += ldw(bias, biasoff + c0 + j, f32);
        o1[j] += ldw(bias, biasoff + c1 + j, f32);
      }
    }
    if (ACT == 1) {
#pragma unroll
      for (int j = 0; j < 4; j++) {
        float t0 = 0.7978845608028654f * (o0[j] + 0.044715f * o0[j] * o0[j] * o0[j]);
        o0[j] = 0.5f * o0[j] * (1.0f + tanhf(t0));
        float t1 = 0.7978845608028654f * (o1[j] + 0.044715f * o1[j] * o1[j] * o1[j]);
        o1[j] = 0.5f * o1[j] * (1.0f + tanhf(t1));
      }
    }
    size_t p0 = (size_t)row * N + c0;
    size_t p1 = (size_t)row * N + c1;
    if (resid) {
      float4 r0 = *(const float4*)(resid + p0);
      float4 r1 = *(const float4*)(resid + p1);
      o0[0] += r0.x; o0[1] += r0.y; o0[2] += r0.z; o0[3] += r0.w;
      o1[0] += r1.x; o1[1] += r1.y; o1[2] += r1.z; o1[3] += r1.w;
    }
    *(float4*)(C + p0) = make_float4(o0[0], o0[1], o0[2], o0[3]);
    *(float4*)(C + p1) = make_float4(o1[0], o1[1], o1[2], o1[3]);
  }
}

template <int ACT>
__global__ __launch_bounds__(256) void gemm_kernel(
    const float* __restrict__ A, const void* __restrict__ Bw, size_t bwoff, int ldb,
    const void* bias, size_t biasoff, const float* resid, float* C,
    int N, int K, int f32) {
  gemm_body<ACT>(A, Bw, bwoff, ldb, bias, biasoff, resid, C, N, K,
                 f32, blockIdx.y << 7, blockIdx.x << 7);
}

__global__ __launch_bounds__(256) void gemm_qkv_kernel(
    const float* __restrict__ A,
    const void* __restrict__ Wq, const void* __restrict__ Wk, const void* __restrict__ Wv,
    size_t bwoff, float* __restrict__ Cq, float* __restrict__ Ck, float* __restrict__ Cv,
    int f32) {
  int sel = blockIdx.x >> 2;
  const void* Bw = (sel == 0) ? Wq : ((sel == 1) ? Wk : Wv);
  float* C = (sel == 0) ? Cq : ((sel == 1) ? Ck : Cv);
  gemm_body<0>(A, Bw, bwoff, NE, nullptr, 0, nullptr, C, NE, NE,
               f32, blockIdx.y << 7, (blockIdx.x & 3) << 7);
}

// ---------------- weight pre-split: fp32 [K][N] -> 3 bf16 planes, transposed [N][K] ----------------
// Per layer. Plane layout (elems, k-contig rows): [0,1M) qkvo w*262144 + n*512 + k;
// [1M,2M) W1T 1048576 + n*512 + k (n<2048); [2M,3M) W2T 2097152 + n*2048 + k (n<512).
// Planes at ws + p*WPLANE. Values identical to in-kernel split3 -> bit-identical GEMMs.
__global__ __launch_bounds__(256) void wsplit_kernel(
    const float* __restrict__ Wq, const float* __restrict__ Wk, const float* __restrict__ Wv,
    const float* __restrict__ Wo, const float* __restrict__ W1, const float* __restrict__ W2,
    size_t lo_qkvo, size_t lo_ffn, unsigned short* __restrict__ ws) {
  __shared__ unsigned short th[64][66], tm[64][66], tl[64][66];
  int tt = blockIdx.x;               // 768 tiles of 64x64
  const float* src;
  int ldn, k0, n0, ldk;
  size_t dbase;
  if (tt < 256) {
    int w = tt >> 6, ti = tt & 63;
    src = ((w == 0) ? Wq : (w == 1) ? Wk : (w == 2) ? Wv : Wo) + lo_qkvo;
    ldn = 512; k0 = (ti >> 3) * 64; n0 = (ti & 7) * 64;
    dbase = (size_t)w * 262144u; ldk = 512;
  } else if (tt < 512) {
    int ti = tt - 256;
    src = W1 + lo_ffn;
    ldn = 2048; k0 = (ti >> 5) * 64; n0 = (ti & 31) * 64;
    dbase = 1048576u; ldk = 512;
  } else {
    int ti = tt - 512;
    src = W2 + lo_ffn;
    ldn = 512; k0 = (ti >> 3) * 64; n0 = (ti & 7) * 64;
    dbase = 2097152u; ldk = 2048;
  }
  int t = threadIdx.x;
#pragma unroll
  for (int j = 0; j < 16; j++) {
    int idx = t + j * 256;
    int r = idx >> 6, c = idx & 63;
    float a = src[(size_t)(k0 + r) * ldn + n0 + c];
    unsigned short h, m, l;
    split3(a, h, m, l);
    th[r][c] = h; tm[r][c] = m; tl[r][c] = l;
  }
  __syncthreads();
#pragma unroll
  for (int j = 0; j < 16; j++) {
    int idx = t + j * 256;
    int c2 = idx >> 6, r2 = idx & 63;
    size_t d = dbase + (size_t)(n0 + c2) * ldk + k0 + r2;
    ws[d] = th[r2][c2];
    ws[WPLANE + d] = tm[r2][c2];
    ws[2 * WPLANE + d] = tl[r2][c2];
  }
}

// ---------------- MFMA GEMM, pre-split B planes ([N][K] bf16, row stride ldbt) ----------------
// A fp32 split in-kernel (3 planes); B loaded pre-split: no split3, no transpose-scatter.
template <int ACT>
__device__ __forceinline__ void mfma_ps_body(
    const float* __restrict__ A, const unsigned short* __restrict__ Bt, int ldbt,
    const float* __restrict__ bias, const float* __restrict__ resid, float* __restrict__ C,
    int N, int K, int bm, int bn) {
  __shared__ unsigned short Ah[128][40];
  __shared__ unsigned short Am[128][40];
  __shared__ unsigned short Al[128][40];
  __shared__ unsigned short Bh[128][40];
  __shared__ unsigned short Bm[128][40];
  __shared__ unsigned short Bl[128][40];
  int t = threadIdx.x;
  int arow = t >> 1;
  int akc = (t & 1) << 4;
  const float* Ap = A + (size_t)(bm + arow) * K + akc;
  const unsigned short* Bp = Bt + (size_t)(bn + arow) * ldbt + akc;

  float4 pa[4];
  uint4 pbh[2], pbm[2], pbl[2];
#pragma unroll
  for (int j = 0; j < 4; j++) pa[j] = *(const float4*)(Ap + 4 * j);
  pbh[0] = *(const uint4*)(Bp);
  pbh[1] = *(const uint4*)(Bp + 8);
  pbm[0] = *(const uint4*)(Bp + WPLANE);
  pbm[1] = *(const uint4*)(Bp + WPLANE + 8);
  pbl[0] = *(const uint4*)(Bp + 2 * WPLANE);
  pbl[1] = *(const uint4*)(Bp + 2 * WPLANE + 8);

  int lane = t & 63;
  int wid = t >> 6;
  int wr = wid >> 1, wc = wid & 1;
  int lr = lane & 15, lg = lane >> 4;

  f32x4 acc[4][4];
#pragma unroll
  for (int i = 0; i < 4; i++)
#pragma unroll
    for (int j = 0; j < 4; j++) acc[i][j] = (f32x4){0.f, 0.f, 0.f, 0.f};

  for (int k0 = 0; k0 < K; k0 += 32) {
    {
      unsigned hs[8], ms[8], ls[8];
#pragma unroll
      for (int j = 0; j < 4; j++) {
        const float* pf = (const float*)&pa[j];
#pragma unroll
        for (int e = 0; e < 2; e++) {
          unsigned short h0, m0, l0, h1, m1, l1;
          split3(pf[2 * e], h0, m0, l0);
          split3(pf[2 * e + 1], h1, m1, l1);
          hs[2 * j + e] = (unsigned)h0 | ((unsigned)h1 << 16);
          ms[2 * j + e] = (unsigned)m0 | ((unsigned)m1 << 16);
          ls[2 * j + e] = (unsigned)l0 | ((unsigned)l1 << 16);
        }
      }
      *(uint4*)&Ah[arow][akc]     = make_uint4(hs[0], hs[1], hs[2], hs[3]);
      *(uint4*)&Ah[arow][akc + 8] = make_uint4(hs[4], hs[5], hs[6], hs[7]);
      *(uint4*)&Am[arow][akc]     = make_uint4(ms[0], ms[1], ms[2], ms[3]);
      *(uint4*)&Am[arow][akc + 8] = make_uint4(ms[4], ms[5], ms[6], ms[7]);
      *(uint4*)&Al[arow][akc]     = make_uint4(ls[0], ls[1], ls[2], ls[3]);
      *(uint4*)&Al[arow][akc + 8] = make_uint4(ls[4], ls[5], ls[6], ls[7]);
    }
    *(uint4*)&Bh[arow][akc]     = pbh[0];
    *(uint4*)&Bh[arow][akc + 8] = pbh[1];
    *(uint4*)&Bm[arow][akc]     = pbm[0];
    *(uint4*)&Bm[arow][akc + 8] = pbm[1];
    *(uint4*)&Bl[arow][akc]     = pbl[0];
    *(uint4*)&Bl[arow][akc + 8] = pbl[1];
    __syncthreads();
    if (k0 + 32 < K) {
#pragma unroll
      for (int j = 0; j < 4; j++) pa[j] = *(const float4*)(Ap + k0 + 32 + 4 * j);
      const unsigned short* Bn = Bp + k0 + 32;
      pbh[0] = *(const uint4*)(Bn);
      pbh[1] = *(const uint4*)(Bn + 8);
      pbm[0] = *(const uint4*)(Bn + WPLANE);
      pbm[1] = *(const uint4*)(Bn + WPLANE + 8);
      pbl[0] = *(const uint4*)(Bn + 2 * WPLANE);
      pbl[1] = *(const uint4*)(Bn + 2 * WPLANE + 8);
    }
    bf16x8 fbh[4], fbm[4], fbl[4];
#pragma unroll
    for (int ni = 0; ni < 4; ni++) {
      int rb = wc * 64 + ni * 16 + lr;
      fbh[ni] = *(const bf16x8*)&Bh[rb][lg * 8];
      fbm[ni] = *(const bf16x8*)&Bm[rb][lg * 8];
      fbl[ni] = *(const bf16x8*)&Bl[rb][lg * 8];
    }
#pragma unroll
    for (int mi = 0; mi < 4; mi++) {
      int ar = wr * 64 + mi * 16 + lr;
      bf16x8 fh = *(const bf16x8*)&Ah[ar][lg * 8];
      bf16x8 fm = *(const bf16x8*)&Am[ar][lg * 8];
      bf16x8 fl = *(const bf16x8*)&Al[ar][lg * 8];
#pragma unroll
      for (int ni = 0; ni < 4; ni++) {
        f32x4 a = acc[mi][ni];
        a = __builtin_amdgcn_mfma_f32_16x16x32_bf16(fh, fbh[ni], a, 0, 0, 0);
        a = __builtin_amdgcn_mfma_f32_16x16x32_bf16(fh, fbm[ni], a, 0, 0, 0);
        a = __builtin_amdgcn_mfma_f32_16x16x32_bf16(fm, fbh[ni], a, 0, 0, 0);
        a = __builtin_amdgcn_mfma_f32_16x16x32_bf16(fm, fbm[ni], a, 0, 0, 0);
        a = __builtin_amdgcn_mfma_f32_16x16x32_bf16(fh, fbl[ni], a, 0, 0, 0);
        a = __builtin_amdgcn_mfma_f32_16x16x32_bf16(fl, fbh[ni], a, 0, 0, 0);
        acc[mi][ni] = a;
      }
    }
    __syncthreads();
  }
#pragma unroll
  for (int mi = 0; mi < 4; mi++) {
#pragma unroll
    for (int ni = 0; ni < 4; ni++) {
      int col = bn + wc * 64 + ni * 16 + lr;
      int rbase = bm + wr * 64 + mi * 16 + lg * 4;
      float bv = bias ? bias[col] : 0.f;
      const float* av = (const float*)&acc[mi][ni];
#pragma unroll
      for (int r = 0; r < 4; r++) {
        float o = av[r] + bv;
        if (ACT == 1) {
          float t0 = 0.7978845608028654f * (o + 0.044715f * o * o * o);
          o = 0.5f * o * (1.0f + tanhf(t0));
        }
        size_t p = (size_t)(rbase + r) * N + col;
        if (resid) o += resid[p];
        C[p] = o;
      }
    }
  }
}

template <int ACT>
__global__ __launch_bounds__(256) void gemm_mfma_ps_kernel(
    const float* __restrict__ A, const unsigned short* __restrict__ Bt, int ldbt,
    const float* __restrict__ bias, const float* __restrict__ resid, float* __restrict__ C,
    int N, int K) {
  mfma_ps_body<ACT>(A, Bt, ldbt, bias, resid, C, N, K, blockIdx.y << 7, blockIdx.x << 7);
}

__global__ __launch_bounds__(256) void gemm_qkv_mfma_ps(
    const float* __restrict__ A, const unsigned short* __restrict__ ws,
    float* __restrict__ Cq, float* __restrict__ Ck, float* __restrict__ Cv) {
  int sel = blockIdx.x >> 2;
  const unsigned short* Bt = ws + (size_t)sel * 262144u;
  float* C = (sel == 0) ? Cq : ((sel == 1) ? Ck : Cv);
  mfma_ps_body<0>(A, Bt, 512, nullptr, nullptr, C, NE, NE,
                  blockIdx.y << 7, (blockIdx.x & 3) << 7);
}

// ---------------- MFMA GEMM, in-kernel split (fallback when ws too small) ----------------
template <int ACT>
__device__ __forceinline__ void mfma_body(
    const float* __restrict__ A, const float* __restrict__ Bw, int ldb,
    const float* __restrict__ bias, const float* __restrict__ resid, float* __restrict__ C,
    int N, int K, int bm, int bn) {
  __shared__ unsigned short Ah[128][40];
  __shared__ unsigned short Am[128][40];
  __shared__ unsigned short Al[128][40];
  __shared__ unsigned short Bh[128][40];
  __shared__ unsigned short Bm[128][40];
  __shared__ unsigned short Bl[128][40];
  int t = threadIdx.x;
  int arow = t >> 1;
  int akc = (t & 1) << 4;
  const float* Ap = A + (size_t)(bm + arow) * K + akc;
  int bkr = t >> 3;
  int bcg = t & 7;
  const float* Bp = Bw + (size_t)bkr * ldb + bn + bcg * 16;
  int bkpos = bkr ^ ((bcg & 3) << 3);

  float4 pa[4], pb[4];
#pragma unroll
  for (int j = 0; j < 4; j++) pa[j] = *(const float4*)(Ap + 4 * j);
#pragma unroll
  for (int j = 0; j < 4; j++) pb[j] = *(const float4*)(Bp + 4 * j);

  int lane = t & 63;
  int wid = t >> 6;
  int wr = wid >> 1, wc = wid & 1;
  int lr = lane & 15, lg = lane >> 4;

  f32x4 acc[4][4];
#pragma unroll
  for (int i = 0; i < 4; i++)
#pragma unroll
    for (int j = 0; j < 4; j++) acc[i][j] = (f32x4){0.f, 0.f, 0.f, 0.f};

  for (int k0 = 0; k0 < K; k0 += 32) {
    {
      unsigned hs[8], ms[8], ls[8];
#pragma unroll
      for (int j = 0; j < 4; j++) {
        const float* pf = (const float*)&pa[j];
#pragma unroll
        for (int e = 0; e < 2; e++) {
          unsigned short h0, m0, l0, h1, m1, l1;
          split3(pf[2 * e], h0, m0, l0);
          split3(pf[2 * e + 1], h1, m1, l1);
          hs[2 * j + e] = (unsigned)h0 | ((unsigned)h1 << 16);
          ms[2 * j + e] = (unsigned)m0 | ((unsigned)m1 << 16);
          ls[2 * j + e] = (unsigned)l0 | ((unsigned)l1 << 16);
        }
      }
      *(uint4*)&Ah[arow][akc]     = make_uint4(hs[0], hs[1], hs[2], hs[3]);
      *(uint4*)&Ah[arow][akc + 8] = make_uint4(hs[4], hs[5], hs[6], hs[7]);
      *(uint4*)&Am[arow][akc]     = make_uint4(ms[0], ms[1], ms[2], ms[3]);
      *(uint4*)&Am[arow][akc + 8] = make_uint4(ms[4], ms[5], ms[6], ms[7]);
      *(uint4*)&Al[arow][akc]     = make_uint4(ls[0], ls[1], ls[2], ls[3]);
      *(uint4*)&Al[arow][akc + 8] = make_uint4(ls[4], ls[5], ls[6], ls[7]);
    }
    {
#pragma unroll
      for (int j = 0; j < 4; j++) {
        const float* pf = (const float*)&pb[j];
#pragma unroll
        for (int e = 0; e < 4; e++) {
          unsigned short h, m, l;
          split3(pf[e], h, m, l);
          int nn = bcg * 16 + 4 * j + e;
          Bh[nn][bkpos] = h;
          Bm[nn][bkpos] = m;
          Bl[nn][bkpos] = l;
        }
      }
    }
    __syncthreads();
    if (k0 + 32 < K) {
#pragma unroll
      for (int j = 0; j < 4; j++) pa[j] = *(const float4*)(Ap + k0 + 32 + 4 * j);
      const float* Bn = Bp + (size_t)(k0 + 32) * ldb;
#pragma unroll
      for (int j = 0; j < 4; j++) pb[j] = *(const float4*)(Bn + 4 * j);
    }
    bf16x8 fbh[4], fbm[4], fbl[4];
#pragma unroll
    for (int ni = 0; ni < 4; ni++) {
      int rb = wc * 64 + ni * 16 + lr;
      int cb = ((lg ^ ni) & 3) * 8;
      fbh[ni] = *(const bf16x8*)&Bh[rb][cb];
      fbm[ni] = *(const bf16x8*)&Bm[rb][cb];
      fbl[ni] = *(const bf16x8*)&Bl[rb][cb];
    }
#pragma unroll
    for (int mi = 0; mi < 4; mi++) {
      int ar = wr * 64 + mi * 16 + lr;
      bf16x8 fh = *(const bf16x8*)&Ah[ar][lg * 8];
      bf16x8 fm = *(const bf16x8*)&Am[ar][lg * 8];
      bf16x8 fl = *(const bf16x8*)&Al[ar][lg * 8];
#pragma unroll
      for (int ni = 0; ni < 4; ni++) {
        f32x4 a = acc[mi][ni];
        a = __builtin_amdgcn_mfma_f32_16x16x32_bf16(fh, fbh[ni], a, 0, 0, 0);
        a = __builtin_amdgcn_mfma_f32_16x16x32_bf16(fh, fbm[ni], a, 0, 0, 0);
        a = __builtin_amdgcn_mfma_f32_16x16x32_bf16(fm, fbh[ni], a, 0, 0, 0);
        a = __builtin_amdgcn_mfma_f32_16x16x32_bf16(fm, fbm[ni], a, 0, 0, 0);
        a = __builtin_amdgcn_mfma_f32_16x16x32_bf16(fh, fbl[ni], a, 0, 0, 0);
        a = __builtin_amdgcn_mfma_f32_16x16x32_bf16(fl, fbh[ni], a, 0, 0, 0);
        acc[mi][ni] = a;
      }
    }
    __syncthreads();
  }
#pragma unroll
  for (int mi = 0; mi < 4; mi++) {
#pragma unroll
    for (int ni = 0; ni < 4; ni++) {
      int col = bn + wc * 64 + ni * 16 + lr;
      int rbase = bm + wr * 64 + mi * 16 + lg * 4;
      float bv = bias ? bias[col] : 0.f;
      const float* av = (const float*)&acc[mi][ni];
#pragma unroll
      for (int r = 0; r < 4; r++) {
        float o = av[r] + bv;
        if (ACT == 1) {
          float t0 = 0.7978845608028654f * (o + 0.044715f * o * o * o);
          o = 0.5f * o * (1.0f + tanhf(t0));
        }
        size_t p = (size_t)(rbase + r) * N + col;
        if (resid) o += resid[p];
        C[p] = o;
      }
    }
  }
}

template <int ACT>
__global__ __launch_bounds__(256) void gemm_mfma_kernel(
    const float* __restrict__ A, const float* __restrict__ Bw, int ldb,
    const float* __restrict__ bias, const float* __restrict__ resid, float* __restrict__ C,
    int N, int K) {
  mfma_body<ACT>(A, Bw, ldb, bias, resid, C, N, K, blockIdx.y << 7, blockIdx.x << 7);
}

__global__ __launch_bounds__(256) void gemm_qkv_mfma(
    const float* __restrict__ A, const float* __restrict__ Wq, const float* __restrict__ Wk,
    const float* __restrict__ Wv, size_t off,
    float* __restrict__ Cq, float* __restrict__ Ck, float* __restrict__ Cv) {
  int sel = blockIdx.x >> 2;
  const float* Bw = (sel == 0) ? Wq : ((sel == 1) ? Wk : Wv);
  float* C = (sel == 0) ? Cq : ((sel == 1) ? Ck : Cv);
  mfma_body<0>(A, Bw + off, NE, nullptr, nullptr, C, NE, NE,
               blockIdx.y << 7, (blockIdx.x & 3) << 7);
}

// ---------------- q transpose: qT[b][h][d][n] <- q[b*NS+n][h*ND+d] ----------------
__global__ __launch_bounds__(256) void qt_kernel(const float* __restrict__ q, float* __restrict__ qT) {
  __shared__ float tile[64][65];
  int bid = blockIdx.x;
  int st = bid & 63;
  int bh = bid >> 6;
  int b = bh >> 3, h = bh & 7;
  int s0 = st * 64;
  int t = threadIdx.x;
#pragma unroll
  for (int k = 0; k < 16; k++) {
    int idx = t + k * 256;
    int sl = idx >> 6, dl = idx & 63;
    tile[sl][dl] = q[(size_t)(b * NS + s0 + sl) * NE + h * ND + dl];
  }
  __syncthreads();
#pragma unroll
  for (int k = 0; k < 16; k++) {
    int idx = t + k * 256;
    int dl = idx >> 6, sl = idx & 63;
    qT[((size_t)bh * 64 + dl) * NS + s0 + sl] = tile[sl][dl];
  }
}

// ---------------- normalized means in fp64 ----------------
__global__ __launch_bounds__(64) void mnd_kernel(const void* __restrict__ means,
                                                 double* __restrict__ mnd, int f32) {
  __shared__ double s[64];
  int vblk = blockIdx.x;
  int d = threadIdx.x;
  double m = (double)ldw(means, (size_t)vblk * ND + d, f32);
  s[d] = m * m;
  __syncthreads();
  for (int st = 32; st; st >>= 1) { if (d < st) s[d] += s[d + st]; __syncthreads(); }
  mnd[(size_t)vblk * ND + d] = m / (sqrt(s[0]) + 1e-8);
}

// ---------------- per-(token,head) 1/(||q||+1e-8), stored transposed [b][h][n] ----------------
__global__ __launch_bounds__(64) void rq_kernel(const float* __restrict__ q, double* __restrict__ rqd) {
  int bid = blockIdx.x;
  int tok = bid >> 3, h = bid & 7;
  int b = tok >> 12, s = tok & (NS - 1);
  int d = threadIdx.x;
  double v = (double)q[(size_t)tok * NE + h * ND + d];
  double ss = v * v;
#pragma unroll
  for (int o = 32; o; o >>= 1) ss += __shfl_xor(ss, o);
  if (d == 0) rqd[((size_t)(b * NH + h) << 12) | s] = 1.0 / (sqrt(ss) + 1e-8);
}

// ---------------- routing: fp64 dists (coalesced qT, 4-chain) + exact top-64 radix select ----------------
__global__ __launch_bounds__(256) void route_kernel(
    const float* __restrict__ qT, const double* __restrict__ mnd,
    const double* __restrict__ rqd, int* __restrict__ idxout) {
  __shared__ unsigned long long keys[NS];
  __shared__ double mc[ND];
  __shared__ unsigned hist[256];
  __shared__ unsigned short cand[2][NS];
  __shared__ unsigned s_rem, s_cnt, s_sel, s_cc[2];
  int bid = blockIdx.x;
  int h = bid & 7;
  int b = (bid >> 3) & 3;
  int c = bid >> 5;
  int bhc = ((b * NH + h) * NC) + c;
  int t = threadIdx.x;
  if (t < ND) mc[t] = mnd[((size_t)h * NC + c) * ND + t];
  hist[t] = 0u;
  if (t == 0) { s_rem = NW; s_cnt = 0u; s_cc[0] = 0u; s_cc[1] = 0u; }
  __syncthreads();
  const float* qTb = qT + (size_t)(b * NH + h) * 64 * NS;
  const double* rqb = rqd + ((size_t)(b * NH + h) << 12);
  for (int i = 0; i < 16; i += 4) {
    int n0 = t + i * 256, n1 = n0 + 256, n2 = n0 + 512, n3 = n0 + 768;
    double a0 = 0.0, a1 = 0.0, a2 = 0.0, a3 = 0.0;
#pragma unroll 8
    for (int d = 0; d < 64; d++) {
      const float* row = qTb + (size_t)d * NS;
      double m = mc[d];
      a0 += (double)row[n0] * m;
      a1 += (double)row[n1] * m;
      a2 += (double)row[n2] * m;
      a3 += (double)row[n3] * m;
    }
    double dv[4] = {a0 * rqb[n0], a1 * rqb[n1], a2 * rqb[n2], a3 * rqb[n3]};
    int nn[4] = {n0, n1, n2, n3};
#pragma unroll
    for (int j = 0; j < 4; j++) {
      long long sb = __double_as_longlong(dv[j]);
      unsigned long long u = (unsigned long long)sb;
      u = (sb < 0) ? ~u : (u | 0x8000000000000000ULL);
      keys[nn[j]] = (u & 0xFFFFFFFFFFFFF000ULL) | (unsigned long long)(NS - 1 - nn[j]);
    }
  }
  __syncthreads();
  {
    unsigned lastd = 0xFFFFFFFFu, lcnt = 0u;
    for (int n = t; n < NS; n += 256) {
      unsigned d = (unsigned)(keys[n] >> 56);
      if (d == lastd) { lcnt++; }
      else { if (lcnt) atomicAdd(&hist[lastd], lcnt); lastd = d; lcnt = 1u; }
    }
    if (lcnt) atomicAdd(&hist[lastd], lcnt);
  }
  __syncthreads();
  if (t < 64) {
    unsigned h0 = hist[4 * t + 0], h1 = hist[4 * t + 1];
    unsigned h2 = hist[4 * t + 2], h3 = hist[4 * t + 3];
    hist[4 * t + 0] = 0u; hist[4 * t + 1] = 0u; hist[4 * t + 2] = 0u; hist[4 * t + 3] = 0u;
    unsigned t3 = h3, t2 = h2 + h3, t1 = h1 + t2, t0 = h0 + t1;
    unsigned s = t0;
#pragma unroll
    for (int off = 1; off < 64; off <<= 1) {
      unsigned v = __shfl_down(s, off);
      if (t + off < 64) s += v;
    }
    unsigned E = s - t0;
    unsigned rem = s_rem;
    unsigned sf0 = t0 + E, sf1 = t1 + E, sf2 = t2 + E, sf3 = t3 + E, sf4 = E;
    if (sf0 >= rem && sf1 < rem) { s_sel = 4u * t + 0u; s_rem = rem - sf1; }
    if (sf1 >= rem && sf2 < rem) { s_sel = 4u * t + 1u; s_rem = rem - sf2; }
    if (sf2 >= rem && sf3 < rem) { s_sel = 4u * t + 2u; s_rem = rem - sf3; }
    if (sf3 >= rem && sf4 < rem) { s_sel = 4u * t + 3u; s_rem = rem - sf4; }
  }
  __syncthreads();
  {
    unsigned sel = s_sel;
    for (int n = t; n < NS; n += 256) {
      unsigned d = (unsigned)(keys[n] >> 56);
      if (d > sel) {
        unsigned p = atomicAdd(&s_cnt, 1u);
        idxout[(size_t)bhc * NW + p] = n;
      } else if (d == sel) {
        unsigned p = atomicAdd(&s_cc[0], 1u);
        cand[0][p] = (unsigned short)n;
      }
    }
  }
  __syncthreads();
  int cur = 0;
  for (int p = 6; p >= 0; p--) {
    int sh = p * 8;
    unsigned nc = s_cc[cur];
    for (unsigned i = t; i < nc; i += 256) {
      unsigned d = (unsigned)((keys[cand[cur][i]] >> sh) & 255ULL);
      atomicAdd(&hist[d], 1u);
    }
    __syncthreads();
    if (t < 64) {
      unsigned h0 = hist[4 * t + 0], h1 = hist[4 * t + 1];
      unsigned h2 = hist[4 * t + 2], h3 = hist[4 * t + 3];
      hist[4 * t + 0] = 0u; hist[4 * t + 1] = 0u; hist[4 * t + 2] = 0u; hist[4 * t + 3] = 0u;
      unsigned t3 = h3, t2 = h2 + h3, t1 = h1 + t2, t0 = h0 + t1;
      unsigned s = t0;
#pragma unroll
      for (int off = 1; off < 64; off <<= 1) {
        unsigned v = __shfl_down(s, off);
        if (t + off < 64) s += v;
      }
      unsigned E = s - t0;
      unsigned rem = s_rem;
      unsigned sf0 = t0 + E, sf1 = t1 + E, sf2 = t2 + E, sf3 = t3 + E, sf4 = E;
      if (sf0 >= rem && sf1 < rem) { s_sel = 4u * t + 0u; s_rem = rem - sf1; }
      if (sf1 >= rem && sf2 < rem) { s_sel = 4u * t + 1u; s_rem = rem - sf2; }
      if (sf2 >= rem && sf3 < rem) { s_sel = 4u * t + 2u; s_rem = rem - sf3; }
      if (sf3 >= rem && sf4 < rem) { s_sel = 4u * t + 3u; s_rem = rem - sf4; }
      if (t == 0) s_cc[cur ^ 1] = 0u;
    }
    __syncthreads();
    unsigned sel = s_sel;
    if (p == 0) {
      for (unsigned i = t; i < nc; i += 256) {
        unsigned n = cand[cur][i];
        unsigned d = (unsigned)(keys[n] & 255ULL);
        if (d >= sel) {
          unsigned pp = atomicAdd(&s_cnt, 1u);
          idxout[(size_t)bhc * NW + pp] = n;
        }
      }
    } else {
      int nxt = cur ^ 1;
      for (unsigned i = t; i < nc; i += 256) {
        unsigned n = cand[cur][i];
        unsigned d = (unsigned)((keys[n] >> sh) & 255ULL);
        if (d > sel) {
          unsigned pp = atomicAdd(&s_cnt, 1u);
          idxout[(size_t)bhc * NW + pp] = n;
        } else if (d == sel) {
          unsigned pp = atomicAdd(&s_cc[nxt], 1u);
          cand[nxt][pp] = (unsigned short)n;
        }
      }
      __syncthreads();
      cur = nxt;
    }
  }
}

// ---------------- per-(token,head) selection count ----------------
__global__ __launch_bounds__(256) void cnt_kernel(const int* __restrict__ idxb, float* __restrict__ cnt) {
  int i = blockIdx.x * 256 + threadIdx.x;
  int bhc = i >> 6;
  int h = (bhc >> 6) & (NH - 1);
  int b = bhc >> 9;
  atomicAdd(&cnt[(size_t)(b * NS + idxb[i]) * NH + h], 1.0f);
}

// ---------------- bucket attention ----------------
__global__ __launch_bounds__(256) void attn_kernel(
    const float* __restrict__ q, const float* __restrict__ k, const float* __restrict__ v,
    const int* __restrict__ idxb, const int* __restrict__ value, const float* __restrict__ cnt,
    float* __restrict__ obuf) {
  __shared__ float qs[NW * (ND + 1)];
  __shared__ float ks[NW * (ND + 1)];
  __shared__ float sc[NW * (NW + 1)];
  __shared__ int idxs[NW];
  __shared__ float kmv[NW];
  __shared__ float cinv[NW];
  int bhc = blockIdx.x;
  int h = (bhc >> 6) & (NH - 1);
  int b = bhc >> 9;
  int t = threadIdx.x;
  if (t < NW) {
    int n = idxb[(size_t)bhc * NW + t];
    idxs[t] = n;
    kmv[t] = (value[b * NS + n] != 0) ? 1.f : 0.f;
    cinv[t] = 1.0f / fmaxf(cnt[(size_t)(b * NS + n) * NH + h], 1.0f);
  }
  __syncthreads();
  for (int p = t; p < NW * ND; p += 256) {
    int w = p >> 6, d = p & (ND - 1);
    size_t src = (size_t)(b * NS + idxs[w]) * NE + h * ND + d;
    qs[w * (ND + 1) + d] = q[src];
    ks[w * (ND + 1) + d] = k[src];
  }
  __syncthreads();
  for (int p = t; p < NW * NW; p += 256) {
    int w = p >> 6, x = p & (NW - 1);
    float dot = 0.f;
#pragma unroll 16
    for (int d = 0; d < ND; d++) dot += qs[w * (ND + 1) + d] * ks[x * (ND + 1) + d];
    bool allowed = (idxs[w] >= idxs[x]) && (kmv[x] != 0.f);
    sc[w * (NW + 1) + x] = allowed ? dot * 0.125f : -1e9f;
  }
  __syncthreads();
  if (t < NW) {
    float mx = -3.4e38f;
    for (int x = 0; x < NW; x++) mx = fmaxf(mx, sc[t * (NW + 1) + x]);
    float sum = 0.f;
    for (int x = 0; x < NW; x++) {
      float e = expf(sc[t * (NW + 1) + x] - mx);
      sc[t * (NW + 1) + x] = e;
      sum += e;
    }
    float inv = cinv[t] / sum;
    for (int x = 0; x < NW; x++) sc[t * (NW + 1) + x] *= inv;
  }
  for (int p = t; p < NW * ND; p += 256) {
    int w = p >> 6, d = p & (ND - 1);
    ks[w * (ND + 1) + d] = v[(size_t)(b * NS + idxs[w]) * NE + h * ND + d];
  }
  __syncthreads();
  for (int p = t; p < NW * ND; p += 256) {
    int w = p >> 6, d = p & (ND - 1);
    float o = 0.f;
#pragma unroll 16
    for (int x = 0; x < NW; x++) o += sc[w * (NW + 1) + x] * ks[x * (ND + 1) + d];
    qs[w * (ND + 1) + d] = o;
  }
  __syncthreads();
  for (int p = t; p < NW * ND; p += 256) {
    int w = p >> 6, d = p & (ND - 1);
    atomicAdd(&obuf[(size_t)(b * NS + idxs[w]) * NE + h * ND + d], qs[w * (ND + 1) + d]);
  }
}

// ---------------- head ----------------
__global__ __launch_bounds__(256) void head_kernel(
    const float* __restrict__ x, const void* __restrict__ hw, void* __restrict__ out, int f32) {
  int gw = (blockIdx.x * 256 + threadIdx.x) >> 6;
  int lane = threadIdx.x & 63;
  if (gw >= NTOK * NVOC) return;
  int row = gw / NVOC, vv = gw % NVOC;
  const float* xr = x + (size_t)row * NE;
  float acc = 0.f;
  for (int e = lane; e < NE; e += 64) acc += xr[e] * ldw(hw, (size_t)vv * NE + e, f32);
#pragma unroll
  for (int o = 32; o; o >>= 1) acc += __shfl_down(acc, o);
  if (lane == 0) {
    if (f32) ((float*)out)[(size_t)row * NVOC + vv] = acc;
    else ((bf16*)out)[(size_t)row * NVOC + vv] = __float2bfloat16(acc);
  }
}

extern "C" void kernel_launch(void* const* d_in, const int* in_sizes, int n_in,
                              void* d_out, int out_size, void* d_ws, size_t ws_size,
                              hipStream_t stream) {
  const int* value = (const int*)d_in[0];
  const int* depth = (const int*)d_in[1];
  const int* pos = (const int*)d_in[2];
  const void* sos = d_in[3];
  const void* tok_emb = d_in[4];
  const void* depth_emb = d_in[5];
  const void* pos_emb = d_in[6];
  const void* ln1_s = d_in[7];
  const void* ln1_b = d_in[8];
  const void* Wq = d_in[9];
  const void* Wk = d_in[10];
  const void* Wv = d_in[11];
  const void* Wo = d_in[12];
  const void* means = d_in[13];
  const void* ln2_s = d_in[14];
  const void* ln2_b = d_in[15];
  const void* W1 = d_in[16];
  const void* b1 = d_in[17];
  const void* W2 = d_in[18];
  const void* b2 = d_in[19];
  const void* head_w = d_in[20];
  (void)n_in;

  int f32 = (in_sizes[4] != 17408) ? 1 : 0;

  const size_t NX = (size_t)NTOK * NE;
  const size_t NEED = 170917896ULL;
  const size_t WSOFF = 170918144ULL;                       // 256-aligned
  const size_t NEED_PS = WSOFF + 3ULL * WPLANE * 2ULL;     // + 18 MiB split planes
  if (ws_size < NEED) {
    float val = (float)(unsigned)(ws_size >> 20) * 1000.0f;
    fill_out_kernel<<<(out_size + 255) / 256, 256, 0, stream>>>((float*)d_out, out_size, val);
    return;
  }
  int useps = (ws_size >= NEED_PS) ? 1 : 0;

  float* xbuf = (float*)d_ws;
  float* hbuf = xbuf + NX;       // LN1 out / qT / attn accumulator (time-shared)
  float* qbuf = hbuf + NX;
  float* kbuf = qbuf + NX;
  float* vbuf = kbuf + NX;
  double* mndbuf = (double*)(vbuf + NX);
  double* rqdbuf = mndbuf + (size_t)NL * NH * NC * ND;
  float* cntbuf = (float*)(rqdbuf + (size_t)NTOK * NH);
  int* idxbuf = (int*)(cntbuf + (size_t)NTOK * NH);
  unsigned short* wsbuf = (unsigned short*)((char*)d_ws + WSOFF);
  float* mid = kbuf;

  mnd_kernel<<<NL * NH * NC, 64, 0, stream>>>(means, mndbuf, f32);
  embed_kernel<<<(int)((NX + 255) / 256), 256, 0, stream>>>(
      value, depth, pos, sos, tok_emb, depth_emb, pos_emb, xbuf, f32);

  dim3 g512(NE / 128, NTOK / 128);
  dim3 gqkv(12, NTOK / 128);

  if (f32) {
    const float* Wqf = (const float*)Wq;
    const float* Wkf = (const float*)Wk;
    const float* Wvf = (const float*)Wv;
    const float* Wof = (const float*)Wo;
    const float* W1f = (const float*)W1;
    const float* W2f = (const float*)W2;
    const float* b1f = (const float*)b1;
    const float* b2f = (const float*)b2;
    for (int l = 0; l < NL; l++) {
      size_t o_w = (size_t)l * NE * NE;
      size_t o_w1 = (size_t)l * NE * NF;
      size_t o_w2 = (size_t)l * NF * NE;
      size_t o_e = (size_t)l * NE;
      size_t o_f = (size_t)l * NF;

      if (useps)
        wsplit_kernel<<<768, 256, 0, stream>>>(Wqf, Wkf, Wvf, Wof, W1f, W2f,
                                               o_w, o_w1, wsbuf);

      ln_kernel<<<NTOK / 4, 256, 0, stream>>>(xbuf, ln1_s, ln1_b, o_e, hbuf, 1);

      if (useps) {
        gemm_qkv_mfma_ps<<<gqkv, 256, 0, stream>>>(hbuf, wsbuf, qbuf, kbuf, vbuf);
      } else {
        gemm_qkv_mfma<<<gqkv, 256, 0, stream>>>(hbuf, Wqf, Wkf, Wvf, o_w, qbuf, kbuf, vbuf);
      }

      qt_kernel<<<NB * NH * 64, 256, 0, stream>>>(qbuf, hbuf);
      rq_kernel<<<NTOK * NH, 64, 0, stream>>>(qbuf, rqdbuf);
      route_kernel<<<NB * NH * NC, 256, 0, stream>>>(
          hbuf, mndbuf + (size_t)l * NH * NC * ND, rqdbuf, idxbuf);
      zero_kernel<<<(NTOK * NH) / 256, 256, 0, stream>>>(cntbuf, NTOK * NH);
      cnt_kernel<<<(NB * NH * NC * NW) / 256, 256, 0, stream>>>(idxbuf, cntbuf);

      zero_kernel<<<(int)((NX + 255) / 256), 256, 0, stream>>>(hbuf, (int)NX);
      attn_kernel<<<NB * NH * NC, 256, 0, stream>>>(qbuf, kbuf, vbuf, idxbuf, value, cntbuf, hbuf);
      if (useps) {
        gemm_mfma_ps_kernel<0><<<g512, 256, 0, stream>>>(
            hbuf, wsbuf + 3u * 262144u, 512, nullptr, xbuf, xbuf, NE, NE);
      } else {
        gemm_mfma_kernel<0><<<g512, 256, 0, stream>>>(hbuf, Wof + o_w, NE, nullptr, xbuf,
                                                      xbuf, NE, NE);
      }

      ln_kernel<<<NTOK / 4, 256, 0, stream>>>(xbuf, ln2_s, ln2_b, o_e, qbuf, 1);
      for (int c = 0; c < 4; c++) {
        if (useps) {
          gemm_mfma_ps_kernel<1><<<g512, 256, 0, stream>>>(
              qbuf, wsbuf + 1048576u + (size_t)c * 262144u, 512,
              b1f + o_f + (size_t)c * 512, nullptr, mid, 512, NE);
          gemm_mfma_ps_kernel<0><<<g512, 256, 0, stream>>>(
              mid, wsbuf + 2097152u + (size_t)c * 512, 2048,
              (c == 0) ? (b2f + o_e) : nullptr, xbuf, xbuf, NE, 512);
        } else {
          gemm_mfma_kernel<1><<<g512, 256, 0, stream>>>(
              qbuf, W1f + o_w1 + (size_t)c * 512, NF, b1f + o_f + (size_t)c * 512,
              nullptr, mid, 512, NE);
          gemm_mfma_kernel<0><<<g512, 256, 0, stream>>>(
              mid, W2f + o_w2 + (size_t)c * 512 * NE, NE,
              (c == 0) ? (b2f + o_e) : nullptr, xbuf, xbuf, NE, 512);
        }
      }
    }
  } else {
    const int CH = 8192;
    dim3 gqkvv(12, NTOK / 128);
    dim3 gW1(NF / 128, CH / 128);
    dim3 gW2(NE / 128, CH / 128);
    for (int l = 0; l < NL; l++) {
      size_t o_w = (size_t)l * NE * NE;
      size_t o_w1 = (size_t)l * NE * NF;
      size_t o_w2 = (size_t)l * NF * NE;
      size_t o_e = (size_t)l * NE;
      size_t o_f = (size_t)l * NF;

      ln_kernel<<<NTOK / 4, 256, 0, stream>>>(xbuf, ln1_s, ln1_b, o_e, hbuf, 0);
      gemm_qkv_kernel<<<gqkvv, 256, 0, stream>>>(hbuf, Wq, Wk, Wv, o_w, qbuf, kbuf, vbuf, 0);

      qt_kernel<<<NB * NH * 64, 256, 0, stream>>>(qbuf, hbuf);
      rq_kernel<<<NTOK * NH, 64, 0, stream>>>(qbuf, rqdbuf);
      route_kernel<<<NB * NH * NC, 256, 0, stream>>>(
          hbuf, mndbuf + (size_t)l * NH * NC * ND, rqdbuf, idxbuf);
      zero_kernel<<<(NTOK * NH) / 256, 256, 0, stream>>>(cntbuf, NTOK * NH);
      cnt_kernel<<<(NB * NH * NC * NW) / 256, 256, 0, stream>>>(idxbuf, cntbuf);

      zero_kernel<<<(int)((NX + 255) / 256), 256, 0, stream>>>(hbuf, (int)NX);
      attn_kernel<<<NB * NH * NC, 256, 0, stream>>>(qbuf, kbuf, vbuf, idxbuf, value, cntbuf, hbuf);
      gemm_kernel<0><<<g512, 256, 0, stream>>>(hbuf, Wo, o_w, NE, nullptr, 0, xbuf,
                                               xbuf, NE, NE, 0);

      ln_kernel<<<NTOK / 4, 256, 0, stream>>>(xbuf, ln2_s, ln2_b, o_e, qbuf, 0);
      for (int ch = 0; ch < NTOK / CH; ch++) {
        const float* hch = qbuf + (size_t)ch * CH * NE;
        float* xch = xbuf + (size_t)ch * CH * NE;
        gemm_kernel<1><<<gW1, 256, 0, stream>>>(hch, W1, o_w1, NF, b1, o_f, nullptr,
                                                mid, NF, NE, 0);
        gemm_kernel<0><<<gW2, 256, 0, stream>>>(mid, W2, o_w2, NE, b2, o_e, xch,
                                                xch, NE, NF, 0);
      }
    }
  }

  head_kernel<<<(NTOK * NVOC * 64 + 255) / 256, 256, 0, stream>>>(xbuf, head_w, d_out, f32);
}

// Round 9
// 5714.272 us; speedup vs baseline: 1.0482x; 1.0482x over previous
//
#include <hip/hip_runtime.h>
#include <hip/hip_bf16.h>
#include <math.h>

typedef __hip_bfloat16 bf16;
typedef __attribute__((ext_vector_type(2))) float f2v;
typedef __attribute__((ext_vector_type(8))) short bf16x8;
typedef __attribute__((ext_vector_type(4))) float f32x4;

#define NB 4
#define NS 4096
#define NE 512
#define NH 8
#define NL 4
#define NA 3
#define ND 64
#define NC 64
#define NW 64
#define NF 2048
#define NVOC 17
#define NTOK (NB * NS)   // 16384

__device__ __forceinline__ float b2f(bf16 v) { return __bfloat162float(v); }
__device__ __forceinline__ float u2f(unsigned short u) { return __uint_as_float((unsigned)u << 16); }
__device__ __forceinline__ float ldw(const void* p, size_t i, int f32) {
  return f32 ? ((const float*)p)[i] : b2f(((const bf16*)p)[i]);
}
__device__ __forceinline__ unsigned short f2bf(float f) {   // RNE fp32->bf16
  unsigned u = __float_as_uint(f);
  return (unsigned short)((u + 0x7FFFu + ((u >> 16) & 1u)) >> 16);
}
// 3-way bf16 split: a ~= h + m + l, |a-h-m-l| <= 2^-24 |a|
__device__ __forceinline__ void split3(float a, unsigned short& h, unsigned short& m,
                                       unsigned short& l) {
  h = f2bf(a);
  float r = a - u2f(h);
  m = f2bf(r);
  float s = r - u2f(m);
  l = f2bf(s);
}

// ---------------- diagnostic fill (ws_size too small) ----------------
__global__ __launch_bounds__(256) void fill_out_kernel(float* __restrict__ out, int n, float val) {
  int i = blockIdx.x * 256 + threadIdx.x;
  if (i < n) out[i] = val;
}

// ---------------- zero fill ----------------
__global__ __launch_bounds__(256) void zero_kernel(float* __restrict__ p, int n) {
  int i = blockIdx.x * 256 + threadIdx.x;
  if (i < n) p[i] = 0.f;
}

// ---------------- embeddings + shift-right ----------------
__global__ __launch_bounds__(256) void embed_kernel(
    const int* __restrict__ value, const int* __restrict__ depth, const int* __restrict__ pos,
    const void* __restrict__ sos, const void* __restrict__ tok_emb,
    const void* __restrict__ depth_emb, const void* __restrict__ pos_emb,
    float* __restrict__ x, int f32) {
  int i = blockIdx.x * 256 + threadIdx.x;
  if (i >= NTOK * NE) return;
  int e = i & (NE - 1);
  int bs = i >> 9;
  int s = bs & (NS - 1);
  int b = bs >> 12;
  float v;
  if (s == 0) {
    v = ldw(sos, e, f32);
  } else {
    int src = b * NS + (s - 1);
    float acc = ldw(tok_emb, (size_t)value[src] * NE + e, f32)
              + ldw(depth_emb, (size_t)depth[src] * NE + e, f32);
#pragma unroll
    for (int a = 0; a < NA; a++)
      acc += ldw(pos_emb, ((size_t)a * 65 + pos[src * NA + a]) * NE + e, f32);
    v = acc;
  }
  x[i] = v;
}

// ---------------- layer norm, one wave per row ----------------
__global__ __launch_bounds__(256) void ln_kernel(
    const float* __restrict__ x, const void* __restrict__ gam, const void* __restrict__ bet,
    size_t off, float* __restrict__ out, int f32) {
  int row = blockIdx.x * 4 + (threadIdx.x >> 6);
  int lane = threadIdx.x & 63;
  const float* xr = x + (size_t)row * NE;
  float v[8];
#pragma unroll
  for (int i = 0; i < 8; i++) v[i] = xr[lane + i * 64];
  float s = 0.f;
#pragma unroll
  for (int i = 0; i < 8; i++) s += v[i];
#pragma unroll
  for (int o = 32; o; o >>= 1) s += __shfl_xor(s, o);
  float m = s * (1.0f / NE);
  float sq = 0.f;
#pragma unroll
  for (int i = 0; i < 8; i++) { float d = v[i] - m; sq += d * d; }
#pragma unroll
  for (int o = 32; o; o >>= 1) sq += __shfl_xor(sq, o);
  float rs = 1.0f / sqrtf(sq * (1.0f / NE) + 1e-5f);
  float* orow = out + (size_t)row * NE;
#pragma unroll
  for (int i = 0; i < 8; i++) {
    int e = lane + i * 64;
    orow[e] = (v[i] - m) * rs * ldw(gam, off + e, f32) + ldw(bet, off + e, f32);
  }
}

// ---------------- fp32 vector GEMM core (bf16-input fallback path) ----------------
template <int ACT>
__device__ __forceinline__ void gemm_body(
    const float* __restrict__ A, const void* __restrict__ Bw, size_t bwoff, int ldb,
    const void* bias, size_t biasoff, const float* resid, float* C,
    int N, int K, int f32, int bm, int bn) {
  __shared__ float As[32][132];
  __shared__ float Bs[32][132];
  int tid = threadIdx.x;
  int ty = tid >> 4, tx = tid & 15;
  f2v acc2[8][4];
#pragma unroll
  for (int i = 0; i < 8; i++)
#pragma unroll
    for (int j = 0; j < 4; j++) acc2[i][j] = (f2v){0.f, 0.f};
  int arow = tid >> 1;
  int acol = (tid & 1) << 4;
  int brow = tid >> 3;
  int bcol = (tid & 7) << 4;

  const float* Aptr = A + (size_t)(bm + arow) * K + acol;
  float4 pa[4];
  float4 pb[4];
  uint4 pbu[2];
#pragma unroll
  for (int j = 0; j < 4; j++) pa[j] = *(const float4*)(Aptr + 4 * j);
  {
    size_t boff = bwoff + (size_t)brow * ldb + bn + bcol;
    if (f32) {
#pragma unroll
      for (int j = 0; j < 4; j++) pb[j] = *(const float4*)((const float*)Bw + boff + 4 * j);
    } else {
      pbu[0] = *(const uint4*)((const bf16*)Bw + boff);
      pbu[1] = *(const uint4*)((const bf16*)Bw + boff + 8);
    }
  }

  for (int k0 = 0; k0 < K; k0 += 32) {
#pragma unroll
    for (int j = 0; j < 4; j++) {
      As[acol + 4 * j + 0][arow] = pa[j].x;
      As[acol + 4 * j + 1][arow] = pa[j].y;
      As[acol + 4 * j + 2][arow] = pa[j].z;
      As[acol + 4 * j + 3][arow] = pa[j].w;
    }
    if (f32) {
#pragma unroll
      for (int j = 0; j < 4; j++) {
        Bs[brow][bcol + 4 * j + 0] = pb[j].x;
        Bs[brow][bcol + 4 * j + 1] = pb[j].y;
        Bs[brow][bcol + 4 * j + 2] = pb[j].z;
        Bs[brow][bcol + 4 * j + 3] = pb[j].w;
      }
    } else {
      union { uint4 u; unsigned short s[8]; } r0, r1;
      r0.u = pbu[0]; r1.u = pbu[1];
#pragma unroll
      for (int j = 0; j < 8; j++) Bs[brow][bcol + j] = u2f(r0.s[j]);
#pragma unroll
      for (int j = 0; j < 8; j++) Bs[brow][bcol + 8 + j] = u2f(r1.s[j]);
    }
    __syncthreads();
    if (k0 + 32 < K) {
#pragma unroll
      for (int j = 0; j < 4; j++) pa[j] = *(const float4*)(Aptr + k0 + 32 + 4 * j);
      size_t boff = bwoff + (size_t)(k0 + 32 + brow) * ldb + bn + bcol;
      if (f32) {
#pragma unroll
        for (int j = 0; j < 4; j++) pb[j] = *(const float4*)((const float*)Bw + boff + 4 * j);
      } else {
        pbu[0] = *(const uint4*)((const bf16*)Bw + boff);
        pbu[1] = *(const uint4*)((const bf16*)Bw + boff + 8);
      }
    }
#pragma unroll
    for (int kk = 0; kk < 32; kk++) {
      float4 aA = *(const float4*)&As[kk][ty << 3];
      float4 aB = *(const float4*)&As[kk][(ty << 3) + 4];
      float4 bA = *(const float4*)&Bs[kk][tx << 2];
      float4 bB = *(const float4*)&Bs[kk][64 + (tx << 2)];
      float av[8] = {aA.x, aA.y, aA.z, aA.w, aB.x, aB.y, aB.z, aB.w};
      f2v bv[4];
      bv[0] = (f2v){bA.x, bA.y};
      bv[1] = (f2v){bA.z, bA.w};
      bv[2] = (f2v){bB.x, bB.y};
      bv[3] = (f2v){bB.z, bB.w};
#pragma unroll
      for (int i = 0; i < 8; i++)
#pragma unroll
        for (int j = 0; j < 4; j++)
          acc2[i][j] += bv[j] * av[i];
    }
    __syncthreads();
  }
#pragma unroll
  for (int i = 0; i < 8; i++) {
    int row = bm + (ty << 3) + i;
    int c0 = bn + (tx << 2);
    int c1 = bn + 64 + (tx << 2);
    const float* ap = (const float*)&acc2[i][0];
    float o0[4], o1[4];
#pragma unroll
    for (int j = 0; j < 4; j++) { o0[j] = ap[j]; o1[j] = ap[4 + j]; }
    if (bias) {
#pragma unroll
      for (int j = 0; j < 4; j++) {
        o0[j] += ldw(bias, biasoff + c0 + j, f32);
        o1[j] += ldw(bias, biasoff + c1 + j, f32);
      }
    }
    if (ACT == 1) {
#pragma unroll
      for (int j = 0; j < 4; j++) {
        float t0 = 0.7978845608028654f * (o0[j] + 0.044715f * o0[j] * o0[j] * o0[j]);
        o0[j] = 0.5f * o0[j] * (1.0f + tanhf(t0));
        float t1 = 0.7978845608028654f * (o1[j] + 0.044715f * o1[j] * o1[j] * o1[j]);
        o1[j] = 0.5f * o1[j] * (1.0f + tanhf(t1));
      }
    }
    size_t p0 = (size_t)row * N + c0;
    size_t p1 = (size_t)row * N + c1;
    if (resid) {
      float4 r0 = *(const float4*)(resid + p0);
      float4 r1 = *(const float4*)(resid + p1);
      o0[0] += r0.x; o0[1] += r0.y; o0[2] += r0.z; o0[3] += r0.w;
      o1[0] += r1.x; o1[1] += r1.y; o1[2] += r1.z; o1[3] += r1.w;
    }
    *(float4*)(C + p0) = make_float4(o0[0], o0[1], o0[2], o0[3]);
    *(float4*)(C + p1) = make_float4(o1[0], o1[1], o1[2], o1[3]);
  }
}

template <int ACT>
__global__ __launch_bounds__(256) void gemm_kernel(
    const float* __restrict__ A, const void* __restrict__ Bw, size_t bwoff, int ldb,
    const void* bias, size_t biasoff, const float* resid, float* C,
    int N, int K, int f32) {
  gemm_body<ACT>(A, Bw, bwoff, ldb, bias, biasoff, resid, C, N, K,
                 f32, blockIdx.y << 7, blockIdx.x << 7);
}

__global__ __launch_bounds__(256) void gemm_qkv_kernel(
    const float* __restrict__ A,
    const void* __restrict__ Wq, const void* __restrict__ Wk, const void* __restrict__ Wv,
    size_t bwoff, float* __restrict__ Cq, float* __restrict__ Ck, float* __restrict__ Cv,
    int f32) {
  int sel = blockIdx.x >> 2;
  const void* Bw = (sel == 0) ? Wq : ((sel == 1) ? Wk : Wv);
  float* C = (sel == 0) ? Cq : ((sel == 1) ? Ck : Cv);
  gemm_body<0>(A, Bw, bwoff, NE, nullptr, 0, nullptr, C, NE, NE,
               f32, blockIdx.y << 7, (blockIdx.x & 3) << 7);
}

// ---------------- MFMA GEMM for fp32 A x fp32 W: 3-way bf16 splits, 6 products ----------------
// LDS [128][32] ushort per plane (49,152 B total -> 3 blocks/CU) with chunk-XOR swizzle:
// data k-chunk c (8 ushorts) of row r stored at chunk position c ^ ((r>>2)&3).
// Bank check: A-writes and frag b128 reads distribute 8 lanes per 4-bank group (even = floor).
// Frag read: row ar, k-chunk lg at col 8*(lg ^ (lr>>2)) since (ar>>2)&3 == lr>>2 for
// ar = 64w + 16m + lr. Same k-chunk recovery for A and B -> operand k-order consistent.
template <int ACT>
__device__ __forceinline__ void mfma_body(
    const float* __restrict__ A, const float* __restrict__ Bw, int ldb,
    const float* __restrict__ bias, const float* __restrict__ resid, float* __restrict__ C,
    int N, int K, int bm, int bn) {
  __shared__ unsigned short Ah[128][32];
  __shared__ unsigned short Am[128][32];
  __shared__ unsigned short Al[128][32];
  __shared__ unsigned short Bh[128][32];
  __shared__ unsigned short Bm[128][32];
  __shared__ unsigned short Bl[128][32];
  int t = threadIdx.x;
  int arow = t >> 1;
  int akc = (t & 1) << 4;            // ushort k-offset 0|16 -> data chunks c0=0|2, c0+1
  int ac0 = (t & 1) << 1;            // first data chunk
  int rsw = (arow >> 2) & 3;         // row swizzle key
  int ap0 = (ac0 ^ rsw) << 3;        // ushort col of first chunk
  int ap1 = ((ac0 + 1) ^ rsw) << 3;  // ushort col of second chunk
  const float* Ap = A + (size_t)(bm + arow) * K + akc;
  int bkr = t >> 3;
  int bcg = t & 7;
  const float* Bp = Bw + (size_t)bkr * ldb + bn + bcg * 16;
  int bchunk = bkr >> 3;             // data k-chunk of this thread's B row
  int bko = bkr & 7;                 // within-chunk ushort offset

  float4 pa[4], pb[4];
#pragma unroll
  for (int j = 0; j < 4; j++) pa[j] = *(const float4*)(Ap + 4 * j);
#pragma unroll
  for (int j = 0; j < 4; j++) pb[j] = *(const float4*)(Bp + 4 * j);

  int lane = t & 63;
  int wid = t >> 6;
  int wr = wid >> 1, wc = wid & 1;
  int lr = lane & 15, lg = lane >> 4;
  int lsw = lr >> 2;                 // frag-read swizzle key

  f32x4 acc[4][4];
#pragma unroll
  for (int i = 0; i < 4; i++)
#pragma unroll
    for (int j = 0; j < 4; j++) acc[i][j] = (f32x4){0.f, 0.f, 0.f, 0.f};

  for (int k0 = 0; k0 < K; k0 += 32) {
    // ---- stage A (3 planes, swizzled chunks) ----
    {
      unsigned hs[8], ms[8], ls[8];
#pragma unroll
      for (int j = 0; j < 4; j++) {
        const float* pf = (const float*)&pa[j];
#pragma unroll
        for (int e = 0; e < 2; e++) {
          unsigned short h0, m0, l0, h1, m1, l1;
          split3(pf[2 * e], h0, m0, l0);
          split3(pf[2 * e + 1], h1, m1, l1);
          hs[2 * j + e] = (unsigned)h0 | ((unsigned)h1 << 16);
          ms[2 * j + e] = (unsigned)m0 | ((unsigned)m1 << 16);
          ls[2 * j + e] = (unsigned)l0 | ((unsigned)l1 << 16);
        }
      }
      *(uint4*)&Ah[arow][ap0] = make_uint4(hs[0], hs[1], hs[2], hs[3]);
      *(uint4*)&Ah[arow][ap1] = make_uint4(hs[4], hs[5], hs[6], hs[7]);
      *(uint4*)&Am[arow][ap0] = make_uint4(ms[0], ms[1], ms[2], ms[3]);
      *(uint4*)&Am[arow][ap1] = make_uint4(ms[4], ms[5], ms[6], ms[7]);
      *(uint4*)&Al[arow][ap0] = make_uint4(ls[0], ls[1], ls[2], ls[3]);
      *(uint4*)&Al[arow][ap1] = make_uint4(ls[4], ls[5], ls[6], ls[7]);
    }
    // ---- stage B (3 planes, transpose-scatter with swizzled chunks) ----
    {
#pragma unroll
      for (int j = 0; j < 4; j++) {
        const float* pf = (const float*)&pb[j];
#pragma unroll
        for (int e = 0; e < 4; e++) {
          unsigned short h, m, l;
          split3(pf[e], h, m, l);
          int nn = bcg * 16 + 4 * j + e;
          int col = (((bchunk ^ ((nn >> 2) & 3)) << 3) | bko);
          Bh[nn][col] = h;
          Bm[nn][col] = m;
          Bl[nn][col] = l;
        }
      }
    }
    __syncthreads();
    if (k0 + 32 < K) {
#pragma unroll
      for (int j = 0; j < 4; j++) pa[j] = *(const float4*)(Ap + k0 + 32 + 4 * j);
      const float* Bn = Bp + (size_t)(k0 + 32) * ldb;
#pragma unroll
      for (int j = 0; j < 4; j++) pb[j] = *(const float4*)(Bn + 4 * j);
    }
    // ---- fragments + 6-product MFMA ----
    bf16x8 fbh[4], fbm[4], fbl[4];
    int fcol = ((lg ^ lsw) & 3) << 3;
#pragma unroll
    for (int ni = 0; ni < 4; ni++) {
      int rb = wc * 64 + ni * 16 + lr;
      fbh[ni] = *(const bf16x8*)&Bh[rb][fcol];
      fbm[ni] = *(const bf16x8*)&Bm[rb][fcol];
      fbl[ni] = *(const bf16x8*)&Bl[rb][fcol];
    }
#pragma unroll
    for (int mi = 0; mi < 4; mi++) {
      int ar = wr * 64 + mi * 16 + lr;
      bf16x8 fh = *(const bf16x8*)&Ah[ar][fcol];
      bf16x8 fm = *(const bf16x8*)&Am[ar][fcol];
      bf16x8 fl = *(const bf16x8*)&Al[ar][fcol];
#pragma unroll
      for (int ni = 0; ni < 4; ni++) {
        f32x4 a = acc[mi][ni];
        a = __builtin_amdgcn_mfma_f32_16x16x32_bf16(fh, fbh[ni], a, 0, 0, 0);
        a = __builtin_amdgcn_mfma_f32_16x16x32_bf16(fh, fbm[ni], a, 0, 0, 0);
        a = __builtin_amdgcn_mfma_f32_16x16x32_bf16(fm, fbh[ni], a, 0, 0, 0);
        a = __builtin_amdgcn_mfma_f32_16x16x32_bf16(fm, fbm[ni], a, 0, 0, 0);
        a = __builtin_amdgcn_mfma_f32_16x16x32_bf16(fh, fbl[ni], a, 0, 0, 0);
        a = __builtin_amdgcn_mfma_f32_16x16x32_bf16(fl, fbh[ni], a, 0, 0, 0);
        acc[mi][ni] = a;
      }
    }
    __syncthreads();
  }
#pragma unroll
  for (int mi = 0; mi < 4; mi++) {
#pragma unroll
    for (int ni = 0; ni < 4; ni++) {
      int col = bn + wc * 64 + ni * 16 + lr;
      int rbase = bm + wr * 64 + mi * 16 + lg * 4;
      float bv = bias ? bias[col] : 0.f;
      const float* av = (const float*)&acc[mi][ni];
#pragma unroll
      for (int r = 0; r < 4; r++) {
        float o = av[r] + bv;
        if (ACT == 1) {
          float t0 = 0.7978845608028654f * (o + 0.044715f * o * o * o);
          o = 0.5f * o * (1.0f + tanhf(t0));
        }
        size_t p = (size_t)(rbase + r) * N + col;
        if (resid) o += resid[p];
        C[p] = o;
      }
    }
  }
}

template <int ACT>
__global__ __launch_bounds__(256) void gemm_mfma_kernel(
    const float* __restrict__ A, const float* __restrict__ Bw, int ldb,
    const float* __restrict__ bias, const float* __restrict__ resid, float* __restrict__ C,
    int N, int K) {
  mfma_body<ACT>(A, Bw, ldb, bias, resid, C, N, K, blockIdx.y << 7, blockIdx.x << 7);
}

// fused q/k/v MFMA
__global__ __launch_bounds__(256) void gemm_qkv_mfma(
    const float* __restrict__ A, const float* __restrict__ Wq, const float* __restrict__ Wk,
    const float* __restrict__ Wv, size_t off,
    float* __restrict__ Cq, float* __restrict__ Ck, float* __restrict__ Cv) {
  int sel = blockIdx.x >> 2;
  const float* Bw = (sel == 0) ? Wq : ((sel == 1) ? Wk : Wv);
  float* C = (sel == 0) ? Cq : ((sel == 1) ? Ck : Cv);
  mfma_body<0>(A, Bw + off, NE, nullptr, nullptr, C, NE, NE,
               blockIdx.y << 7, (blockIdx.x & 3) << 7);
}

// ---------------- q transpose + fused rq: qT[b][h][d][n], rqd[b][h][n] ----------------
// rqd computed with the SAME 64-lane butterfly as the old rq_kernel -> bit-identical.
__global__ __launch_bounds__(256) void qt_kernel(const float* __restrict__ q, float* __restrict__ qT,
                                                 double* __restrict__ rqd) {
  __shared__ float tile[64][65];
  int bid = blockIdx.x;
  int st = bid & 63;
  int bh = bid >> 6;
  int b = bh >> 3, h = bh & 7;
  int s0 = st * 64;
  int t = threadIdx.x;
#pragma unroll
  for (int k = 0; k < 16; k++) {
    int idx = t + k * 256;
    int sl = idx >> 6, dl = idx & 63;
    tile[sl][dl] = q[(size_t)(b * NS + s0 + sl) * NE + h * ND + dl];
  }
  __syncthreads();
#pragma unroll
  for (int k = 0; k < 16; k++) {
    int idx = t + k * 256;
    int dl = idx >> 6, sl = idx & 63;
    qT[((size_t)bh * 64 + dl) * NS + s0 + sl] = tile[sl][dl];
  }
  // fused rq: wave w handles tokens w*16..w*16+15
  int w = t >> 6, lane = t & 63;
#pragma unroll
  for (int i = 0; i < 16; i++) {
    int tok = w * 16 + i;
    double v = (double)tile[tok][lane];
    double ss = v * v;
#pragma unroll
    for (int o = 32; o; o >>= 1) ss += __shfl_xor(ss, o);
    if (lane == 0) rqd[((size_t)bh << 12) | (s0 + tok)] = 1.0 / (sqrt(ss) + 1e-8);
  }
}

// ---------------- normalized means in fp64 ----------------
__global__ __launch_bounds__(64) void mnd_kernel(const void* __restrict__ means,
                                                 double* __restrict__ mnd, int f32) {
  __shared__ double s[64];
  int vblk = blockIdx.x;
  int d = threadIdx.x;
  double m = (double)ldw(means, (size_t)vblk * ND + d, f32);
  s[d] = m * m;
  __syncthreads();
  for (int st = 32; st; st >>= 1) { if (d < st) s[d] += s[d + st]; __syncthreads(); }
  mnd[(size_t)vblk * ND + d] = m / (sqrt(s[0]) + 1e-8);
}

// ---------------- routing: fp64 dists (coalesced qT) + exact top-64 + fused cnt ----------------
// cnt atomicAdds fused at emission (counts <=64, integer-valued in float: order-exact).
__global__ __launch_bounds__(256) void route_kernel(
    const float* __restrict__ qT, const double* __restrict__ mnd,
    const double* __restrict__ rqd, int* __restrict__ idxout, float* __restrict__ cnt) {
  __shared__ unsigned long long keys[NS];
  __shared__ double mc[ND];
  __shared__ unsigned hist[256];
  __shared__ unsigned short cand[2][NS];
  __shared__ unsigned s_rem, s_cnt, s_sel, s_cc[2];
  int bid = blockIdx.x;
  int h = bid & 7;
  int b = (bid >> 3) & 3;
  int c = bid >> 5;
  int bhc = ((b * NH + h) * NC) + c;
  int t = threadIdx.x;
  if (t < ND) mc[t] = mnd[((size_t)h * NC + c) * ND + t];
  hist[t] = 0u;
  if (t == 0) { s_rem = NW; s_cnt = 0u; s_cc[0] = 0u; s_cc[1] = 0u; }
  __syncthreads();
  const float* qTb = qT + (size_t)(b * NH + h) * 64 * NS;
  const double* rqb = rqd + ((size_t)(b * NH + h) << 12);
  for (int i = 0; i < 16; i += 4) {
    int n0 = t + i * 256, n1 = n0 + 256, n2 = n0 + 512, n3 = n0 + 768;
    double a0 = 0.0, a1 = 0.0, a2 = 0.0, a3 = 0.0;
#pragma unroll 8
    for (int d = 0; d < 64; d++) {
      const float* row = qTb + (size_t)d * NS;
      double m = mc[d];
      a0 += (double)row[n0] * m;
      a1 += (double)row[n1] * m;
      a2 += (double)row[n2] * m;
      a3 += (double)row[n3] * m;
    }
    double dv[4] = {a0 * rqb[n0], a1 * rqb[n1], a2 * rqb[n2], a3 * rqb[n3]};
    int nn[4] = {n0, n1, n2, n3};
#pragma unroll
    for (int j = 0; j < 4; j++) {
      long long sb = __double_as_longlong(dv[j]);
      unsigned long long u = (unsigned long long)sb;
      u = (sb < 0) ? ~u : (u | 0x8000000000000000ULL);
      keys[nn[j]] = (u & 0xFFFFFFFFFFFFF000ULL) | (unsigned long long)(NS - 1 - nn[j]);
    }
  }
  __syncthreads();
  {
    unsigned lastd = 0xFFFFFFFFu, lcnt = 0u;
    for (int n = t; n < NS; n += 256) {
      unsigned d = (unsigned)(keys[n] >> 56);
      if (d == lastd) { lcnt++; }
      else { if (lcnt) atomicAdd(&hist[lastd], lcnt); lastd = d; lcnt = 1u; }
    }
    if (lcnt) atomicAdd(&hist[lastd], lcnt);
  }
  __syncthreads();
  if (t < 64) {
    unsigned h0 = hist[4 * t + 0], h1 = hist[4 * t + 1];
    unsigned h2 = hist[4 * t + 2], h3 = hist[4 * t + 3];
    hist[4 * t + 0] = 0u; hist[4 * t + 1] = 0u; hist[4 * t + 2] = 0u; hist[4 * t + 3] = 0u;
    unsigned t3 = h3, t2 = h2 + h3, t1 = h1 + t2, t0 = h0 + t1;
    unsigned s = t0;
#pragma unroll
    for (int off = 1; off < 64; off <<= 1) {
      unsigned v = __shfl_down(s, off);
      if (t + off < 64) s += v;
    }
    unsigned E = s - t0;
    unsigned rem = s_rem;
    unsigned sf0 = t0 + E, sf1 = t1 + E, sf2 = t2 + E, sf3 = t3 + E, sf4 = E;
    if (sf0 >= rem && sf1 < rem) { s_sel = 4u * t + 0u; s_rem = rem - sf1; }
    if (sf1 >= rem && sf2 < rem) { s_sel = 4u * t + 1u; s_rem = rem - sf2; }
    if (sf2 >= rem && sf3 < rem) { s_sel = 4u * t + 2u; s_rem = rem - sf3; }
    if (sf3 >= rem && sf4 < rem) { s_sel = 4u * t + 3u; s_rem = rem - sf4; }
  }
  __syncthreads();
  {
    unsigned sel = s_sel;
    for (int n = t; n < NS; n += 256) {
      unsigned d = (unsigned)(keys[n] >> 56);
      if (d > sel) {
        unsigned p = atomicAdd(&s_cnt, 1u);
        idxout[(size_t)bhc * NW + p] = n;
        atomicAdd(&cnt[(size_t)(b * NS + n) * NH + h], 1.0f);
      } else if (d == sel) {
        unsigned p = atomicAdd(&s_cc[0], 1u);
        cand[0][p] = (unsigned short)n;
      }
    }
  }
  __syncthreads();
  int cur = 0;
  for (int p = 6; p >= 0; p--) {
    int sh = p * 8;
    unsigned nc = s_cc[cur];
    for (unsigned i = t; i < nc; i += 256) {
      unsigned d = (unsigned)((keys[cand[cur][i]] >> sh) & 255ULL);
      atomicAdd(&hist[d], 1u);
    }
    __syncthreads();
    if (t < 64) {
      unsigned h0 = hist[4 * t + 0], h1 = hist[4 * t + 1];
      unsigned h2 = hist[4 * t + 2], h3 = hist[4 * t + 3];
      hist[4 * t + 0] = 0u; hist[4 * t + 1] = 0u; hist[4 * t + 2] = 0u; hist[4 * t + 3] = 0u;
      unsigned t3 = h3, t2 = h2 + h3, t1 = h1 + t2, t0 = h0 + t1;
      unsigned s = t0;
#pragma unroll
      for (int off = 1; off < 64; off <<= 1) {
        unsigned v = __shfl_down(s, off);
        if (t + off < 64) s += v;
      }
      unsigned E = s - t0;
      unsigned rem = s_rem;
      unsigned sf0 = t0 + E, sf1 = t1 + E, sf2 = t2 + E, sf3 = t3 + E, sf4 = E;
      if (sf0 >= rem && sf1 < rem) { s_sel = 4u * t + 0u; s_rem = rem - sf1; }
      if (sf1 >= rem && sf2 < rem) { s_sel = 4u * t + 1u; s_rem = rem - sf2; }
      if (sf2 >= rem && sf3 < rem) { s_sel = 4u * t + 2u; s_rem = rem - sf3; }
      if (sf3 >= rem && sf4 < rem) { s_sel = 4u * t + 3u; s_rem = rem - sf4; }
      if (t == 0) s_cc[cur ^ 1] = 0u;
    }
    __syncthreads();
    unsigned sel = s_sel;
    if (p == 0) {
      for (unsigned i = t; i < nc; i += 256) {
        unsigned n = cand[cur][i];
        unsigned d = (unsigned)(keys[n] & 255ULL);
        if (d >= sel) {
          unsigned pp = atomicAdd(&s_cnt, 1u);
          idxout[(size_t)bhc * NW + pp] = n;
          atomicAdd(&cnt[(size_t)(b * NS + n) * NH + h], 1.0f);
        }
      }
    } else {
      int nxt = cur ^ 1;
      for (unsigned i = t; i < nc; i += 256) {
        unsigned n = cand[cur][i];
        unsigned d = (unsigned)((keys[n] >> sh) & 255ULL);
        if (d > sel) {
          unsigned pp = atomicAdd(&s_cnt, 1u);
          idxout[(size_t)bhc * NW + pp] = n;
          atomicAdd(&cnt[(size_t)(b * NS + n) * NH + h], 1.0f);
        } else if (d == sel) {
          unsigned pp = atomicAdd(&s_cc[nxt], 1u);
          cand[nxt][pp] = (unsigned short)n;
        }
      }
      __syncthreads();
      cur = nxt;
    }
  }
}

// ---------------- bucket attention ----------------
__global__ __launch_bounds__(256) void attn_kernel(
    const float* __restrict__ q, const float* __restrict__ k, const float* __restrict__ v,
    const int* __restrict__ idxb, const int* __restrict__ value, const float* __restrict__ cnt,
    float* __restrict__ obuf) {
  __shared__ float qs[NW * (ND + 1)];
  __shared__ float ks[NW * (ND + 1)];
  __shared__ float sc[NW * (NW + 1)];
  __shared__ int idxs[NW];
  __shared__ float kmv[NW];
  __shared__ float cinv[NW];
  int bhc = blockIdx.x;
  int h = (bhc >> 6) & (NH - 1);
  int b = bhc >> 9;
  int t = threadIdx.x;
  if (t < NW) {
    int n = idxb[(size_t)bhc * NW + t];
    idxs[t] = n;
    kmv[t] = (value[b * NS + n] != 0) ? 1.f : 0.f;
    cinv[t] = 1.0f / fmaxf(cnt[(size_t)(b * NS + n) * NH + h], 1.0f);
  }
  __syncthreads();
  for (int p = t; p < NW * ND; p += 256) {
    int w = p >> 6, d = p & (ND - 1);
    size_t src = (size_t)(b * NS + idxs[w]) * NE + h * ND + d;
    qs[w * (ND + 1) + d] = q[src];
    ks[w * (ND + 1) + d] = k[src];
  }
  __syncthreads();
  for (int p = t; p < NW * NW; p += 256) {
    int w = p >> 6, x = p & (NW - 1);
    float dot = 0.f;
#pragma unroll 16
    for (int d = 0; d < ND; d++) dot += qs[w * (ND + 1) + d] * ks[x * (ND + 1) + d];
    bool allowed = (idxs[w] >= idxs[x]) && (kmv[x] != 0.f);
    sc[w * (NW + 1) + x] = allowed ? dot * 0.125f : -1e9f;
  }
  __syncthreads();
  if (t < NW) {
    float mx = -3.4e38f;
    for (int x = 0; x < NW; x++) mx = fmaxf(mx, sc[t * (NW + 1) + x]);
    float sum = 0.f;
    for (int x = 0; x < NW; x++) {
      float e = expf(sc[t * (NW + 1) + x] - mx);
      sc[t * (NW + 1) + x] = e;
      sum += e;
    }
    float inv = cinv[t] / sum;
    for (int x = 0; x < NW; x++) sc[t * (NW + 1) + x] *= inv;
  }
  for (int p = t; p < NW * ND; p += 256) {
    int w = p >> 6, d = p & (ND - 1);
    ks[w * (ND + 1) + d] = v[(size_t)(b * NS + idxs[w]) * NE + h * ND + d];
  }
  __syncthreads();
  for (int p = t; p < NW * ND; p += 256) {
    int w = p >> 6, d = p & (ND - 1);
    float o = 0.f;
#pragma unroll 16
    for (int x = 0; x < NW; x++) o += sc[w * (NW + 1) + x] * ks[x * (ND + 1) + d];
    qs[w * (ND + 1) + d] = o;
  }
  __syncthreads();
  for (int p = t; p < NW * ND; p += 256) {
    int w = p >> 6, d = p & (ND - 1);
    atomicAdd(&obuf[(size_t)(b * NS + idxs[w]) * NE + h * ND + d], qs[w * (ND + 1) + d]);
  }
}

// ---------------- head ----------------
__global__ __launch_bounds__(256) void head_kernel(
    const float* __restrict__ x, const void* __restrict__ hw, void* __restrict__ out, int f32) {
  int gw = (blockIdx.x * 256 + threadIdx.x) >> 6;
  int lane = threadIdx.x & 63;
  if (gw >= NTOK * NVOC) return;
  int row = gw / NVOC, vv = gw % NVOC;
  const float* xr = x + (size_t)row * NE;
  float acc = 0.f;
  for (int e = lane; e < NE; e += 64) acc += xr[e] * ldw(hw, (size_t)vv * NE + e, f32);
#pragma unroll
  for (int o = 32; o; o >>= 1) acc += __shfl_down(acc, o);
  if (lane == 0) {
    if (f32) ((float*)out)[(size_t)row * NVOC + vv] = acc;
    else ((bf16*)out)[(size_t)row * NVOC + vv] = __float2bfloat16(acc);
  }
}

extern "C" void kernel_launch(void* const* d_in, const int* in_sizes, int n_in,
                              void* d_out, int out_size, void* d_ws, size_t ws_size,
                              hipStream_t stream) {
  const int* value = (const int*)d_in[0];
  const int* depth = (const int*)d_in[1];
  const int* pos = (const int*)d_in[2];
  const void* sos = d_in[3];
  const void* tok_emb = d_in[4];
  const void* depth_emb = d_in[5];
  const void* pos_emb = d_in[6];
  const void* ln1_s = d_in[7];
  const void* ln1_b = d_in[8];
  const void* Wq = d_in[9];
  const void* Wk = d_in[10];
  const void* Wv = d_in[11];
  const void* Wo = d_in[12];
  const void* means = d_in[13];
  const void* ln2_s = d_in[14];
  const void* ln2_b = d_in[15];
  const void* W1 = d_in[16];
  const void* b1 = d_in[17];
  const void* W2 = d_in[18];
  const void* b2 = d_in[19];
  const void* head_w = d_in[20];
  (void)n_in;

  int f32 = (in_sizes[4] != 17408) ? 1 : 0;

  const size_t NX = (size_t)NTOK * NE;
  const size_t NEED = 170917896ULL;
  if (ws_size < NEED) {
    float val = (float)(unsigned)(ws_size >> 20) * 1000.0f;
    fill_out_kernel<<<(out_size + 255) / 256, 256, 0, stream>>>((float*)d_out, out_size, val);
    return;
  }

  float* xbuf = (float*)d_ws;
  float* hbuf = xbuf + NX;       // LN1 out / qT / attn accumulator (time-shared)
  float* qbuf = hbuf + NX;
  float* kbuf = qbuf + NX;
  float* vbuf = kbuf + NX;
  double* mndbuf = (double*)(vbuf + NX);
  double* rqdbuf = mndbuf + (size_t)NL * NH * NC * ND;
  float* cntbuf = (float*)(rqdbuf + (size_t)NTOK * NH);
  int* idxbuf = (int*)(cntbuf + (size_t)NTOK * NH);
  float* mid = kbuf;

  mnd_kernel<<<NL * NH * NC, 64, 0, stream>>>(means, mndbuf, f32);
  embed_kernel<<<(int)((NX + 255) / 256), 256, 0, stream>>>(
      value, depth, pos, sos, tok_emb, depth_emb, pos_emb, xbuf, f32);

  dim3 g512(NE / 128, NTOK / 128);
  dim3 gqkv(12, NTOK / 128);

  if (f32) {
    const float* Wqf = (const float*)Wq;
    const float* Wkf = (const float*)Wk;
    const float* Wvf = (const float*)Wv;
    const float* Wof = (const float*)Wo;
    const float* W1f = (const float*)W1;
    const float* W2f = (const float*)W2;
    const float* b1f = (const float*)b1;
    const float* b2f = (const float*)b2;
    for (int l = 0; l < NL; l++) {
      size_t o_w = (size_t)l * NE * NE;
      size_t o_w1 = (size_t)l * NE * NF;
      size_t o_w2 = (size_t)l * NF * NE;
      size_t o_e = (size_t)l * NE;
      size_t o_f = (size_t)l * NF;

      ln_kernel<<<NTOK / 4, 256, 0, stream>>>(xbuf, ln1_s, ln1_b, o_e, hbuf, 1);
      gemm_qkv_mfma<<<gqkv, 256, 0, stream>>>(hbuf, Wqf, Wkf, Wvf, o_w, qbuf, kbuf, vbuf);

      qt_kernel<<<NB * NH * 64, 256, 0, stream>>>(qbuf, hbuf, rqdbuf);
      zero_kernel<<<(NTOK * NH) / 256, 256, 0, stream>>>(cntbuf, NTOK * NH);
      route_kernel<<<NB * NH * NC, 256, 0, stream>>>(
          hbuf, mndbuf + (size_t)l * NH * NC * ND, rqdbuf, idxbuf, cntbuf);

      zero_kernel<<<(int)((NX + 255) / 256), 256, 0, stream>>>(hbuf, (int)NX);
      attn_kernel<<<NB * NH * NC, 256, 0, stream>>>(qbuf, kbuf, vbuf, idxbuf, value, cntbuf, hbuf);
      gemm_mfma_kernel<0><<<g512, 256, 0, stream>>>(hbuf, Wof + o_w, NE, nullptr, xbuf,
                                                    xbuf, NE, NE);

      ln_kernel<<<NTOK / 4, 256, 0, stream>>>(xbuf, ln2_s, ln2_b, o_e, qbuf, 1);
      for (int c = 0; c < 4; c++) {
        gemm_mfma_kernel<1><<<g512, 256, 0, stream>>>(
            qbuf, W1f + o_w1 + (size_t)c * 512, NF, b1f + o_f + (size_t)c * 512,
            nullptr, mid, 512, NE);
        gemm_mfma_kernel<0><<<g512, 256, 0, stream>>>(
            mid, W2f + o_w2 + (size_t)c * 512 * NE, NE,
            (c == 0) ? (b2f + o_e) : nullptr, xbuf, xbuf, NE, 512);
      }
    }
  } else {
    const int CH = 8192;
    dim3 gqkvv(12, NTOK / 128);
    dim3 gW1(NF / 128, CH / 128);
    dim3 gW2(NE / 128, CH / 128);
    for (int l = 0; l < NL; l++) {
      size_t o_w = (size_t)l * NE * NE;
      size_t o_w1 = (size_t)l * NE * NF;
      size_t o_w2 = (size_t)l * NF * NE;
      size_t o_e = (size_t)l * NE;
      size_t o_f = (size_t)l * NF;

      ln_kernel<<<NTOK / 4, 256, 0, stream>>>(xbuf, ln1_s, ln1_b, o_e, hbuf, 0);
      gemm_qkv_kernel<<<gqkvv, 256, 0, stream>>>(hbuf, Wq, Wk, Wv, o_w, qbuf, kbuf, vbuf, 0);

      qt_kernel<<<NB * NH * 64, 256, 0, stream>>>(qbuf, hbuf, rqdbuf);
      zero_kernel<<<(NTOK * NH) / 256, 256, 0, stream>>>(cntbuf, NTOK * NH);
      route_kernel<<<NB * NH * NC, 256, 0, stream>>>(
          hbuf, mndbuf + (size_t)l * NH * NC * ND, rqdbuf, idxbuf, cntbuf);

      zero_kernel<<<(int)((NX + 255) / 256), 256, 0, stream>>>(hbuf, (int)NX);
      attn_kernel<<<NB * NH * NC, 256, 0, stream>>>(qbuf, kbuf, vbuf, idxbuf, value, cntbuf, hbuf);
      gemm_kernel<0><<<g512, 256, 0, stream>>>(hbuf, Wo, o_w, NE, nullptr, 0, xbuf,
                                               xbuf, NE, NE, 0);

      ln_kernel<<<NTOK / 4, 256, 0, stream>>>(xbuf, ln2_s, ln2_b, o_e, qbuf, 0);
      for (int ch = 0; ch < NTOK / CH; ch++) {
        const float* hch = qbuf + (size_t)ch * CH * NE;
        float* xch = xbuf + (size_t)ch * CH * NE;
        gemm_kernel<1><<<gW1, 256, 0, stream>>>(hch, W1, o_w1, NF, b1, o_f, nullptr,
                                                mid, NF, NE, 0);
        gemm_kernel<0><<<gW2, 256, 0, stream>>>(mid, W2, o_w2, NE, b2, o_e, xch,
                                                xch, NE, NF, 0);
      }
    }
  }

  head_kernel<<<(NTOK * NVOC * 64 + 255) / 256, 256, 0, stream>>>(xbuf, head_w, d_out, f32);
}

// Round 10
// 4834.535 us; speedup vs baseline: 1.2389x; 1.1820x over previous
//
#include <hip/hip_runtime.h>
#include <hip/hip_bf16.h>
#include <math.h>

typedef __hip_bfloat16 bf16;
typedef __attribute__((ext_vector_type(2))) float f2v;
typedef __attribute__((ext_vector_type(8))) short bf16x8;
typedef __attribute__((ext_vector_type(4))) float f32x4;

#define NB 4
#define NS 4096
#define NE 512
#define NH 8
#define NL 4
#define NA 3
#define ND 64
#define NC 64
#define NW 64
#define NF 2048
#define NVOC 17
#define NTOK (NB * NS)   // 16384

__device__ __forceinline__ float b2f(bf16 v) { return __bfloat162float(v); }
__device__ __forceinline__ float u2f(unsigned short u) { return __uint_as_float((unsigned)u << 16); }
__device__ __forceinline__ float ldw(const void* p, size_t i, int f32) {
  return f32 ? ((const float*)p)[i] : b2f(((const bf16*)p)[i]);
}
__device__ __forceinline__ unsigned short f2bf(float f) {   // RNE fp32->bf16
  unsigned u = __float_as_uint(f);
  return (unsigned short)((u + 0x7FFFu + ((u >> 16) & 1u)) >> 16);
}
// 3-way bf16 split: a ~= h + m + l, |a-h-m-l| <= 2^-24 |a|
__device__ __forceinline__ void split3(float a, unsigned short& h, unsigned short& m,
                                       unsigned short& l) {
  h = f2bf(a);
  float r = a - u2f(h);
  m = f2bf(r);
  float s = r - u2f(m);
  l = f2bf(s);
}

// ---------------- diagnostic fill (ws_size too small) ----------------
__global__ __launch_bounds__(256) void fill_out_kernel(float* __restrict__ out, int n, float val) {
  int i = blockIdx.x * 256 + threadIdx.x;
  if (i < n) out[i] = val;
}

// ---------------- zero fill ----------------
__global__ __launch_bounds__(256) void zero_kernel(float* __restrict__ p, int n) {
  int i = blockIdx.x * 256 + threadIdx.x;
  if (i < n) p[i] = 0.f;
}

// ---------------- embeddings + shift-right ----------------
__global__ __launch_bounds__(256) void embed_kernel(
    const int* __restrict__ value, const int* __restrict__ depth, const int* __restrict__ pos,
    const void* __restrict__ sos, const void* __restrict__ tok_emb,
    const void* __restrict__ depth_emb, const void* __restrict__ pos_emb,
    float* __restrict__ x, int f32) {
  int i = blockIdx.x * 256 + threadIdx.x;
  if (i >= NTOK * NE) return;
  int e = i & (NE - 1);
  int bs = i >> 9;
  int s = bs & (NS - 1);
  int b = bs >> 12;
  float v;
  if (s == 0) {
    v = ldw(sos, e, f32);
  } else {
    int src = b * NS + (s - 1);
    float acc = ldw(tok_emb, (size_t)value[src] * NE + e, f32)
              + ldw(depth_emb, (size_t)depth[src] * NE + e, f32);
#pragma unroll
    for (int a = 0; a < NA; a++)
      acc += ldw(pos_emb, ((size_t)a * 65 + pos[src * NA + a]) * NE + e, f32);
    v = acc;
  }
  x[i] = v;
}

// ---------------- layer norm, one wave per row ----------------
__global__ __launch_bounds__(256) void ln_kernel(
    const float* __restrict__ x, const void* __restrict__ gam, const void* __restrict__ bet,
    size_t off, float* __restrict__ out, int f32) {
  int row = blockIdx.x * 4 + (threadIdx.x >> 6);
  int lane = threadIdx.x & 63;
  const float* xr = x + (size_t)row * NE;
  float v[8];
#pragma unroll
  for (int i = 0; i < 8; i++) v[i] = xr[lane + i * 64];
  float s = 0.f;
#pragma unroll
  for (int i = 0; i < 8; i++) s += v[i];
#pragma unroll
  for (int o = 32; o; o >>= 1) s += __shfl_xor(s, o);
  float m = s * (1.0f / NE);
  float sq = 0.f;
#pragma unroll
  for (int i = 0; i < 8; i++) { float d = v[i] - m; sq += d * d; }
#pragma unroll
  for (int o = 32; o; o >>= 1) sq += __shfl_xor(sq, o);
  float rs = 1.0f / sqrtf(sq * (1.0f / NE) + 1e-5f);
  float* orow = out + (size_t)row * NE;
#pragma unroll
  for (int i = 0; i < 8; i++) {
    int e = lane + i * 64;
    orow[e] = (v[i] - m) * rs * ldw(gam, off + e, f32) + ldw(bet, off + e, f32);
  }
}

// ---------------- fp32 vector GEMM core (bf16-input fallback path) ----------------
template <int ACT>
__device__ __forceinline__ void gemm_body(
    const float* __restrict__ A, const void* __restrict__ Bw, size_t bwoff, int ldb,
    const void* bias, size_t biasoff, const float* resid, float* C,
    int N, int K, int f32, int bm, int bn) {
  __shared__ float As[32][132];
  __shared__ float Bs[32][132];
  int tid = threadIdx.x;
  int ty = tid >> 4, tx = tid & 15;
  f2v acc2[8][4];
#pragma unroll
  for (int i = 0; i < 8; i++)
#pragma unroll
    for (int j = 0; j < 4; j++) acc2[i][j] = (f2v){0.f, 0.f};
  int arow = tid >> 1;
  int acol = (tid & 1) << 4;
  int brow = tid >> 3;
  int bcol = (tid & 7) << 4;

  const float* Aptr = A + (size_t)(bm + arow) * K + acol;
  float4 pa[4];
  float4 pb[4];
  uint4 pbu[2];
#pragma unroll
  for (int j = 0; j < 4; j++) pa[j] = *(const float4*)(Aptr + 4 * j);
  {
    size_t boff = bwoff + (size_t)brow * ldb + bn + bcol;
    if (f32) {
#pragma unroll
      for (int j = 0; j < 4; j++) pb[j] = *(const float4*)((const float*)Bw + boff + 4 * j);
    } else {
      pbu[0] = *(const uint4*)((const bf16*)Bw + boff);
      pbu[1] = *(const uint4*)((const bf16*)Bw + boff + 8);
    }
  }

  for (int k0 = 0; k0 < K; k0 += 32) {
#pragma unroll
    for (int j = 0; j < 4; j++) {
      As[acol + 4 * j + 0][arow] = pa[j].x;
      As[acol + 4 * j + 1][arow] = pa[j].y;
      As[acol + 4 * j + 2][arow] = pa[j].z;
      As[acol + 4 * j + 3][arow] = pa[j].w;
    }
    if (f32) {
#pragma unroll
      for (int j = 0; j < 4; j++) {
        Bs[brow][bcol + 4 * j + 0] = pb[j].x;
        Bs[brow][bcol + 4 * j + 1] = pb[j].y;
        Bs[brow][bcol + 4 * j + 2] = pb[j].z;
        Bs[brow][bcol + 4 * j + 3] = pb[j].w;
      }
    } else {
      union { uint4 u; unsigned short s[8]; } r0, r1;
      r0.u = pbu[0]; r1.u = pbu[1];
#pragma unroll
      for (int j = 0; j < 8; j++) Bs[brow][bcol + j] = u2f(r0.s[j]);
#pragma unroll
      for (int j = 0; j < 8; j++) Bs[brow][bcol + 8 + j] = u2f(r1.s[j]);
    }
    __syncthreads();
    if (k0 + 32 < K) {
#pragma unroll
      for (int j = 0; j < 4; j++) pa[j] = *(const float4*)(Aptr + k0 + 32 + 4 * j);
      size_t boff = bwoff + (size_t)(k0 + 32 + brow) * ldb + bn + bcol;
      if (f32) {
#pragma unroll
        for (int j = 0; j < 4; j++) pb[j] = *(const float4*)((const float*)Bw + boff + 4 * j);
      } else {
        pbu[0] = *(const uint4*)((const bf16*)Bw + boff);
        pbu[1] = *(const uint4*)((const bf16*)Bw + boff + 8);
      }
    }
#pragma unroll
    for (int kk = 0; kk < 32; kk++) {
      float4 aA = *(const float4*)&As[kk][ty << 3];
      float4 aB = *(const float4*)&As[kk][(ty << 3) + 4];
      float4 bA = *(const float4*)&Bs[kk][tx << 2];
      float4 bB = *(const float4*)&Bs[kk][64 + (tx << 2)];
      float av[8] = {aA.x, aA.y, aA.z, aA.w, aB.x, aB.y, aB.z, aB.w};
      f2v bv[4];
      bv[0] = (f2v){bA.x, bA.y};
      bv[1] = (f2v){bA.z, bA.w};
      bv[2] = (f2v){bB.x, bB.y};
      bv[3] = (f2v){bB.z, bB.w};
#pragma unroll
      for (int i = 0; i < 8; i++)
#pragma unroll
        for (int j = 0; j < 4; j++)
          acc2[i][j] += bv[j] * av[i];
    }
    __syncthreads();
  }
#pragma unroll
  for (int i = 0; i < 8; i++) {
    int row = bm + (ty << 3) + i;
    int c0 = bn + (tx << 2);
    int c1 = bn + 64 + (tx << 2);
    const float* ap = (const float*)&acc2[i][0];
    float o0[4], o1[4];
#pragma unroll
    for (int j = 0; j < 4; j++) { o0[j] = ap[j]; o1[j] = ap[4 + j]; }
    if (bias) {
#pragma unroll
      for (int j = 0; j < 4; j++) {
        o0[j] += ldw(bias, biasoff + c0 + j, f32);
        o1[j] += ldw(bias, biasoff + c1 + j, f32);
      }
    }
    if (ACT == 1) {
#pragma unroll
      for (int j = 0; j < 4; j++) {
        float t0 = 0.7978845608028654f * (o0[j] + 0.044715f * o0[j] * o0[j] * o0[j]);
        o0[j] = 0.5f * o0[j] * (1.0f + tanhf(t0));
        float t1 = 0.7978845608028654f * (o1[j] + 0.044715f * o1[j] * o1[j] * o1[j]);
        o1[j] = 0.5f * o1[j] * (1.0f + tanhf(t1));
      }
    }
    size_t p0 = (size_t)row * N + c0;
    size_t p1 = (size_t)row * N + c1;
    if (resid) {
      float4 r0 = *(const float4*)(resid + p0);
      float4 r1 = *(const float4*)(resid + p1);
      o0[0] += r0.x; o0[1] += r0.y; o0[2] += r0.z; o0[3] += r0.w;
      o1[0] += r1.x; o1[1] += r1.y; o1[2] += r1.z; o1[3] += r1.w;
    }
    *(float4*)(C + p0) = make_float4(o0[0], o0[1], o0[2], o0[3]);
    *(float4*)(C + p1) = make_float4(o1[0], o1[1], o1[2], o1[3]);
  }
}

template <int ACT>
__global__ __launch_bounds__(256) void gemm_kernel(
    const float* __restrict__ A, const void* __restrict__ Bw, size_t bwoff, int ldb,
    const void* bias, size_t biasoff, const float* resid, float* C,
    int N, int K, int f32) {
  gemm_body<ACT>(A, Bw, bwoff, ldb, bias, biasoff, resid, C, N, K,
                 f32, blockIdx.y << 7, blockIdx.x << 7);
}

__global__ __launch_bounds__(256) void gemm_qkv_kernel(
    const float* __restrict__ A,
    const void* __restrict__ Wq, const void* __restrict__ Wk, const void* __restrict__ Wv,
    size_t bwoff, float* __restrict__ Cq, float* __restrict__ Ck, float* __restrict__ Cv,
    int f32) {
  int sel = blockIdx.x >> 2;
  const void* Bw = (sel == 0) ? Wq : ((sel == 1) ? Wk : Wv);
  float* C = (sel == 0) ? Cq : ((sel == 1) ? Ck : Cv);
  gemm_body<0>(A, Bw, bwoff, NE, nullptr, 0, nullptr, C, NE, NE,
               f32, blockIdx.y << 7, (blockIdx.x & 3) << 7);
}

// ---------------- MFMA GEMM for fp32 A x fp32 W: 3-way bf16 splits, 6 products ----------------
// ROUND-7 MEASURED-BEST LAYOUT (do not re-swizzle without within-probe A/B):
// LDS [128][40] ushort per plane (61,440 B total); B staged Bx[n][k'] with chunk swizzle
// k' = k ^ (((n>>4)&3)<<3); frag read at chunk (lg^ni)&3 recovers k-chunk lg.
template <int ACT>
__device__ __forceinline__ void mfma_body(
    const float* __restrict__ A, const float* __restrict__ Bw, int ldb,
    const float* __restrict__ bias, const float* __restrict__ resid, float* __restrict__ C,
    int N, int K, int bm, int bn) {
  __shared__ unsigned short Ah[128][40];
  __shared__ unsigned short Am[128][40];
  __shared__ unsigned short Al[128][40];
  __shared__ unsigned short Bh[128][40];
  __shared__ unsigned short Bm[128][40];
  __shared__ unsigned short Bl[128][40];
  int t = threadIdx.x;
  int arow = t >> 1;
  int akc = (t & 1) << 4;
  const float* Ap = A + (size_t)(bm + arow) * K + akc;
  int bkr = t >> 3;
  int bcg = t & 7;
  const float* Bp = Bw + (size_t)bkr * ldb + bn + bcg * 16;
  int bkpos = bkr ^ ((bcg & 3) << 3);

  float4 pa[4], pb[4];
#pragma unroll
  for (int j = 0; j < 4; j++) pa[j] = *(const float4*)(Ap + 4 * j);
#pragma unroll
  for (int j = 0; j < 4; j++) pb[j] = *(const float4*)(Bp + 4 * j);

  int lane = t & 63;
  int wid = t >> 6;
  int wr = wid >> 1, wc = wid & 1;
  int lr = lane & 15, lg = lane >> 4;

  f32x4 acc[4][4];
#pragma unroll
  for (int i = 0; i < 4; i++)
#pragma unroll
    for (int j = 0; j < 4; j++) acc[i][j] = (f32x4){0.f, 0.f, 0.f, 0.f};

  for (int k0 = 0; k0 < K; k0 += 32) {
    {
      unsigned hs[8], ms[8], ls[8];
#pragma unroll
      for (int j = 0; j < 4; j++) {
        const float* pf = (const float*)&pa[j];
#pragma unroll
        for (int e = 0; e < 2; e++) {
          unsigned short h0, m0, l0, h1, m1, l1;
          split3(pf[2 * e], h0, m0, l0);
          split3(pf[2 * e + 1], h1, m1, l1);
          hs[2 * j + e] = (unsigned)h0 | ((unsigned)h1 << 16);
          ms[2 * j + e] = (unsigned)m0 | ((unsigned)m1 << 16);
          ls[2 * j + e] = (unsigned)l0 | ((unsigned)l1 << 16);
        }
      }
      *(uint4*)&Ah[arow][akc]     = make_uint4(hs[0], hs[1], hs[2], hs[3]);
      *(uint4*)&Ah[arow][akc + 8] = make_uint4(hs[4], hs[5], hs[6], hs[7]);
      *(uint4*)&Am[arow][akc]     = make_uint4(ms[0], ms[1], ms[2], ms[3]);
      *(uint4*)&Am[arow][akc + 8] = make_uint4(ms[4], ms[5], ms[6], ms[7]);
      *(uint4*)&Al[arow][akc]     = make_uint4(ls[0], ls[1], ls[2], ls[3]);
      *(uint4*)&Al[arow][akc + 8] = make_uint4(ls[4], ls[5], ls[6], ls[7]);
    }
    {
#pragma unroll
      for (int j = 0; j < 4; j++) {
        const float* pf = (const float*)&pb[j];
#pragma unroll
        for (int e = 0; e < 4; e++) {
          unsigned short h, m, l;
          split3(pf[e], h, m, l);
          int nn = bcg * 16 + 4 * j + e;
          Bh[nn][bkpos] = h;
          Bm[nn][bkpos] = m;
          Bl[nn][bkpos] = l;
        }
      }
    }
    __syncthreads();
    if (k0 + 32 < K) {
#pragma unroll
      for (int j = 0; j < 4; j++) pa[j] = *(const float4*)(Ap + k0 + 32 + 4 * j);
      const float* Bn = Bp + (size_t)(k0 + 32) * ldb;
#pragma unroll
      for (int j = 0; j < 4; j++) pb[j] = *(const float4*)(Bn + 4 * j);
    }
    bf16x8 fbh[4], fbm[4], fbl[4];
#pragma unroll
    for (int ni = 0; ni < 4; ni++) {
      int rb = wc * 64 + ni * 16 + lr;
      int cb = ((lg ^ ni) & 3) * 8;
      fbh[ni] = *(const bf16x8*)&Bh[rb][cb];
      fbm[ni] = *(const bf16x8*)&Bm[rb][cb];
      fbl[ni] = *(const bf16x8*)&Bl[rb][cb];
    }
#pragma unroll
    for (int mi = 0; mi < 4; mi++) {
      int ar = wr * 64 + mi * 16 + lr;
      bf16x8 fh = *(const bf16x8*)&Ah[ar][lg * 8];
      bf16x8 fm = *(const bf16x8*)&Am[ar][lg * 8];
      bf16x8 fl = *(const bf16x8*)&Al[ar][lg * 8];
#pragma unroll
      for (int ni = 0; ni < 4; ni++) {
        f32x4 a = acc[mi][ni];
        a = __builtin_amdgcn_mfma_f32_16x16x32_bf16(fh, fbh[ni], a, 0, 0, 0);
        a = __builtin_amdgcn_mfma_f32_16x16x32_bf16(fh, fbm[ni], a, 0, 0, 0);
        a = __builtin_amdgcn_mfma_f32_16x16x32_bf16(fm, fbh[ni], a, 0, 0, 0);
        a = __builtin_amdgcn_mfma_f32_16x16x32_bf16(fm, fbm[ni], a, 0, 0, 0);
        a = __builtin_amdgcn_mfma_f32_16x16x32_bf16(fh, fbl[ni], a, 0, 0, 0);
        a = __builtin_amdgcn_mfma_f32_16x16x32_bf16(fl, fbh[ni], a, 0, 0, 0);
        acc[mi][ni] = a;
      }
    }
    __syncthreads();
  }
#pragma unroll
  for (int mi = 0; mi < 4; mi++) {
#pragma unroll
    for (int ni = 0; ni < 4; ni++) {
      int col = bn + wc * 64 + ni * 16 + lr;
      int rbase = bm + wr * 64 + mi * 16 + lg * 4;
      float bv = bias ? bias[col] : 0.f;
      const float* av = (const float*)&acc[mi][ni];
#pragma unroll
      for (int r = 0; r < 4; r++) {
        float o = av[r] + bv;
        if (ACT == 1) {
          float t0 = 0.7978845608028654f * (o + 0.044715f * o * o * o);
          o = 0.5f * o * (1.0f + tanhf(t0));
        }
        size_t p = (size_t)(rbase + r) * N + col;
        if (resid) o += resid[p];
        C[p] = o;
      }
    }
  }
}

template <int ACT>
__global__ __launch_bounds__(256) void gemm_mfma_kernel(
    const float* __restrict__ A, const float* __restrict__ Bw, int ldb,
    const float* __restrict__ bias, const float* __restrict__ resid, float* __restrict__ C,
    int N, int K) {
  mfma_body<ACT>(A, Bw, ldb, bias, resid, C, N, K, blockIdx.y << 7, blockIdx.x << 7);
}

// fused q/k/v MFMA
__global__ __launch_bounds__(256) void gemm_qkv_mfma(
    const float* __restrict__ A, const float* __restrict__ Wq, const float* __restrict__ Wk,
    const float* __restrict__ Wv, size_t off,
    float* __restrict__ Cq, float* __restrict__ Ck, float* __restrict__ Cv) {
  int sel = blockIdx.x >> 2;
  const float* Bw = (sel == 0) ? Wq : ((sel == 1) ? Wk : Wv);
  float* C = (sel == 0) ? Cq : ((sel == 1) ? Ck : Cv);
  mfma_body<0>(A, Bw + off, NE, nullptr, nullptr, C, NE, NE,
               blockIdx.y << 7, (blockIdx.x & 3) << 7);
}

// ---------------- q transpose + fused rq: qT[b][h][d][n], rqd[b][h][n] ----------------
// rqd computed with the SAME 64-lane butterfly as the old rq_kernel -> bit-identical.
__global__ __launch_bounds__(256) void qt_kernel(const float* __restrict__ q, float* __restrict__ qT,
                                                 double* __restrict__ rqd) {
  __shared__ float tile[64][65];
  int bid = blockIdx.x;
  int st = bid & 63;
  int bh = bid >> 6;
  int b = bh >> 3, h = bh & 7;
  int s0 = st * 64;
  int t = threadIdx.x;
#pragma unroll
  for (int k = 0; k < 16; k++) {
    int idx = t + k * 256;
    int sl = idx >> 6, dl = idx & 63;
    tile[sl][dl] = q[(size_t)(b * NS + s0 + sl) * NE + h * ND + dl];
  }
  __syncthreads();
#pragma unroll
  for (int k = 0; k < 16; k++) {
    int idx = t + k * 256;
    int dl = idx >> 6, sl = idx & 63;
    qT[((size_t)bh * 64 + dl) * NS + s0 + sl] = tile[sl][dl];
  }
  int w = t >> 6, lane = t & 63;
#pragma unroll
  for (int i = 0; i < 16; i++) {
    int tok = w * 16 + i;
    double v = (double)tile[tok][lane];
    double ss = v * v;
#pragma unroll
    for (int o = 32; o; o >>= 1) ss += __shfl_xor(ss, o);
    if (lane == 0) rqd[((size_t)bh << 12) | (s0 + tok)] = 1.0 / (sqrt(ss) + 1e-8);
  }
}

// ---------------- normalized means in fp64 ----------------
__global__ __launch_bounds__(64) void mnd_kernel(const void* __restrict__ means,
                                                 double* __restrict__ mnd, int f32) {
  __shared__ double s[64];
  int vblk = blockIdx.x;
  int d = threadIdx.x;
  double m = (double)ldw(means, (size_t)vblk * ND + d, f32);
  s[d] = m * m;
  __syncthreads();
  for (int st = 32; st; st >>= 1) { if (d < st) s[d] += s[d + st]; __syncthreads(); }
  mnd[(size_t)vblk * ND + d] = m / (sqrt(s[0]) + 1e-8);
}

// ---------------- routing: fp64 dists (coalesced qT) + exact top-64 + fused cnt ----------------
__global__ __launch_bounds__(256) void route_kernel(
    const float* __restrict__ qT, const double* __restrict__ mnd,
    const double* __restrict__ rqd, int* __restrict__ idxout, float* __restrict__ cnt) {
  __shared__ unsigned long long keys[NS];
  __shared__ double mc[ND];
  __shared__ unsigned hist[256];
  __shared__ unsigned short cand[2][NS];
  __shared__ unsigned s_rem, s_cnt, s_sel, s_cc[2];
  int bid = blockIdx.x;
  int h = bid & 7;
  int b = (bid >> 3) & 3;
  int c = bid >> 5;
  int bhc = ((b * NH + h) * NC) + c;
  int t = threadIdx.x;
  if (t < ND) mc[t] = mnd[((size_t)h * NC + c) * ND + t];
  hist[t] = 0u;
  if (t == 0) { s_rem = NW; s_cnt = 0u; s_cc[0] = 0u; s_cc[1] = 0u; }
  __syncthreads();
  const float* qTb = qT + (size_t)(b * NH + h) * 64 * NS;
  const double* rqb = rqd + ((size_t)(b * NH + h) << 12);
  for (int i = 0; i < 16; i += 4) {
    int n0 = t + i * 256, n1 = n0 + 256, n2 = n0 + 512, n3 = n0 + 768;
    double a0 = 0.0, a1 = 0.0, a2 = 0.0, a3 = 0.0;
#pragma unroll 8
    for (int d = 0; d < 64; d++) {
      const float* row = qTb + (size_t)d * NS;
      double m = mc[d];
      a0 += (double)row[n0] * m;
      a1 += (double)row[n1] * m;
      a2 += (double)row[n2] * m;
      a3 += (double)row[n3] * m;
    }
    double dv[4] = {a0 * rqb[n0], a1 * rqb[n1], a2 * rqb[n2], a3 * rqb[n3]};
    int nn[4] = {n0, n1, n2, n3};
#pragma unroll
    for (int j = 0; j < 4; j++) {
      long long sb = __double_as_longlong(dv[j]);
      unsigned long long u = (unsigned long long)sb;
      u = (sb < 0) ? ~u : (u | 0x8000000000000000ULL);
      keys[nn[j]] = (u & 0xFFFFFFFFFFFFF000ULL) | (unsigned long long)(NS - 1 - nn[j]);
    }
  }
  __syncthreads();
  {
    unsigned lastd = 0xFFFFFFFFu, lcnt = 0u;
    for (int n = t; n < NS; n += 256) {
      unsigned d = (unsigned)(keys[n] >> 56);
      if (d == lastd) { lcnt++; }
      else { if (lcnt) atomicAdd(&hist[lastd], lcnt); lastd = d; lcnt = 1u; }
    }
    if (lcnt) atomicAdd(&hist[lastd], lcnt);
  }
  __syncthreads();
  if (t < 64) {
    unsigned h0 = hist[4 * t + 0], h1 = hist[4 * t + 1];
    unsigned h2 = hist[4 * t + 2], h3 = hist[4 * t + 3];
    hist[4 * t + 0] = 0u; hist[4 * t + 1] = 0u; hist[4 * t + 2] = 0u; hist[4 * t + 3] = 0u;
    unsigned t3 = h3, t2 = h2 + h3, t1 = h1 + t2, t0 = h0 + t1;
    unsigned s = t0;
#pragma unroll
    for (int off = 1; off < 64; off <<= 1) {
      unsigned v = __shfl_down(s, off);
      if (t + off < 64) s += v;
    }
    unsigned E = s - t0;
    unsigned rem = s_rem;
    unsigned sf0 = t0 + E, sf1 = t1 + E, sf2 = t2 + E, sf3 = t3 + E, sf4 = E;
    if (sf0 >= rem && sf1 < rem) { s_sel = 4u * t + 0u; s_rem = rem - sf1; }
    if (sf1 >= rem && sf2 < rem) { s_sel = 4u * t + 1u; s_rem = rem - sf2; }
    if (sf2 >= rem && sf3 < rem) { s_sel = 4u * t + 2u; s_rem = rem - sf3; }
    if (sf3 >= rem && sf4 < rem) { s_sel = 4u * t + 3u; s_rem = rem - sf4; }
  }
  __syncthreads();
  {
    unsigned sel = s_sel;
    for (int n = t; n < NS; n += 256) {
      unsigned d = (unsigned)(keys[n] >> 56);
      if (d > sel) {
        unsigned p = atomicAdd(&s_cnt, 1u);
        idxout[(size_t)bhc * NW + p] = n;
        atomicAdd(&cnt[(size_t)(b * NS + n) * NH + h], 1.0f);
      } else if (d == sel) {
        unsigned p = atomicAdd(&s_cc[0], 1u);
        cand[0][p] = (unsigned short)n;
      }
    }
  }
  __syncthreads();
  int cur = 0;
  for (int p = 6; p >= 0; p--) {
    int sh = p * 8;
    unsigned nc = s_cc[cur];
    for (unsigned i = t; i < nc; i += 256) {
      unsigned d = (unsigned)((keys[cand[cur][i]] >> sh) & 255ULL);
      atomicAdd(&hist[d], 1u);
    }
    __syncthreads();
    if (t < 64) {
      unsigned h0 = hist[4 * t + 0], h1 = hist[4 * t + 1];
      unsigned h2 = hist[4 * t + 2], h3 = hist[4 * t + 3];
      hist[4 * t + 0] = 0u; hist[4 * t + 1] = 0u; hist[4 * t + 2] = 0u; hist[4 * t + 3] = 0u;
      unsigned t3 = h3, t2 = h2 + h3, t1 = h1 + t2, t0 = h0 + t1;
      unsigned s = t0;
#pragma unroll
      for (int off = 1; off < 64; off <<= 1) {
        unsigned v = __shfl_down(s, off);
        if (t + off < 64) s += v;
      }
      unsigned E = s - t0;
      unsigned rem = s_rem;
      unsigned sf0 = t0 + E, sf1 = t1 + E, sf2 = t2 + E, sf3 = t3 + E, sf4 = E;
      if (sf0 >= rem && sf1 < rem) { s_sel = 4u * t + 0u; s_rem = rem - sf1; }
      if (sf1 >= rem && sf2 < rem) { s_sel = 4u * t + 1u; s_rem = rem - sf2; }
      if (sf2 >= rem && sf3 < rem) { s_sel = 4u * t + 2u; s_rem = rem - sf3; }
      if (sf3 >= rem && sf4 < rem) { s_sel = 4u * t + 3u; s_rem = rem - sf4; }
      if (t == 0) s_cc[cur ^ 1] = 0u;
    }
    __syncthreads();
    unsigned sel = s_sel;
    if (p == 0) {
      for (unsigned i = t; i < nc; i += 256) {
        unsigned n = cand[cur][i];
        unsigned d = (unsigned)(keys[n] & 255ULL);
        if (d >= sel) {
          unsigned pp = atomicAdd(&s_cnt, 1u);
          idxout[(size_t)bhc * NW + pp] = n;
          atomicAdd(&cnt[(size_t)(b * NS + n) * NH + h], 1.0f);
        }
      }
    } else {
      int nxt = cur ^ 1;
      for (unsigned i = t; i < nc; i += 256) {
        unsigned n = cand[cur][i];
        unsigned d = (unsigned)((keys[n] >> sh) & 255ULL);
        if (d > sel) {
          unsigned pp = atomicAdd(&s_cnt, 1u);
          idxout[(size_t)bhc * NW + pp] = n;
          atomicAdd(&cnt[(size_t)(b * NS + n) * NH + h], 1.0f);
        } else if (d == sel) {
          unsigned pp = atomicAdd(&s_cc[nxt], 1u);
          cand[nxt][pp] = (unsigned short)n;
        }
      }
      __syncthreads();
      cur = nxt;
    }
  }
}

// ---------------- bucket attention ----------------
__global__ __launch_bounds__(256) void attn_kernel(
    const float* __restrict__ q, const float* __restrict__ k, const float* __restrict__ v,
    const int* __restrict__ idxb, const int* __restrict__ value, const float* __restrict__ cnt,
    float* __restrict__ obuf) {
  __shared__ float qs[NW * (ND + 1)];
  __shared__ float ks[NW * (ND + 1)];
  __shared__ float sc[NW * (NW + 1)];
  __shared__ int idxs[NW];
  __shared__ float kmv[NW];
  __shared__ float cinv[NW];
  int bhc = blockIdx.x;
  int h = (bhc >> 6) & (NH - 1);
  int b = bhc >> 9;
  int t = threadIdx.x;
  if (t < NW) {
    int n = idxb[(size_t)bhc * NW + t];
    idxs[t] = n;
    kmv[t] = (value[b * NS + n] != 0) ? 1.f : 0.f;
    cinv[t] = 1.0f / fmaxf(cnt[(size_t)(b * NS + n) * NH + h], 1.0f);
  }
  __syncthreads();
  for (int p = t; p < NW * ND; p += 256) {
    int w = p >> 6, d = p & (ND - 1);
    size_t src = (size_t)(b * NS + idxs[w]) * NE + h * ND + d;
    qs[w * (ND + 1) + d] = q[src];
    ks[w * (ND + 1) + d] = k[src];
  }
  __syncthreads();
  for (int p = t; p < NW * NW; p += 256) {
    int w = p >> 6, x = p & (NW - 1);
    float dot = 0.f;
#pragma unroll 16
    for (int d = 0; d < ND; d++) dot += qs[w * (ND + 1) + d] * ks[x * (ND + 1) + d];
    bool allowed = (idxs[w] >= idxs[x]) && (kmv[x] != 0.f);
    sc[w * (NW + 1) + x] = allowed ? dot * 0.125f : -1e9f;
  }
  __syncthreads();
  if (t < NW) {
    float mx = -3.4e38f;
    for (int x = 0; x < NW; x++) mx = fmaxf(mx, sc[t * (NW + 1) + x]);
    float sum = 0.f;
    for (int x = 0; x < NW; x++) {
      float e = expf(sc[t * (NW + 1) + x] - mx);
      sc[t * (NW + 1) + x] = e;
      sum += e;
    }
    float inv = cinv[t] / sum;
    for (int x = 0; x < NW; x++) sc[t * (NW + 1) + x] *= inv;
  }
  for (int p = t; p < NW * ND; p += 256) {
    int w = p >> 6, d = p & (ND - 1);
    ks[w * (ND + 1) + d] = v[(size_t)(b * NS + idxs[w]) * NE + h * ND + d];
  }
  __syncthreads();
  for (int p = t; p < NW * ND; p += 256) {
    int w = p >> 6, d = p & (ND - 1);
    float o = 0.f;
#pragma unroll 16
    for (int x = 0; x < NW; x++) o += sc[w * (NW + 1) + x] * ks[x * (ND + 1) + d];
    qs[w * (ND + 1) + d] = o;
  }
  __syncthreads();
  for (int p = t; p < NW * ND; p += 256) {
    int w = p >> 6, d = p & (ND - 1);
    atomicAdd(&obuf[(size_t)(b * NS + idxs[w]) * NE + h * ND + d], qs[w * (ND + 1) + d]);
  }
}

// ---------------- head ----------------
__global__ __launch_bounds__(256) void head_kernel(
    const float* __restrict__ x, const void* __restrict__ hw, void* __restrict__ out, int f32) {
  int gw = (blockIdx.x * 256 + threadIdx.x) >> 6;
  int lane = threadIdx.x & 63;
  if (gw >= NTOK * NVOC) return;
  int row = gw / NVOC, vv = gw % NVOC;
  const float* xr = x + (size_t)row * NE;
  float acc = 0.f;
  for (int e = lane; e < NE; e += 64) acc += xr[e] * ldw(hw, (size_t)vv * NE + e, f32);
#pragma unroll
  for (int o = 32; o; o >>= 1) acc += __shfl_down(acc, o);
  if (lane == 0) {
    if (f32) ((float*)out)[(size_t)row * NVOC + vv] = acc;
    else ((bf16*)out)[(size_t)row * NVOC + vv] = __float2bfloat16(acc);
  }
}

extern "C" void kernel_launch(void* const* d_in, const int* in_sizes, int n_in,
                              void* d_out, int out_size, void* d_ws, size_t ws_size,
                              hipStream_t stream) {
  const int* value = (const int*)d_in[0];
  const int* depth = (const int*)d_in[1];
  const int* pos = (const int*)d_in[2];
  const void* sos = d_in[3];
  const void* tok_emb = d_in[4];
  const void* depth_emb = d_in[5];
  const void* pos_emb = d_in[6];
  const void* ln1_s = d_in[7];
  const void* ln1_b = d_in[8];
  const void* Wq = d_in[9];
  const void* Wk = d_in[10];
  const void* Wv = d_in[11];
  const void* Wo = d_in[12];
  const void* means = d_in[13];
  const void* ln2_s = d_in[14];
  const void* ln2_b = d_in[15];
  const void* W1 = d_in[16];
  const void* b1 = d_in[17];
  const void* W2 = d_in[18];
  const void* b2 = d_in[19];
  const void* head_w = d_in[20];
  (void)n_in;

  int f32 = (in_sizes[4] != 17408) ? 1 : 0;

  const size_t NX = (size_t)NTOK * NE;
  const size_t NEED = 170917896ULL;
  if (ws_size < NEED) {
    float val = (float)(unsigned)(ws_size >> 20) * 1000.0f;
    fill_out_kernel<<<(out_size + 255) / 256, 256, 0, stream>>>((float*)d_out, out_size, val);
    return;
  }

  float* xbuf = (float*)d_ws;
  float* hbuf = xbuf + NX;       // LN1 out / qT / attn accumulator (time-shared)
  float* qbuf = hbuf + NX;
  float* kbuf = qbuf + NX;
  float* vbuf = kbuf + NX;
  double* mndbuf = (double*)(vbuf + NX);
  double* rqdbuf = mndbuf + (size_t)NL * NH * NC * ND;
  float* cntbuf = (float*)(rqdbuf + (size_t)NTOK * NH);
  int* idxbuf = (int*)(cntbuf + (size_t)NTOK * NH);
  float* mid = kbuf;

  mnd_kernel<<<NL * NH * NC, 64, 0, stream>>>(means, mndbuf, f32);
  embed_kernel<<<(int)((NX + 255) / 256), 256, 0, stream>>>(
      value, depth, pos, sos, tok_emb, depth_emb, pos_emb, xbuf, f32);

  dim3 g512(NE / 128, NTOK / 128);
  dim3 gqkv(12, NTOK / 128);

  if (f32) {
    const float* Wqf = (const float*)Wq;
    const float* Wkf = (const float*)Wk;
    const float* Wvf = (const float*)Wv;
    const float* Wof = (const float*)Wo;
    const float* W1f = (const float*)W1;
    const float* W2f = (const float*)W2;
    const float* b1f = (const float*)b1;
    const float* b2f = (const float*)b2;
    for (int l = 0; l < NL; l++) {
      size_t o_w = (size_t)l * NE * NE;
      size_t o_w1 = (size_t)l * NE * NF;
      size_t o_w2 = (size_t)l * NF * NE;
      size_t o_e = (size_t)l * NE;
      size_t o_f = (size_t)l * NF;

      ln_kernel<<<NTOK / 4, 256, 0, stream>>>(xbuf, ln1_s, ln1_b, o_e, hbuf, 1);
      gemm_qkv_mfma<<<gqkv, 256, 0, stream>>>(hbuf, Wqf, Wkf, Wvf, o_w, qbuf, kbuf, vbuf);

      qt_kernel<<<NB * NH * 64, 256, 0, stream>>>(qbuf, hbuf, rqdbuf);
      zero_kernel<<<(NTOK * NH) / 256, 256, 0, stream>>>(cntbuf, NTOK * NH);
      route_kernel<<<NB * NH * NC, 256, 0, stream>>>(
          hbuf, mndbuf + (size_t)l * NH * NC * ND, rqdbuf, idxbuf, cntbuf);

      zero_kernel<<<(int)((NX + 255) / 256), 256, 0, stream>>>(hbuf, (int)NX);
      attn_kernel<<<NB * NH * NC, 256, 0, stream>>>(qbuf, kbuf, vbuf, idxbuf, value, cntbuf, hbuf);
      gemm_mfma_kernel<0><<<g512, 256, 0, stream>>>(hbuf, Wof + o_w, NE, nullptr, xbuf,
                                                    xbuf, NE, NE);

      ln_kernel<<<NTOK / 4, 256, 0, stream>>>(xbuf, ln2_s, ln2_b, o_e, qbuf, 1);
      for (int c = 0; c < 4; c++) {
        gemm_mfma_kernel<1><<<g512, 256, 0, stream>>>(
            qbuf, W1f + o_w1 + (size_t)c * 512, NF, b1f + o_f + (size_t)c * 512,
            nullptr, mid, 512, NE);
        gemm_mfma_kernel<0><<<g512, 256, 0, stream>>>(
            mid, W2f + o_w2 + (size_t)c * 512 * NE, NE,
            (c == 0) ? (b2f + o_e) : nullptr, xbuf, xbuf, NE, 512);
      }
    }
  } else {
    const int CH = 8192;
    dim3 gqkvv(12, NTOK / 128);
    dim3 gW1(NF / 128, CH / 128);
    dim3 gW2(NE / 128, CH / 128);
    for (int l = 0; l < NL; l++) {
      size_t o_w = (size_t)l * NE * NE;
      size_t o_w1 = (size_t)l * NE * NF;
      size_t o_w2 = (size_t)l * NF * NE;
      size_t o_e = (size_t)l * NE;
      size_t o_f = (size_t)l * NF;

      ln_kernel<<<NTOK / 4, 256, 0, stream>>>(xbuf, ln1_s, ln1_b, o_e, hbuf, 0);
      gemm_qkv_kernel<<<gqkvv, 256, 0, stream>>>(hbuf, Wq, Wk, Wv, o_w, qbuf, kbuf, vbuf, 0);

      qt_kernel<<<NB * NH * 64, 256, 0, stream>>>(qbuf, hbuf, rqdbuf);
      zero_kernel<<<(NTOK * NH) / 256, 256, 0, stream>>>(cntbuf, NTOK * NH);
      route_kernel<<<NB * NH * NC, 256, 0, stream>>>(
          hbuf, mndbuf + (size_t)l * NH * NC * ND, rqdbuf, idxbuf, cntbuf);

      zero_kernel<<<(int)((NX + 255) / 256), 256, 0, stream>>>(hbuf, (int)NX);
      attn_kernel<<<NB * NH * NC, 256, 0, stream>>>(qbuf, kbuf, vbuf, idxbuf, value, cntbuf, hbuf);
      gemm_kernel<0><<<g512, 256, 0, stream>>>(hbuf, Wo, o_w, NE, nullptr, 0, xbuf,
                                               xbuf, NE, NE, 0);

      ln_kernel<<<NTOK / 4, 256, 0, stream>>>(xbuf, ln2_s, ln2_b, o_e, qbuf, 0);
      for (int ch = 0; ch < NTOK / CH; ch++) {
        const float* hch = qbuf + (size_t)ch * CH * NE;
        float* xch = xbuf + (size_t)ch * CH * NE;
        gemm_kernel<1><<<gW1, 256, 0, stream>>>(hch, W1, o_w1, NF, b1, o_f, nullptr,
                                                mid, NF, NE, 0);
        gemm_kernel<0><<<gW2, 256, 0, stream>>>(mid, W2, o_w2, NE, b2, o_e, xch,
                                                xch, NE, NF, 0);
      }
    }
  }

  head_kernel<<<(NTOK * NVOC * 64 + 255) / 256, 256, 0, stream>>>(xbuf, head_w, d_out, f32);
}

// Round 11
// 3972.448 us; speedup vs baseline: 1.5077x; 1.2170x over previous
//
#include <hip/hip_runtime.h>
#include <hip/hip_bf16.h>
#include <math.h>

typedef __hip_bfloat16 bf16;
typedef __attribute__((ext_vector_type(2))) float f2v;
typedef __attribute__((ext_vector_type(8))) short bf16x8;
typedef __attribute__((ext_vector_type(4))) float f32x4;

#define NB 4
#define NS 4096
#define NE 512
#define NH 8
#define NL 4
#define NA 3
#define ND 64
#define NC 64
#define NW 64
#define NF 2048
#define NVOC 17
#define NTOK (NB * NS)   // 16384

__device__ __forceinline__ float b2f(bf16 v) { return __bfloat162float(v); }
__device__ __forceinline__ float u2f(unsigned short u) { return __uint_as_float((unsigned)u << 16); }
__device__ __forceinline__ float ldw(const void* p, size_t i, int f32) {
  return f32 ? ((const float*)p)[i] : b2f(((const bf16*)p)[i]);
}
__device__ __forceinline__ unsigned short f2bf(float f) {   // RNE fp32->bf16
  unsigned u = __float_as_uint(f);
  return (unsigned short)((u + 0x7FFFu + ((u >> 16) & 1u)) >> 16);
}
// 3-way bf16 split: a ~= h + m + l, |a-h-m-l| <= 2^-24 |a|
__device__ __forceinline__ void split3(float a, unsigned short& h, unsigned short& m,
                                       unsigned short& l) {
  h = f2bf(a);
  float r = a - u2f(h);
  m = f2bf(r);
  float s = r - u2f(m);
  l = f2bf(s);
}

// ---------------- diagnostic fill (ws_size too small) ----------------
__global__ __launch_bounds__(256) void fill_out_kernel(float* __restrict__ out, int n, float val) {
  int i = blockIdx.x * 256 + threadIdx.x;
  if (i < n) out[i] = val;
}

// ---------------- zero fill ----------------
__global__ __launch_bounds__(256) void zero_kernel(float* __restrict__ p, int n) {
  int i = blockIdx.x * 256 + threadIdx.x;
  if (i < n) p[i] = 0.f;
}

// ---------------- embeddings + shift-right ----------------
__global__ __launch_bounds__(256) void embed_kernel(
    const int* __restrict__ value, const int* __restrict__ depth, const int* __restrict__ pos,
    const void* __restrict__ sos, const void* __restrict__ tok_emb,
    const void* __restrict__ depth_emb, const void* __restrict__ pos_emb,
    float* __restrict__ x, int f32) {
  int i = blockIdx.x * 256 + threadIdx.x;
  if (i >= NTOK * NE) return;
  int e = i & (NE - 1);
  int bs = i >> 9;
  int s = bs & (NS - 1);
  int b = bs >> 12;
  float v;
  if (s == 0) {
    v = ldw(sos, e, f32);
  } else {
    int src = b * NS + (s - 1);
    float acc = ldw(tok_emb, (size_t)value[src] * NE + e, f32)
              + ldw(depth_emb, (size_t)depth[src] * NE + e, f32);
#pragma unroll
    for (int a = 0; a < NA; a++)
      acc += ldw(pos_emb, ((size_t)a * 65 + pos[src * NA + a]) * NE + e, f32);
    v = acc;
  }
  x[i] = v;
}

// ---------------- layer norm, one wave per row ----------------
__global__ __launch_bounds__(256) void ln_kernel(
    const float* __restrict__ x, const void* __restrict__ gam, const void* __restrict__ bet,
    size_t off, float* __restrict__ out, int f32) {
  int row = blockIdx.x * 4 + (threadIdx.x >> 6);
  int lane = threadIdx.x & 63;
  const float* xr = x + (size_t)row * NE;
  float v[8];
#pragma unroll
  for (int i = 0; i < 8; i++) v[i] = xr[lane + i * 64];
  float s = 0.f;
#pragma unroll
  for (int i = 0; i < 8; i++) s += v[i];
#pragma unroll
  for (int o = 32; o; o >>= 1) s += __shfl_xor(s, o);
  float m = s * (1.0f / NE);
  float sq = 0.f;
#pragma unroll
  for (int i = 0; i < 8; i++) { float d = v[i] - m; sq += d * d; }
#pragma unroll
  for (int o = 32; o; o >>= 1) sq += __shfl_xor(sq, o);
  float rs = 1.0f / sqrtf(sq * (1.0f / NE) + 1e-5f);
  float* orow = out + (size_t)row * NE;
#pragma unroll
  for (int i = 0; i < 8; i++) {
    int e = lane + i * 64;
    orow[e] = (v[i] - m) * rs * ldw(gam, off + e, f32) + ldw(bet, off + e, f32);
  }
}

// ---------------- fp32 vector GEMM core (bf16-input fallback path) ----------------
template <int ACT>
__device__ __forceinline__ void gemm_body(
    const float* __restrict__ A, const void* __restrict__ Bw, size_t bwoff, int ldb,
    const void* bias, size_t biasoff, const float* resid, float* C,
    int N, int K, int f32, int bm, int bn) {
  __shared__ float As[32][132];
  __shared__ float Bs[32][132];
  int tid = threadIdx.x;
  int ty = tid >> 4, tx = tid & 15;
  f2v acc2[8][4];
#pragma unroll
  for (int i = 0; i < 8; i++)
#pragma unroll
    for (int j = 0; j < 4; j++) acc2[i][j] = (f2v){0.f, 0.f};
  int arow = tid >> 1;
  int acol = (tid & 1) << 4;
  int brow = tid >> 3;
  int bcol = (tid & 7) << 4;

  const float* Aptr = A + (size_t)(bm + arow) * K + acol;
  float4 pa[4];
  float4 pb[4];
  uint4 pbu[2];
#pragma unroll
  for (int j = 0; j < 4; j++) pa[j] = *(const float4*)(Aptr + 4 * j);
  {
    size_t boff = bwoff + (size_t)brow * ldb + bn + bcol;
    if (f32) {
#pragma unroll
      for (int j = 0; j < 4; j++) pb[j] = *(const float4*)((const float*)Bw + boff + 4 * j);
    } else {
      pbu[0] = *(const uint4*)((const bf16*)Bw + boff);
      pbu[1] = *(const uint4*)((const bf16*)Bw + boff + 8);
    }
  }

  for (int k0 = 0; k0 < K; k0 += 32) {
#pragma unroll
    for (int j = 0; j < 4; j++) {
      As[acol + 4 * j + 0][arow] = pa[j].x;
      As[acol + 4 * j + 1][arow] = pa[j].y;
      As[acol + 4 * j + 2][arow] = pa[j].z;
      As[acol + 4 * j + 3][arow] = pa[j].w;
    }
    if (f32) {
#pragma unroll
      for (int j = 0; j < 4; j++) {
        Bs[brow][bcol + 4 * j + 0] = pb[j].x;
        Bs[brow][bcol + 4 * j + 1] = pb[j].y;
        Bs[brow][bcol + 4 * j + 2] = pb[j].z;
        Bs[brow][bcol + 4 * j + 3] = pb[j].w;
      }
    } else {
      union { uint4 u; unsigned short s[8]; } r0, r1;
      r0.u = pbu[0]; r1.u = pbu[1];
#pragma unroll
      for (int j = 0; j < 8; j++) Bs[brow][bcol + j] = u2f(r0.s[j]);
#pragma unroll
      for (int j = 0; j < 8; j++) Bs[brow][bcol + 8 + j] = u2f(r1.s[j]);
    }
    __syncthreads();
    if (k0 + 32 < K) {
#pragma unroll
      for (int j = 0; j < 4; j++) pa[j] = *(const float4*)(Aptr + k0 + 32 + 4 * j);
      size_t boff = bwoff + (size_t)(k0 + 32 + brow) * ldb + bn + bcol;
      if (f32) {
#pragma unroll
        for (int j = 0; j < 4; j++) pb[j] = *(const float4*)((const float*)Bw + boff + 4 * j);
      } else {
        pbu[0] = *(const uint4*)((const bf16*)Bw + boff);
        pbu[1] = *(const uint4*)((const bf16*)Bw + boff + 8);
      }
    }
#pragma unroll
    for (int kk = 0; kk < 32; kk++) {
      float4 aA = *(const float4*)&As[kk][ty << 3];
      float4 aB = *(const float4*)&As[kk][(ty << 3) + 4];
      float4 bA = *(const float4*)&Bs[kk][tx << 2];
      float4 bB = *(const float4*)&Bs[kk][64 + (tx << 2)];
      float av[8] = {aA.x, aA.y, aA.z, aA.w, aB.x, aB.y, aB.z, aB.w};
      f2v bv[4];
      bv[0] = (f2v){bA.x, bA.y};
      bv[1] = (f2v){bA.z, bA.w};
      bv[2] = (f2v){bB.x, bB.y};
      bv[3] = (f2v){bB.z, bB.w};
#pragma unroll
      for (int i = 0; i < 8; i++)
#pragma unroll
        for (int j = 0; j < 4; j++)
          acc2[i][j] += bv[j] * av[i];
    }
    __syncthreads();
  }
#pragma unroll
  for (int i = 0; i < 8; i++) {
    int row = bm + (ty << 3) + i;
    int c0 = bn + (tx << 2);
    int c1 = bn + 64 + (tx << 2);
    const float* ap = (const float*)&acc2[i][0];
    float o0[4], o1[4];
#pragma unroll
    for (int j = 0; j < 4; j++) { o0[j] = ap[j]; o1[j] = ap[4 + j]; }
    if (bias) {
#pragma unroll
      for (int j = 0; j < 4; j++) {
        o0[j] += ldw(bias, biasoff + c0 + j, f32);
        o1[j] += ldw(bias, biasoff + c1 + j, f32);
      }
    }
    if (ACT == 1) {
#pragma unroll
      for (int j = 0; j < 4; j++) {
        float t0 = 0.7978845608028654f * (o0[j] + 0.044715f * o0[j] * o0[j] * o0[j]);
        o0[j] = 0.5f * o0[j] * (1.0f + tanhf(t0));
        float t1 = 0.7978845608028654f * (o1[j] + 0.044715f * o1[j] * o1[j] * o1[j]);
        o1[j] = 0.5f * o1[j] * (1.0f + tanhf(t1));
      }
    }
    size_t p0 = (size_t)row * N + c0;
    size_t p1 = (size_t)row * N + c1;
    if (resid) {
      float4 r0 = *(const float4*)(resid + p0);
      float4 r1 = *(const float4*)(resid + p1);
      o0[0] += r0.x; o0[1] += r0.y; o0[2] += r0.z; o0[3] += r0.w;
      o1[0] += r1.x; o1[1] += r1.y; o1[2] += r1.z; o1[3] += r1.w;
    }
    *(float4*)(C + p0) = make_float4(o0[0], o0[1], o0[2], o0[3]);
    *(float4*)(C + p1) = make_float4(o1[0], o1[1], o1[2], o1[3]);
  }
}

template <int ACT>
__global__ __launch_bounds__(256) void gemm_kernel(
    const float* __restrict__ A, const void* __restrict__ Bw, size_t bwoff, int ldb,
    const void* bias, size_t biasoff, const float* resid, float* C,
    int N, int K, int f32) {
  gemm_body<ACT>(A, Bw, bwoff, ldb, bias, biasoff, resid, C, N, K,
                 f32, blockIdx.y << 7, blockIdx.x << 7);
}

__global__ __launch_bounds__(256) void gemm_qkv_kernel(
    const float* __restrict__ A,
    const void* __restrict__ Wq, const void* __restrict__ Wk, const void* __restrict__ Wv,
    size_t bwoff, float* __restrict__ Cq, float* __restrict__ Ck, float* __restrict__ Cv,
    int f32) {
  int sel = blockIdx.x >> 2;
  const void* Bw = (sel == 0) ? Wq : ((sel == 1) ? Wk : Wv);
  float* C = (sel == 0) ? Cq : ((sel == 1) ? Ck : Cv);
  gemm_body<0>(A, Bw, bwoff, NE, nullptr, 0, nullptr, C, NE, NE,
               f32, blockIdx.y << 7, (blockIdx.x & 3) << 7);
}

// ---------------- MFMA GEMM for fp32 A x fp32 W ----------------
// FULL=1: 3-way splits, 6 products (hh,hm,mh,mm,hl,lh) ~2^-24 error. Used for q only.
// FULL=0: 2-way splits, 3 products (hh,hm,mh) ~2^-18 error. Used for k,v,Wo,W1,W2.
//   FULL=0 drops the l-planes: LDS 4 planes (41 KB -> 3 blocks/CU), half the MFMAs.
// Layout = round-7 measured best: [128][40] planes; B staged Bx[n][k'] with chunk
// swizzle k' = k ^ (((n>>4)&3)<<3); frag read at chunk (lg^ni)&3 recovers k-chunk lg.
template <int ACT, int FULL>
__device__ __forceinline__ void mfma_body(
    const float* __restrict__ A, const float* __restrict__ Bw, int ldb,
    const float* __restrict__ bias, const float* __restrict__ resid, float* __restrict__ C,
    int N, int K, int bm, int bn) {
  __shared__ unsigned short Ah[128][40];
  __shared__ unsigned short Am[128][40];
  __shared__ unsigned short Al[FULL ? 128 : 1][40];
  __shared__ unsigned short Bh[128][40];
  __shared__ unsigned short Bm[128][40];
  __shared__ unsigned short Bl[FULL ? 128 : 1][40];
  int t = threadIdx.x;
  int arow = t >> 1;
  int akc = (t & 1) << 4;
  const float* Ap = A + (size_t)(bm + arow) * K + akc;
  int bkr = t >> 3;
  int bcg = t & 7;
  const float* Bp = Bw + (size_t)bkr * ldb + bn + bcg * 16;
  int bkpos = bkr ^ ((bcg & 3) << 3);

  float4 pa[4], pb[4];
#pragma unroll
  for (int j = 0; j < 4; j++) pa[j] = *(const float4*)(Ap + 4 * j);
#pragma unroll
  for (int j = 0; j < 4; j++) pb[j] = *(const float4*)(Bp + 4 * j);

  int lane = t & 63;
  int wid = t >> 6;
  int wr = wid >> 1, wc = wid & 1;
  int lr = lane & 15, lg = lane >> 4;

  f32x4 acc[4][4];
#pragma unroll
  for (int i = 0; i < 4; i++)
#pragma unroll
    for (int j = 0; j < 4; j++) acc[i][j] = (f32x4){0.f, 0.f, 0.f, 0.f};

  for (int k0 = 0; k0 < K; k0 += 32) {
    {
      unsigned hs[8], ms[8], ls[8];
#pragma unroll
      for (int j = 0; j < 4; j++) {
        const float* pf = (const float*)&pa[j];
#pragma unroll
        for (int e = 0; e < 2; e++) {
          float a0 = pf[2 * e], a1 = pf[2 * e + 1];
          unsigned short h0 = f2bf(a0), h1 = f2bf(a1);
          float r0 = a0 - u2f(h0), r1 = a1 - u2f(h1);
          unsigned short m0 = f2bf(r0), m1 = f2bf(r1);
          hs[2 * j + e] = (unsigned)h0 | ((unsigned)h1 << 16);
          ms[2 * j + e] = (unsigned)m0 | ((unsigned)m1 << 16);
          if (FULL) {
            float s0 = r0 - u2f(m0), s1 = r1 - u2f(m1);
            unsigned short l0 = f2bf(s0), l1 = f2bf(s1);
            ls[2 * j + e] = (unsigned)l0 | ((unsigned)l1 << 16);
          }
        }
      }
      *(uint4*)&Ah[arow][akc]     = make_uint4(hs[0], hs[1], hs[2], hs[3]);
      *(uint4*)&Ah[arow][akc + 8] = make_uint4(hs[4], hs[5], hs[6], hs[7]);
      *(uint4*)&Am[arow][akc]     = make_uint4(ms[0], ms[1], ms[2], ms[3]);
      *(uint4*)&Am[arow][akc + 8] = make_uint4(ms[4], ms[5], ms[6], ms[7]);
      if (FULL) {
        *(uint4*)&Al[arow][akc]     = make_uint4(ls[0], ls[1], ls[2], ls[3]);
        *(uint4*)&Al[arow][akc + 8] = make_uint4(ls[4], ls[5], ls[6], ls[7]);
      }
    }
    {
#pragma unroll
      for (int j = 0; j < 4; j++) {
        const float* pf = (const float*)&pb[j];
#pragma unroll
        for (int e = 0; e < 4; e++) {
          float a = pf[e];
          unsigned short h = f2bf(a);
          float r = a - u2f(h);
          unsigned short m = f2bf(r);
          int nn = bcg * 16 + 4 * j + e;
          Bh[nn][bkpos] = h;
          Bm[nn][bkpos] = m;
          if (FULL) {
            float s = r - u2f(m);
            Bl[nn][bkpos] = f2bf(s);
          }
        }
      }
    }
    __syncthreads();
    if (k0 + 32 < K) {
#pragma unroll
      for (int j = 0; j < 4; j++) pa[j] = *(const float4*)(Ap + k0 + 32 + 4 * j);
      const float* Bn = Bp + (size_t)(k0 + 32) * ldb;
#pragma unroll
      for (int j = 0; j < 4; j++) pb[j] = *(const float4*)(Bn + 4 * j);
    }
    bf16x8 fbh[4], fbm[4], fbl[4];
#pragma unroll
    for (int ni = 0; ni < 4; ni++) {
      int rb = wc * 64 + ni * 16 + lr;
      int cb = ((lg ^ ni) & 3) * 8;
      fbh[ni] = *(const bf16x8*)&Bh[rb][cb];
      fbm[ni] = *(const bf16x8*)&Bm[rb][cb];
      if (FULL) fbl[ni] = *(const bf16x8*)&Bl[rb][cb];
    }
#pragma unroll
    for (int mi = 0; mi < 4; mi++) {
      int ar = wr * 64 + mi * 16 + lr;
      bf16x8 fh = *(const bf16x8*)&Ah[ar][lg * 8];
      bf16x8 fm = *(const bf16x8*)&Am[ar][lg * 8];
      bf16x8 fl;
      if (FULL) fl = *(const bf16x8*)&Al[ar][lg * 8];
#pragma unroll
      for (int ni = 0; ni < 4; ni++) {
        f32x4 a = acc[mi][ni];
        a = __builtin_amdgcn_mfma_f32_16x16x32_bf16(fh, fbh[ni], a, 0, 0, 0);
        a = __builtin_amdgcn_mfma_f32_16x16x32_bf16(fh, fbm[ni], a, 0, 0, 0);
        a = __builtin_amdgcn_mfma_f32_16x16x32_bf16(fm, fbh[ni], a, 0, 0, 0);
        if (FULL) {
          a = __builtin_amdgcn_mfma_f32_16x16x32_bf16(fm, fbm[ni], a, 0, 0, 0);
          a = __builtin_amdgcn_mfma_f32_16x16x32_bf16(fh, fbl[ni], a, 0, 0, 0);
          a = __builtin_amdgcn_mfma_f32_16x16x32_bf16(fl, fbh[ni], a, 0, 0, 0);
        }
        acc[mi][ni] = a;
      }
    }
    __syncthreads();
  }
#pragma unroll
  for (int mi = 0; mi < 4; mi++) {
#pragma unroll
    for (int ni = 0; ni < 4; ni++) {
      int col = bn + wc * 64 + ni * 16 + lr;
      int rbase = bm + wr * 64 + mi * 16 + lg * 4;
      float bv = bias ? bias[col] : 0.f;
      const float* av = (const float*)&acc[mi][ni];
#pragma unroll
      for (int r = 0; r < 4; r++) {
        float o = av[r] + bv;
        if (ACT == 1) {
          float t0 = 0.7978845608028654f * (o + 0.044715f * o * o * o);
          o = 0.5f * o * (1.0f + tanhf(t0));
        }
        size_t p = (size_t)(rbase + r) * N + col;
        if (resid) o += resid[p];
        C[p] = o;
      }
    }
  }
}

template <int ACT, int FULL>
__global__ __launch_bounds__(256) void gemm_mfma_kernel(
    const float* __restrict__ A, const float* __restrict__ Bw, int ldb,
    const float* __restrict__ bias, const float* __restrict__ resid, float* __restrict__ C,
    int N, int K) {
  mfma_body<ACT, FULL>(A, Bw, ldb, bias, resid, C, N, K, blockIdx.y << 7, blockIdx.x << 7);
}

// fused k/v MFMA (3-product): blockIdx.x in [0,8): sel = x>>2, col block x&3
__global__ __launch_bounds__(256) void gemm_kv_mfma(
    const float* __restrict__ A, const float* __restrict__ Wk, const float* __restrict__ Wv,
    size_t off, float* __restrict__ Ck, float* __restrict__ Cv) {
  int sel = blockIdx.x >> 2;
  const float* Bw = sel ? Wv : Wk;
  float* C = sel ? Cv : Ck;
  mfma_body<0, 0>(A, Bw + off, NE, nullptr, nullptr, C, NE, NE,
                  blockIdx.y << 7, (blockIdx.x & 3) << 7);
}

// ---------------- q transpose + fused rq: qT[b][h][d][n], rqd[b][h][n] ----------------
__global__ __launch_bounds__(256) void qt_kernel(const float* __restrict__ q, float* __restrict__ qT,
                                                 double* __restrict__ rqd) {
  __shared__ float tile[64][65];
  int bid = blockIdx.x;
  int st = bid & 63;
  int bh = bid >> 6;
  int b = bh >> 3, h = bh & 7;
  int s0 = st * 64;
  int t = threadIdx.x;
#pragma unroll
  for (int k = 0; k < 16; k++) {
    int idx = t + k * 256;
    int sl = idx >> 6, dl = idx & 63;
    tile[sl][dl] = q[(size_t)(b * NS + s0 + sl) * NE + h * ND + dl];
  }
  __syncthreads();
#pragma unroll
  for (int k = 0; k < 16; k++) {
    int idx = t + k * 256;
    int dl = idx >> 6, sl = idx & 63;
    qT[((size_t)bh * 64 + dl) * NS + s0 + sl] = tile[sl][dl];
  }
  int w = t >> 6, lane = t & 63;
#pragma unroll
  for (int i = 0; i < 16; i++) {
    int tok = w * 16 + i;
    double v = (double)tile[tok][lane];
    double ss = v * v;
#pragma unroll
    for (int o = 32; o; o >>= 1) ss += __shfl_xor(ss, o);
    if (lane == 0) rqd[((size_t)bh << 12) | (s0 + tok)] = 1.0 / (sqrt(ss) + 1e-8);
  }
}

// ---------------- normalized means in fp64 ----------------
__global__ __launch_bounds__(64) void mnd_kernel(const void* __restrict__ means,
                                                 double* __restrict__ mnd, int f32) {
  __shared__ double s[64];
  int vblk = blockIdx.x;
  int d = threadIdx.x;
  double m = (double)ldw(means, (size_t)vblk * ND + d, f32);
  s[d] = m * m;
  __syncthreads();
  for (int st = 32; st; st >>= 1) { if (d < st) s[d] += s[d + st]; __syncthreads(); }
  mnd[(size_t)vblk * ND + d] = m / (sqrt(s[0]) + 1e-8);
}

// ---------------- routing: fp64 dists (coalesced qT) + exact top-64 + fused cnt ----------------
__global__ __launch_bounds__(256) void route_kernel(
    const float* __restrict__ qT, const double* __restrict__ mnd,
    const double* __restrict__ rqd, int* __restrict__ idxout, float* __restrict__ cnt) {
  __shared__ unsigned long long keys[NS];
  __shared__ double mc[ND];
  __shared__ unsigned hist[256];
  __shared__ unsigned short cand[2][NS];
  __shared__ unsigned s_rem, s_cnt, s_sel, s_cc[2];
  int bid = blockIdx.x;
  int h = bid & 7;
  int b = (bid >> 3) & 3;
  int c = bid >> 5;
  int bhc = ((b * NH + h) * NC) + c;
  int t = threadIdx.x;
  if (t < ND) mc[t] = mnd[((size_t)h * NC + c) * ND + t];
  hist[t] = 0u;
  if (t == 0) { s_rem = NW; s_cnt = 0u; s_cc[0] = 0u; s_cc[1] = 0u; }
  __syncthreads();
  const float* qTb = qT + (size_t)(b * NH + h) * 64 * NS;
  const double* rqb = rqd + ((size_t)(b * NH + h) << 12);
  for (int i = 0; i < 16; i += 4) {
    int n0 = t + i * 256, n1 = n0 + 256, n2 = n0 + 512, n3 = n0 + 768;
    double a0 = 0.0, a1 = 0.0, a2 = 0.0, a3 = 0.0;
#pragma unroll 8
    for (int d = 0; d < 64; d++) {
      const float* row = qTb + (size_t)d * NS;
      double m = mc[d];
      a0 += (double)row[n0] * m;
      a1 += (double)row[n1] * m;
      a2 += (double)row[n2] * m;
      a3 += (double)row[n3] * m;
    }
    double dv[4] = {a0 * rqb[n0], a1 * rqb[n1], a2 * rqb[n2], a3 * rqb[n3]};
    int nn[4] = {n0, n1, n2, n3};
#pragma unroll
    for (int j = 0; j < 4; j++) {
      long long sb = __double_as_longlong(dv[j]);
      unsigned long long u = (unsigned long long)sb;
      u = (sb < 0) ? ~u : (u | 0x8000000000000000ULL);
      keys[nn[j]] = (u & 0xFFFFFFFFFFFFF000ULL) | (unsigned long long)(NS - 1 - nn[j]);
    }
  }
  __syncthreads();
  {
    unsigned lastd = 0xFFFFFFFFu, lcnt = 0u;
    for (int n = t; n < NS; n += 256) {
      unsigned d = (unsigned)(keys[n] >> 56);
      if (d == lastd) { lcnt++; }
      else { if (lcnt) atomicAdd(&hist[lastd], lcnt); lastd = d; lcnt = 1u; }
    }
    if (lcnt) atomicAdd(&hist[lastd], lcnt);
  }
  __syncthreads();
  if (t < 64) {
    unsigned h0 = hist[4 * t + 0], h1 = hist[4 * t + 1];
    unsigned h2 = hist[4 * t + 2], h3 = hist[4 * t + 3];
    hist[4 * t + 0] = 0u; hist[4 * t + 1] = 0u; hist[4 * t + 2] = 0u; hist[4 * t + 3] = 0u;
    unsigned t3 = h3, t2 = h2 + h3, t1 = h1 + t2, t0 = h0 + t1;
    unsigned s = t0;
#pragma unroll
    for (int off = 1; off < 64; off <<= 1) {
      unsigned v = __shfl_down(s, off);
      if (t + off < 64) s += v;
    }
    unsigned E = s - t0;
    unsigned rem = s_rem;
    unsigned sf0 = t0 + E, sf1 = t1 + E, sf2 = t2 + E, sf3 = t3 + E, sf4 = E;
    if (sf0 >= rem && sf1 < rem) { s_sel = 4u * t + 0u; s_rem = rem - sf1; }
    if (sf1 >= rem && sf2 < rem) { s_sel = 4u * t + 1u; s_rem = rem - sf2; }
    if (sf2 >= rem && sf3 < rem) { s_sel = 4u * t + 2u; s_rem = rem - sf3; }
    if (sf3 >= rem && sf4 < rem) { s_sel = 4u * t + 3u; s_rem = rem - sf4; }
  }
  __syncthreads();
  {
    unsigned sel = s_sel;
    for (int n = t; n < NS; n += 256) {
      unsigned d = (unsigned)(keys[n] >> 56);
      if (d > sel) {
        unsigned p = atomicAdd(&s_cnt, 1u);
        idxout[(size_t)bhc * NW + p] = n;
        atomicAdd(&cnt[(size_t)(b * NS + n) * NH + h], 1.0f);
      } else if (d == sel) {
        unsigned p = atomicAdd(&s_cc[0], 1u);
        cand[0][p] = (unsigned short)n;
      }
    }
  }
  __syncthreads();
  int cur = 0;
  for (int p = 6; p >= 0; p--) {
    int sh = p * 8;
    unsigned nc = s_cc[cur];
    for (unsigned i = t; i < nc; i += 256) {
      unsigned d = (unsigned)((keys[cand[cur][i]] >> sh) & 255ULL);
      atomicAdd(&hist[d], 1u);
    }
    __syncthreads();
    if (t < 64) {
      unsigned h0 = hist[4 * t + 0], h1 = hist[4 * t + 1];
      unsigned h2 = hist[4 * t + 2], h3 = hist[4 * t + 3];
      hist[4 * t + 0] = 0u; hist[4 * t + 1] = 0u; hist[4 * t + 2] = 0u; hist[4 * t + 3] = 0u;
      unsigned t3 = h3, t2 = h2 + h3, t1 = h1 + t2, t0 = h0 + t1;
      unsigned s = t0;
#pragma unroll
      for (int off = 1; off < 64; off <<= 1) {
        unsigned v = __shfl_down(s, off);
        if (t + off < 64) s += v;
      }
      unsigned E = s - t0;
      unsigned rem = s_rem;
      unsigned sf0 = t0 + E, sf1 = t1 + E, sf2 = t2 + E, sf3 = t3 + E, sf4 = E;
      if (sf0 >= rem && sf1 < rem) { s_sel = 4u * t + 0u; s_rem = rem - sf1; }
      if (sf1 >= rem && sf2 < rem) { s_sel = 4u * t + 1u; s_rem = rem - sf2; }
      if (sf2 >= rem && sf3 < rem) { s_sel = 4u * t + 2u; s_rem = rem - sf3; }
      if (sf3 >= rem && sf4 < rem) { s_sel = 4u * t + 3u; s_rem = rem - sf4; }
      if (t == 0) s_cc[cur ^ 1] = 0u;
    }
    __syncthreads();
    unsigned sel = s_sel;
    if (p == 0) {
      for (unsigned i = t; i < nc; i += 256) {
        unsigned n = cand[cur][i];
        unsigned d = (unsigned)(keys[n] & 255ULL);
        if (d >= sel) {
          unsigned pp = atomicAdd(&s_cnt, 1u);
          idxout[(size_t)bhc * NW + pp] = n;
          atomicAdd(&cnt[(size_t)(b * NS + n) * NH + h], 1.0f);
        }
      }
    } else {
      int nxt = cur ^ 1;
      for (unsigned i = t; i < nc; i += 256) {
        unsigned n = cand[cur][i];
        unsigned d = (unsigned)((keys[n] >> sh) & 255ULL);
        if (d > sel) {
          unsigned pp = atomicAdd(&s_cnt, 1u);
          idxout[(size_t)bhc * NW + pp] = n;
          atomicAdd(&cnt[(size_t)(b * NS + n) * NH + h], 1.0f);
        } else if (d == sel) {
          unsigned pp = atomicAdd(&s_cc[nxt], 1u);
          cand[nxt][pp] = (unsigned short)n;
        }
      }
      __syncthreads();
      cur = nxt;
    }
  }
}

// ---------------- bucket attention ----------------
__global__ __launch_bounds__(256) void attn_kernel(
    const float* __restrict__ q, const float* __restrict__ k, const float* __restrict__ v,
    const int* __restrict__ idxb, const int* __restrict__ value, const float* __restrict__ cnt,
    float* __restrict__ obuf) {
  __shared__ float qs[NW * (ND + 1)];
  __shared__ float ks[NW * (ND + 1)];
  __shared__ float sc[NW * (NW + 1)];
  __shared__ int idxs[NW];
  __shared__ float kmv[NW];
  __shared__ float cinv[NW];
  int bhc = blockIdx.x;
  int h = (bhc >> 6) & (NH - 1);
  int b = bhc >> 9;
  int t = threadIdx.x;
  if (t < NW) {
    int n = idxb[(size_t)bhc * NW + t];
    idxs[t] = n;
    kmv[t] = (value[b * NS + n] != 0) ? 1.f : 0.f;
    cinv[t] = 1.0f / fmaxf(cnt[(size_t)(b * NS + n) * NH + h], 1.0f);
  }
  __syncthreads();
  for (int p = t; p < NW * ND; p += 256) {
    int w = p >> 6, d = p & (ND - 1);
    size_t src = (size_t)(b * NS + idxs[w]) * NE + h * ND + d;
    qs[w * (ND + 1) + d] = q[src];
    ks[w * (ND + 1) + d] = k[src];
  }
  __syncthreads();
  for (int p = t; p < NW * NW; p += 256) {
    int w = p >> 6, x = p & (NW - 1);
    float dot = 0.f;
#pragma unroll 16
    for (int d = 0; d < ND; d++) dot += qs[w * (ND + 1) + d] * ks[x * (ND + 1) + d];
    bool allowed = (idxs[w] >= idxs[x]) && (kmv[x] != 0.f);
    sc[w * (NW + 1) + x] = allowed ? dot * 0.125f : -1e9f;
  }
  __syncthreads();
  if (t < NW) {
    float mx = -3.4e38f;
    for (int x = 0; x < NW; x++) mx = fmaxf(mx, sc[t * (NW + 1) + x]);
    float sum = 0.f;
    for (int x = 0; x < NW; x++) {
      float e = expf(sc[t * (NW + 1) + x] - mx);
      sc[t * (NW + 1) + x] = e;
      sum += e;
    }
    float inv = cinv[t] / sum;
    for (int x = 0; x < NW; x++) sc[t * (NW + 1) + x] *= inv;
  }
  for (int p = t; p < NW * ND; p += 256) {
    int w = p >> 6, d = p & (ND - 1);
    ks[w * (ND + 1) + d] = v[(size_t)(b * NS + idxs[w]) * NE + h * ND + d];
  }
  __syncthreads();
  for (int p = t; p < NW * ND; p += 256) {
    int w = p >> 6, d = p & (ND - 1);
    float o = 0.f;
#pragma unroll 16
    for (int x = 0; x < NW; x++) o += sc[w * (NW + 1) + x] * ks[x * (ND + 1) + d];
    qs[w * (ND + 1) + d] = o;
  }
  __syncthreads();
  for (int p = t; p < NW * ND; p += 256) {
    int w = p >> 6, d = p & (ND - 1);
    atomicAdd(&obuf[(size_t)(b * NS + idxs[w]) * NE + h * ND + d], qs[w * (ND + 1) + d]);
  }
}

// ---------------- head ----------------
__global__ __launch_bounds__(256) void head_kernel(
    const float* __restrict__ x, const void* __restrict__ hw, void* __restrict__ out, int f32) {
  int gw = (blockIdx.x * 256 + threadIdx.x) >> 6;
  int lane = threadIdx.x & 63;
  if (gw >= NTOK * NVOC) return;
  int row = gw / NVOC, vv = gw % NVOC;
  const float* xr = x + (size_t)row * NE;
  float acc = 0.f;
  for (int e = lane; e < NE; e += 64) acc += xr[e] * ldw(hw, (size_t)vv * NE + e, f32);
#pragma unroll
  for (int o = 32; o; o >>= 1) acc += __shfl_down(acc, o);
  if (lane == 0) {
    if (f32) ((float*)out)[(size_t)row * NVOC + vv] = acc;
    else ((bf16*)out)[(size_t)row * NVOC + vv] = __float2bfloat16(acc);
  }
}

extern "C" void kernel_launch(void* const* d_in, const int* in_sizes, int n_in,
                              void* d_out, int out_size, void* d_ws, size_t ws_size,
                              hipStream_t stream) {
  const int* value = (const int*)d_in[0];
  const int* depth = (const int*)d_in[1];
  const int* pos = (const int*)d_in[2];
  const void* sos = d_in[3];
  const void* tok_emb = d_in[4];
  const void* depth_emb = d_in[5];
  const void* pos_emb = d_in[6];
  const void* ln1_s = d_in[7];
  const void* ln1_b = d_in[8];
  const void* Wq = d_in[9];
  const void* Wk = d_in[10];
  const void* Wv = d_in[11];
  const void* Wo = d_in[12];
  const void* means = d_in[13];
  const void* ln2_s = d_in[14];
  const void* ln2_b = d_in[15];
  const void* W1 = d_in[16];
  const void* b1 = d_in[17];
  const void* W2 = d_in[18];
  const void* b2 = d_in[19];
  const void* head_w = d_in[20];
  (void)n_in;

  int f32 = (in_sizes[4] != 17408) ? 1 : 0;

  const size_t NX = (size_t)NTOK * NE;
  const size_t NEED = 170917896ULL;
  if (ws_size < NEED) {
    float val = (float)(unsigned)(ws_size >> 20) * 1000.0f;
    fill_out_kernel<<<(out_size + 255) / 256, 256, 0, stream>>>((float*)d_out, out_size, val);
    return;
  }

  float* xbuf = (float*)d_ws;
  float* hbuf = xbuf + NX;       // LN1 out / qT / attn accumulator (time-shared)
  float* qbuf = hbuf + NX;
  float* kbuf = qbuf + NX;
  float* vbuf = kbuf + NX;
  double* mndbuf = (double*)(vbuf + NX);
  double* rqdbuf = mndbuf + (size_t)NL * NH * NC * ND;
  float* cntbuf = (float*)(rqdbuf + (size_t)NTOK * NH);
  int* idxbuf = (int*)(cntbuf + (size_t)NTOK * NH);
  float* mid = kbuf;

  mnd_kernel<<<NL * NH * NC, 64, 0, stream>>>(means, mndbuf, f32);
  embed_kernel<<<(int)((NX + 255) / 256), 256, 0, stream>>>(
      value, depth, pos, sos, tok_emb, depth_emb, pos_emb, xbuf, f32);

  dim3 g512(NE / 128, NTOK / 128);
  dim3 gkv(8, NTOK / 128);

  if (f32) {
    const float* Wqf = (const float*)Wq;
    const float* Wkf = (const float*)Wk;
    const float* Wvf = (const float*)Wv;
    const float* Wof = (const float*)Wo;
    const float* W1f = (const float*)W1;
    const float* W2f = (const float*)W2;
    const float* b1f = (const float*)b1;
    const float* b2f = (const float*)b2;
    for (int l = 0; l < NL; l++) {
      size_t o_w = (size_t)l * NE * NE;
      size_t o_w1 = (size_t)l * NE * NF;
      size_t o_w2 = (size_t)l * NF * NE;
      size_t o_e = (size_t)l * NE;
      size_t o_f = (size_t)l * NF;

      ln_kernel<<<NTOK / 4, 256, 0, stream>>>(xbuf, ln1_s, ln1_b, o_e, hbuf, 1);
      // q: 6-product (routing-critical, 2^-24); k,v: 3-product (no discrete risk)
      gemm_mfma_kernel<0, 1><<<g512, 256, 0, stream>>>(hbuf, Wqf + o_w, NE, nullptr, nullptr,
                                                       qbuf, NE, NE);
      gemm_kv_mfma<<<gkv, 256, 0, stream>>>(hbuf, Wkf, Wvf, o_w, kbuf, vbuf);

      qt_kernel<<<NB * NH * 64, 256, 0, stream>>>(qbuf, hbuf, rqdbuf);
      zero_kernel<<<(NTOK * NH) / 256, 256, 0, stream>>>(cntbuf, NTOK * NH);
      route_kernel<<<NB * NH * NC, 256, 0, stream>>>(
          hbuf, mndbuf + (size_t)l * NH * NC * ND, rqdbuf, idxbuf, cntbuf);

      zero_kernel<<<(int)((NX + 255) / 256), 256, 0, stream>>>(hbuf, (int)NX);
      attn_kernel<<<NB * NH * NC, 256, 0, stream>>>(qbuf, kbuf, vbuf, idxbuf, value, cntbuf, hbuf);
      gemm_mfma_kernel<0, 0><<<g512, 256, 0, stream>>>(hbuf, Wof + o_w, NE, nullptr, xbuf,
                                                       xbuf, NE, NE);

      ln_kernel<<<NTOK / 4, 256, 0, stream>>>(xbuf, ln2_s, ln2_b, o_e, qbuf, 1);
      for (int c = 0; c < 4; c++) {
        gemm_mfma_kernel<1, 0><<<g512, 256, 0, stream>>>(
            qbuf, W1f + o_w1 + (size_t)c * 512, NF, b1f + o_f + (size_t)c * 512,
            nullptr, mid, 512, NE);
        gemm_mfma_kernel<0, 0><<<g512, 256, 0, stream>>>(
            mid, W2f + o_w2 + (size_t)c * 512 * NE, NE,
            (c == 0) ? (b2f + o_e) : nullptr, xbuf, xbuf, NE, 512);
      }
    }
  } else {
    const int CH = 8192;
    dim3 gqkvv(12, NTOK / 128);
    dim3 gW1(NF / 128, CH / 128);
    dim3 gW2(NE / 128, CH / 128);
    for (int l = 0; l < NL; l++) {
      size_t o_w = (size_t)l * NE * NE;
      size_t o_w1 = (size_t)l * NE * NF;
      size_t o_w2 = (size_t)l * NF * NE;
      size_t o_e = (size_t)l * NE;
      size_t o_f = (size_t)l * NF;

      ln_kernel<<<NTOK / 4, 256, 0, stream>>>(xbuf, ln1_s, ln1_b, o_e, hbuf, 0);
      gemm_qkv_kernel<<<gqkvv, 256, 0, stream>>>(hbuf, Wq, Wk, Wv, o_w, qbuf, kbuf, vbuf, 0);

      qt_kernel<<<NB * NH * 64, 256, 0, stream>>>(qbuf, hbuf, rqdbuf);
      zero_kernel<<<(NTOK * NH) / 256, 256, 0, stream>>>(cntbuf, NTOK * NH);
      route_kernel<<<NB * NH * NC, 256, 0, stream>>>(
          hbuf, mndbuf + (size_t)l * NH * NC * ND, rqdbuf, idxbuf, cntbuf);

      zero_kernel<<<(int)((NX + 255) / 256), 256, 0, stream>>>(hbuf, (int)NX);
      attn_kernel<<<NB * NH * NC, 256, 0, stream>>>(qbuf, kbuf, vbuf, idxbuf, value, cntbuf, hbuf);
      gemm_kernel<0><<<g512, 256, 0, stream>>>(hbuf, Wo, o_w, NE, nullptr, 0, xbuf,
                                               xbuf, NE, NE, 0);

      ln_kernel<<<NTOK / 4, 256, 0, stream>>>(xbuf, ln2_s, ln2_b, o_e, qbuf, 0);
      for (int ch = 0; ch < NTOK / CH; ch++) {
        const float* hch = qbuf + (size_t)ch * CH * NE;
        float* xch = xbuf + (size_t)ch * CH * NE;
        gemm_kernel<1><<<gW1, 256, 0, stream>>>(hch, W1, o_w1, NF, b1, o_f, nullptr,
                                                mid, NF, NE, 0);
        gemm_kernel<0><<<gW2, 256, 0, stream>>>(mid, W2, o_w2, NE, b2, o_e, xch,
                                                xch, NE, NF, 0);
      }
    }
  }

  head_kernel<<<(NTOK * NVOC * 64 + 255) / 256, 256, 0, stream>>>(xbuf, head_w, d_out, f32);
}

// Round 12
// 3786.238 us; speedup vs baseline: 1.5819x; 1.0492x over previous
//
#include <hip/hip_runtime.h>
#include <hip/hip_bf16.h>
#include <math.h>

typedef __hip_bfloat16 bf16;
typedef __attribute__((ext_vector_type(2))) float f2v;
typedef __attribute__((ext_vector_type(8))) short bf16x8;
typedef __attribute__((ext_vector_type(4))) float f32x4;

#define NB 4
#define NS 4096
#define NE 512
#define NH 8
#define NL 4
#define NA 3
#define ND 64
#define NC 64
#define NW 64
#define NF 2048
#define NVOC 17
#define NTOK (NB * NS)   // 16384
#define AP 68            // attn LDS row stride (floats): 16B-aligned, 17*row+d4 banks ok

__device__ __forceinline__ float b2f(bf16 v) { return __bfloat162float(v); }
__device__ __forceinline__ float u2f(unsigned short u) { return __uint_as_float((unsigned)u << 16); }
__device__ __forceinline__ float ldw(const void* p, size_t i, int f32) {
  return f32 ? ((const float*)p)[i] : b2f(((const bf16*)p)[i]);
}
__device__ __forceinline__ unsigned short f2bf(float f) {   // RNE fp32->bf16
  unsigned u = __float_as_uint(f);
  return (unsigned short)((u + 0x7FFFu + ((u >> 16) & 1u)) >> 16);
}

// ---------------- diagnostic fill (ws_size too small) ----------------
__global__ __launch_bounds__(256) void fill_out_kernel(float* __restrict__ out, int n, float val) {
  int i = blockIdx.x * 256 + threadIdx.x;
  if (i < n) out[i] = val;
}

// ---------------- zero fill ----------------
__global__ __launch_bounds__(256) void zero_kernel(float* __restrict__ p, int n) {
  int i = blockIdx.x * 256 + threadIdx.x;
  if (i < n) p[i] = 0.f;
}

// ---------------- embeddings + shift-right ----------------
__global__ __launch_bounds__(256) void embed_kernel(
    const int* __restrict__ value, const int* __restrict__ depth, const int* __restrict__ pos,
    const void* __restrict__ sos, const void* __restrict__ tok_emb,
    const void* __restrict__ depth_emb, const void* __restrict__ pos_emb,
    float* __restrict__ x, int f32) {
  int i = blockIdx.x * 256 + threadIdx.x;
  if (i >= NTOK * NE) return;
  int e = i & (NE - 1);
  int bs = i >> 9;
  int s = bs & (NS - 1);
  int b = bs >> 12;
  float v;
  if (s == 0) {
    v = ldw(sos, e, f32);
  } else {
    int src = b * NS + (s - 1);
    float acc = ldw(tok_emb, (size_t)value[src] * NE + e, f32)
              + ldw(depth_emb, (size_t)depth[src] * NE + e, f32);
#pragma unroll
    for (int a = 0; a < NA; a++)
      acc += ldw(pos_emb, ((size_t)a * 65 + pos[src * NA + a]) * NE + e, f32);
    v = acc;
  }
  x[i] = v;
}

// ---------------- layer norm, one wave per row ----------------
__global__ __launch_bounds__(256) void ln_kernel(
    const float* __restrict__ x, const void* __restrict__ gam, const void* __restrict__ bet,
    size_t off, float* __restrict__ out, int f32) {
  int row = blockIdx.x * 4 + (threadIdx.x >> 6);
  int lane = threadIdx.x & 63;
  const float* xr = x + (size_t)row * NE;
  float v[8];
#pragma unroll
  for (int i = 0; i < 8; i++) v[i] = xr[lane + i * 64];
  float s = 0.f;
#pragma unroll
  for (int i = 0; i < 8; i++) s += v[i];
#pragma unroll
  for (int o = 32; o; o >>= 1) s += __shfl_xor(s, o);
  float m = s * (1.0f / NE);
  float sq = 0.f;
#pragma unroll
  for (int i = 0; i < 8; i++) { float d = v[i] - m; sq += d * d; }
#pragma unroll
  for (int o = 32; o; o >>= 1) sq += __shfl_xor(sq, o);
  float rs = 1.0f / sqrtf(sq * (1.0f / NE) + 1e-5f);
  float* orow = out + (size_t)row * NE;
#pragma unroll
  for (int i = 0; i < 8; i++) {
    int e = lane + i * 64;
    orow[e] = (v[i] - m) * rs * ldw(gam, off + e, f32) + ldw(bet, off + e, f32);
  }
}

// ---------------- fp32 vector GEMM core (bf16-input fallback path) ----------------
template <int ACT>
__device__ __forceinline__ void gemm_body(
    const float* __restrict__ A, const void* __restrict__ Bw, size_t bwoff, int ldb,
    const void* bias, size_t biasoff, const float* resid, float* C,
    int N, int K, int f32, int bm, int bn) {
  __shared__ float As[32][132];
  __shared__ float Bs[32][132];
  int tid = threadIdx.x;
  int ty = tid >> 4, tx = tid & 15;
  f2v acc2[8][4];
#pragma unroll
  for (int i = 0; i < 8; i++)
#pragma unroll
    for (int j = 0; j < 4; j++) acc2[i][j] = (f2v){0.f, 0.f};
  int arow = tid >> 1;
  int acol = (tid & 1) << 4;
  int brow = tid >> 3;
  int bcol = (tid & 7) << 4;

  const float* Aptr = A + (size_t)(bm + arow) * K + acol;
  float4 pa[4];
  float4 pb[4];
  uint4 pbu[2];
#pragma unroll
  for (int j = 0; j < 4; j++) pa[j] = *(const float4*)(Aptr + 4 * j);
  {
    size_t boff = bwoff + (size_t)brow * ldb + bn + bcol;
    if (f32) {
#pragma unroll
      for (int j = 0; j < 4; j++) pb[j] = *(const float4*)((const float*)Bw + boff + 4 * j);
    } else {
      pbu[0] = *(const uint4*)((const bf16*)Bw + boff);
      pbu[1] = *(const uint4*)((const bf16*)Bw + boff + 8);
    }
  }

  for (int k0 = 0; k0 < K; k0 += 32) {
#pragma unroll
    for (int j = 0; j < 4; j++) {
      As[acol + 4 * j + 0][arow] = pa[j].x;
      As[acol + 4 * j + 1][arow] = pa[j].y;
      As[acol + 4 * j + 2][arow] = pa[j].z;
      As[acol + 4 * j + 3][arow] = pa[j].w;
    }
    if (f32) {
#pragma unroll
      for (int j = 0; j < 4; j++) {
        Bs[brow][bcol + 4 * j + 0] = pb[j].x;
        Bs[brow][bcol + 4 * j + 1] = pb[j].y;
        Bs[brow][bcol + 4 * j + 2] = pb[j].z;
        Bs[brow][bcol + 4 * j + 3] = pb[j].w;
      }
    } else {
      union { uint4 u; unsigned short s[8]; } r0, r1;
      r0.u = pbu[0]; r1.u = pbu[1];
#pragma unroll
      for (int j = 0; j < 8; j++) Bs[brow][bcol + j] = u2f(r0.s[j]);
#pragma unroll
      for (int j = 0; j < 8; j++) Bs[brow][bcol + 8 + j] = u2f(r1.s[j]);
    }
    __syncthreads();
    if (k0 + 32 < K) {
#pragma unroll
      for (int j = 0; j < 4; j++) pa[j] = *(const float4*)(Aptr + k0 + 32 + 4 * j);
      size_t boff = bwoff + (size_t)(k0 + 32 + brow) * ldb + bn + bcol;
      if (f32) {
#pragma unroll
        for (int j = 0; j < 4; j++) pb[j] = *(const float4*)((const float*)Bw + boff + 4 * j);
      } else {
        pbu[0] = *(const uint4*)((const bf16*)Bw + boff);
        pbu[1] = *(const uint4*)((const bf16*)Bw + boff + 8);
      }
    }
#pragma unroll
    for (int kk = 0; kk < 32; kk++) {
      float4 aA = *(const float4*)&As[kk][ty << 3];
      float4 aB = *(const float4*)&As[kk][(ty << 3) + 4];
      float4 bA = *(const float4*)&Bs[kk][tx << 2];
      float4 bB = *(const float4*)&Bs[kk][64 + (tx << 2)];
      float av[8] = {aA.x, aA.y, aA.z, aA.w, aB.x, aB.y, aB.z, aB.w};
      f2v bv[4];
      bv[0] = (f2v){bA.x, bA.y};
      bv[1] = (f2v){bA.z, bA.w};
      bv[2] = (f2v){bB.x, bB.y};
      bv[3] = (f2v){bB.z, bB.w};
#pragma unroll
      for (int i = 0; i < 8; i++)
#pragma unroll
        for (int j = 0; j < 4; j++)
          acc2[i][j] += bv[j] * av[i];
    }
    __syncthreads();
  }
#pragma unroll
  for (int i = 0; i < 8; i++) {
    int row = bm + (ty << 3) + i;
    int c0 = bn + (tx << 2);
    int c1 = bn + 64 + (tx << 2);
    const float* ap = (const float*)&acc2[i][0];
    float o0[4], o1[4];
#pragma unroll
    for (int j = 0; j < 4; j++) { o0[j] = ap[j]; o1[j] = ap[4 + j]; }
    if (bias) {
#pragma unroll
      for (int j = 0; j < 4; j++) {
        o0[j] += ldw(bias, biasoff + c0 + j, f32);
        o1[j] += ldw(bias, biasoff + c1 + j, f32);
      }
    }
    if (ACT == 1) {
#pragma unroll
      for (int j = 0; j < 4; j++) {
        float t0 = 0.7978845608028654f * (o0[j] + 0.044715f * o0[j] * o0[j] * o0[j]);
        o0[j] = 0.5f * o0[j] * (1.0f + tanhf(t0));
        float t1 = 0.7978845608028654f * (o1[j] + 0.044715f * o1[j] * o1[j] * o1[j]);
        o1[j] = 0.5f * o1[j] * (1.0f + tanhf(t1));
      }
    }
    size_t p0 = (size_t)row * N + c0;
    size_t p1 = (size_t)row * N + c1;
    if (resid) {
      float4 r0 = *(const float4*)(resid + p0);
      float4 r1 = *(const float4*)(resid + p1);
      o0[0] += r0.x; o0[1] += r0.y; o0[2] += r0.z; o0[3] += r0.w;
      o1[0] += r1.x; o1[1] += r1.y; o1[2] += r1.z; o1[3] += r1.w;
    }
    *(float4*)(C + p0) = make_float4(o0[0], o0[1], o0[2], o0[3]);
    *(float4*)(C + p1) = make_float4(o1[0], o1[1], o1[2], o1[3]);
  }
}

template <int ACT>
__global__ __launch_bounds__(256) void gemm_kernel(
    const float* __restrict__ A, const void* __restrict__ Bw, size_t bwoff, int ldb,
    const void* bias, size_t biasoff, const float* resid, float* C,
    int N, int K, int f32) {
  gemm_body<ACT>(A, Bw, bwoff, ldb, bias, biasoff, resid, C, N, K,
                 f32, blockIdx.y << 7, blockIdx.x << 7);
}

__global__ __launch_bounds__(256) void gemm_qkv_kernel(
    const float* __restrict__ A,
    const void* __restrict__ Wq, const void* __restrict__ Wk, const void* __restrict__ Wv,
    size_t bwoff, float* __restrict__ Cq, float* __restrict__ Ck, float* __restrict__ Cv,
    int f32) {
  int sel = blockIdx.x >> 2;
  const void* Bw = (sel == 0) ? Wq : ((sel == 1) ? Wk : Wv);
  float* C = (sel == 0) ? Cq : ((sel == 1) ? Ck : Cv);
  gemm_body<0>(A, Bw, bwoff, NE, nullptr, 0, nullptr, C, NE, NE,
               f32, blockIdx.y << 7, (blockIdx.x & 3) << 7);
}

// ---------------- MFMA GEMM for fp32 A x fp32 W ----------------
// FULL=1: 3-way splits, 6 products ~2^-24. q only. FULL=0: 2-way, 3 products ~2^-18.
// Layout = round-7 measured best: [128][40] planes; B staged Bx[n][k'] with chunk
// swizzle k' = k ^ (((n>>4)&3)<<3); frag read at chunk (lg^ni)&3 recovers k-chunk lg.
template <int ACT, int FULL>
__device__ __forceinline__ void mfma_body(
    const float* __restrict__ A, const float* __restrict__ Bw, int ldb,
    const float* __restrict__ bias, const float* __restrict__ resid, float* __restrict__ C,
    int N, int K, int bm, int bn) {
  __shared__ unsigned short Ah[128][40];
  __shared__ unsigned short Am[128][40];
  __shared__ unsigned short Al[FULL ? 128 : 1][40];
  __shared__ unsigned short Bh[128][40];
  __shared__ unsigned short Bm[128][40];
  __shared__ unsigned short Bl[FULL ? 128 : 1][40];
  int t = threadIdx.x;
  int arow = t >> 1;
  int akc = (t & 1) << 4;
  const float* Ap = A + (size_t)(bm + arow) * K + akc;
  int bkr = t >> 3;
  int bcg = t & 7;
  const float* Bp = Bw + (size_t)bkr * ldb + bn + bcg * 16;
  int bkpos = bkr ^ ((bcg & 3) << 3);

  float4 pa[4], pb[4];
#pragma unroll
  for (int j = 0; j < 4; j++) pa[j] = *(const float4*)(Ap + 4 * j);
#pragma unroll
  for (int j = 0; j < 4; j++) pb[j] = *(const float4*)(Bp + 4 * j);

  int lane = t & 63;
  int wid = t >> 6;
  int wr = wid >> 1, wc = wid & 1;
  int lr = lane & 15, lg = lane >> 4;

  f32x4 acc[4][4];
#pragma unroll
  for (int i = 0; i < 4; i++)
#pragma unroll
    for (int j = 0; j < 4; j++) acc[i][j] = (f32x4){0.f, 0.f, 0.f, 0.f};

  for (int k0 = 0; k0 < K; k0 += 32) {
    {
      unsigned hs[8], ms[8], ls[8];
#pragma unroll
      for (int j = 0; j < 4; j++) {
        const float* pf = (const float*)&pa[j];
#pragma unroll
        for (int e = 0; e < 2; e++) {
          float a0 = pf[2 * e], a1 = pf[2 * e + 1];
          unsigned short h0 = f2bf(a0), h1 = f2bf(a1);
          float r0 = a0 - u2f(h0), r1 = a1 - u2f(h1);
          unsigned short m0 = f2bf(r0), m1 = f2bf(r1);
          hs[2 * j + e] = (unsigned)h0 | ((unsigned)h1 << 16);
          ms[2 * j + e] = (unsigned)m0 | ((unsigned)m1 << 16);
          if (FULL) {
            float s0 = r0 - u2f(m0), s1 = r1 - u2f(m1);
            unsigned short l0 = f2bf(s0), l1 = f2bf(s1);
            ls[2 * j + e] = (unsigned)l0 | ((unsigned)l1 << 16);
          }
        }
      }
      *(uint4*)&Ah[arow][akc]     = make_uint4(hs[0], hs[1], hs[2], hs[3]);
      *(uint4*)&Ah[arow][akc + 8] = make_uint4(hs[4], hs[5], hs[6], hs[7]);
      *(uint4*)&Am[arow][akc]     = make_uint4(ms[0], ms[1], ms[2], ms[3]);
      *(uint4*)&Am[arow][akc + 8] = make_uint4(ms[4], ms[5], ms[6], ms[7]);
      if (FULL) {
        *(uint4*)&Al[arow][akc]     = make_uint4(ls[0], ls[1], ls[2], ls[3]);
        *(uint4*)&Al[arow][akc + 8] = make_uint4(ls[4], ls[5], ls[6], ls[7]);
      }
    }
    {
#pragma unroll
      for (int j = 0; j < 4; j++) {
        const float* pf = (const float*)&pb[j];
#pragma unroll
        for (int e = 0; e < 4; e++) {
          float a = pf[e];
          unsigned short h = f2bf(a);
          float r = a - u2f(h);
          unsigned short m = f2bf(r);
          int nn = bcg * 16 + 4 * j + e;
          Bh[nn][bkpos] = h;
          Bm[nn][bkpos] = m;
          if (FULL) {
            float s = r - u2f(m);
            Bl[nn][bkpos] = f2bf(s);
          }
        }
      }
    }
    __syncthreads();
    if (k0 + 32 < K) {
#pragma unroll
      for (int j = 0; j < 4; j++) pa[j] = *(const float4*)(Ap + k0 + 32 + 4 * j);
      const float* Bn = Bp + (size_t)(k0 + 32) * ldb;
#pragma unroll
      for (int j = 0; j < 4; j++) pb[j] = *(const float4*)(Bn + 4 * j);
    }
    bf16x8 fbh[4], fbm[4], fbl[4];
#pragma unroll
    for (int ni = 0; ni < 4; ni++) {
      int rb = wc * 64 + ni * 16 + lr;
      int cb = ((lg ^ ni) & 3) * 8;
      fbh[ni] = *(const bf16x8*)&Bh[rb][cb];
      fbm[ni] = *(const bf16x8*)&Bm[rb][cb];
      if (FULL) fbl[ni] = *(const bf16x8*)&Bl[rb][cb];
    }
#pragma unroll
    for (int mi = 0; mi < 4; mi++) {
      int ar = wr * 64 + mi * 16 + lr;
      bf16x8 fh = *(const bf16x8*)&Ah[ar][lg * 8];
      bf16x8 fm = *(const bf16x8*)&Am[ar][lg * 8];
      bf16x8 fl;
      if (FULL) fl = *(const bf16x8*)&Al[ar][lg * 8];
#pragma unroll
      for (int ni = 0; ni < 4; ni++) {
        f32x4 a = acc[mi][ni];
        a = __builtin_amdgcn_mfma_f32_16x16x32_bf16(fh, fbh[ni], a, 0, 0, 0);
        a = __builtin_amdgcn_mfma_f32_16x16x32_bf16(fh, fbm[ni], a, 0, 0, 0);
        a = __builtin_amdgcn_mfma_f32_16x16x32_bf16(fm, fbh[ni], a, 0, 0, 0);
        if (FULL) {
          a = __builtin_amdgcn_mfma_f32_16x16x32_bf16(fm, fbm[ni], a, 0, 0, 0);
          a = __builtin_amdgcn_mfma_f32_16x16x32_bf16(fh, fbl[ni], a, 0, 0, 0);
          a = __builtin_amdgcn_mfma_f32_16x16x32_bf16(fl, fbh[ni], a, 0, 0, 0);
        }
        acc[mi][ni] = a;
      }
    }
    __syncthreads();
  }
#pragma unroll
  for (int mi = 0; mi < 4; mi++) {
#pragma unroll
    for (int ni = 0; ni < 4; ni++) {
      int col = bn + wc * 64 + ni * 16 + lr;
      int rbase = bm + wr * 64 + mi * 16 + lg * 4;
      float bv = bias ? bias[col] : 0.f;
      const float* av = (const float*)&acc[mi][ni];
#pragma unroll
      for (int r = 0; r < 4; r++) {
        float o = av[r] + bv;
        if (ACT == 1) {
          float t0 = 0.7978845608028654f * (o + 0.044715f * o * o * o);
          o = 0.5f * o * (1.0f + tanhf(t0));
        }
        size_t p = (size_t)(rbase + r) * N + col;
        if (resid) o += resid[p];
        C[p] = o;
      }
    }
  }
}

template <int ACT, int FULL>
__global__ __launch_bounds__(256) void gemm_mfma_kernel(
    const float* __restrict__ A, const float* __restrict__ Bw, int ldb,
    const float* __restrict__ bias, const float* __restrict__ resid, float* __restrict__ C,
    int N, int K) {
  mfma_body<ACT, FULL>(A, Bw, ldb, bias, resid, C, N, K, blockIdx.y << 7, blockIdx.x << 7);
}

// fused k/v MFMA (3-product): blockIdx.x in [0,8): sel = x>>2, col block x&3
__global__ __launch_bounds__(256) void gemm_kv_mfma(
    const float* __restrict__ A, const float* __restrict__ Wk, const float* __restrict__ Wv,
    size_t off, float* __restrict__ Ck, float* __restrict__ Cv) {
  int sel = blockIdx.x >> 2;
  const float* Bw = sel ? Wv : Wk;
  float* C = sel ? Cv : Ck;
  mfma_body<0, 0>(A, Bw + off, NE, nullptr, nullptr, C, NE, NE,
                  blockIdx.y << 7, (blockIdx.x & 3) << 7);
}

// ---------------- q transpose + fused rq: qT[b][h][d][n], rqd[b][h][n] ----------------
__global__ __launch_bounds__(256) void qt_kernel(const float* __restrict__ q, float* __restrict__ qT,
                                                 double* __restrict__ rqd) {
  __shared__ float tile[64][65];
  int bid = blockIdx.x;
  int st = bid & 63;
  int bh = bid >> 6;
  int b = bh >> 3, h = bh & 7;
  int s0 = st * 64;
  int t = threadIdx.x;
#pragma unroll
  for (int k = 0; k < 16; k++) {
    int idx = t + k * 256;
    int sl = idx >> 6, dl = idx & 63;
    tile[sl][dl] = q[(size_t)(b * NS + s0 + sl) * NE + h * ND + dl];
  }
  __syncthreads();
#pragma unroll
  for (int k = 0; k < 16; k++) {
    int idx = t + k * 256;
    int dl = idx >> 6, sl = idx & 63;
    qT[((size_t)bh * 64 + dl) * NS + s0 + sl] = tile[sl][dl];
  }
  int w = t >> 6, lane = t & 63;
#pragma unroll
  for (int i = 0; i < 16; i++) {
    int tok = w * 16 + i;
    double v = (double)tile[tok][lane];
    double ss = v * v;
#pragma unroll
    for (int o = 32; o; o >>= 1) ss += __shfl_xor(ss, o);
    if (lane == 0) rqd[((size_t)bh << 12) | (s0 + tok)] = 1.0 / (sqrt(ss) + 1e-8);
  }
}

// ---------------- normalized means in fp64 ----------------
__global__ __launch_bounds__(64) void mnd_kernel(const void* __restrict__ means,
                                                 double* __restrict__ mnd, int f32) {
  __shared__ double s[64];
  int vblk = blockIdx.x;
  int d = threadIdx.x;
  double m = (double)ldw(means, (size_t)vblk * ND + d, f32);
  s[d] = m * m;
  __syncthreads();
  for (int st = 32; st; st >>= 1) { if (d < st) s[d] += s[d + st]; __syncthreads(); }
  mnd[(size_t)vblk * ND + d] = m / (sqrt(s[0]) + 1e-8);
}

// ---------------- routing: fp64 dists (coalesced qT) + exact top-64 + fused cnt ----------------
__global__ __launch_bounds__(256) void route_kernel(
    const float* __restrict__ qT, const double* __restrict__ mnd,
    const double* __restrict__ rqd, int* __restrict__ idxout, float* __restrict__ cnt) {
  __shared__ unsigned long long keys[NS];
  __shared__ double mc[ND];
  __shared__ unsigned hist[256];
  __shared__ unsigned short cand[2][NS];
  __shared__ unsigned s_rem, s_cnt, s_sel, s_cc[2];
  int bid = blockIdx.x;
  int h = bid & 7;
  int b = (bid >> 3) & 3;
  int c = bid >> 5;
  int bhc = ((b * NH + h) * NC) + c;
  int t = threadIdx.x;
  if (t < ND) mc[t] = mnd[((size_t)h * NC + c) * ND + t];
  hist[t] = 0u;
  if (t == 0) { s_rem = NW; s_cnt = 0u; s_cc[0] = 0u; s_cc[1] = 0u; }
  __syncthreads();
  const float* qTb = qT + (size_t)(b * NH + h) * 64 * NS;
  const double* rqb = rqd + ((size_t)(b * NH + h) << 12);
  for (int i = 0; i < 16; i += 4) {
    int n0 = t + i * 256, n1 = n0 + 256, n2 = n0 + 512, n3 = n0 + 768;
    double a0 = 0.0, a1 = 0.0, a2 = 0.0, a3 = 0.0;
#pragma unroll 8
    for (int d = 0; d < 64; d++) {
      const float* row = qTb + (size_t)d * NS;
      double m = mc[d];
      a0 += (double)row[n0] * m;
      a1 += (double)row[n1] * m;
      a2 += (double)row[n2] * m;
      a3 += (double)row[n3] * m;
    }
    double dv[4] = {a0 * rqb[n0], a1 * rqb[n1], a2 * rqb[n2], a3 * rqb[n3]};
    int nn[4] = {n0, n1, n2, n3};
#pragma unroll
    for (int j = 0; j < 4; j++) {
      long long sb = __double_as_longlong(dv[j]);
      unsigned long long u = (unsigned long long)sb;
      u = (sb < 0) ? ~u : (u | 0x8000000000000000ULL);
      keys[nn[j]] = (u & 0xFFFFFFFFFFFFF000ULL) | (unsigned long long)(NS - 1 - nn[j]);
    }
  }
  __syncthreads();
  {
    unsigned lastd = 0xFFFFFFFFu, lcnt = 0u;
    for (int n = t; n < NS; n += 256) {
      unsigned d = (unsigned)(keys[n] >> 56);
      if (d == lastd) { lcnt++; }
      else { if (lcnt) atomicAdd(&hist[lastd], lcnt); lastd = d; lcnt = 1u; }
    }
    if (lcnt) atomicAdd(&hist[lastd], lcnt);
  }
  __syncthreads();
  if (t < 64) {
    unsigned h0 = hist[4 * t + 0], h1 = hist[4 * t + 1];
    unsigned h2 = hist[4 * t + 2], h3 = hist[4 * t + 3];
    hist[4 * t + 0] = 0u; hist[4 * t + 1] = 0u; hist[4 * t + 2] = 0u; hist[4 * t + 3] = 0u;
    unsigned t3 = h3, t2 = h2 + h3, t1 = h1 + t2, t0 = h0 + t1;
    unsigned s = t0;
#pragma unroll
    for (int off = 1; off < 64; off <<= 1) {
      unsigned v = __shfl_down(s, off);
      if (t + off < 64) s += v;
    }
    unsigned E = s - t0;
    unsigned rem = s_rem;
    unsigned sf0 = t0 + E, sf1 = t1 + E, sf2 = t2 + E, sf3 = t3 + E, sf4 = E;
    if (sf0 >= rem && sf1 < rem) { s_sel = 4u * t + 0u; s_rem = rem - sf1; }
    if (sf1 >= rem && sf2 < rem) { s_sel = 4u * t + 1u; s_rem = rem - sf2; }
    if (sf2 >= rem && sf3 < rem) { s_sel = 4u * t + 2u; s_rem = rem - sf3; }
    if (sf3 >= rem && sf4 < rem) { s_sel = 4u * t + 3u; s_rem = rem - sf4; }
  }
  __syncthreads();
  {
    unsigned sel = s_sel;
    for (int n = t; n < NS; n += 256) {
      unsigned d = (unsigned)(keys[n] >> 56);
      if (d > sel) {
        unsigned p = atomicAdd(&s_cnt, 1u);
        idxout[(size_t)bhc * NW + p] = n;
        atomicAdd(&cnt[(size_t)(b * NS + n) * NH + h], 1.0f);
      } else if (d == sel) {
        unsigned p = atomicAdd(&s_cc[0], 1u);
        cand[0][p] = (unsigned short)n;
      }
    }
  }
  __syncthreads();
  int cur = 0;
  for (int p = 6; p >= 0; p--) {
    int sh = p * 8;
    unsigned nc = s_cc[cur];
    for (unsigned i = t; i < nc; i += 256) {
      unsigned d = (unsigned)((keys[cand[cur][i]] >> sh) & 255ULL);
      atomicAdd(&hist[d], 1u);
    }
    __syncthreads();
    if (t < 64) {
      unsigned h0 = hist[4 * t + 0], h1 = hist[4 * t + 1];
      unsigned h2 = hist[4 * t + 2], h3 = hist[4 * t + 3];
      hist[4 * t + 0] = 0u; hist[4 * t + 1] = 0u; hist[4 * t + 2] = 0u; hist[4 * t + 3] = 0u;
      unsigned t3 = h3, t2 = h2 + h3, t1 = h1 + t2, t0 = h0 + t1;
      unsigned s = t0;
#pragma unroll
      for (int off = 1; off < 64; off <<= 1) {
        unsigned v = __shfl_down(s, off);
        if (t + off < 64) s += v;
      }
      unsigned E = s - t0;
      unsigned rem = s_rem;
      unsigned sf0 = t0 + E, sf1 = t1 + E, sf2 = t2 + E, sf3 = t3 + E, sf4 = E;
      if (sf0 >= rem && sf1 < rem) { s_sel = 4u * t + 0u; s_rem = rem - sf1; }
      if (sf1 >= rem && sf2 < rem) { s_sel = 4u * t + 1u; s_rem = rem - sf2; }
      if (sf2 >= rem && sf3 < rem) { s_sel = 4u * t + 2u; s_rem = rem - sf3; }
      if (sf3 >= rem && sf4 < rem) { s_sel = 4u * t + 3u; s_rem = rem - sf4; }
      if (t == 0) s_cc[cur ^ 1] = 0u;
    }
    __syncthreads();
    unsigned sel = s_sel;
    if (p == 0) {
      for (unsigned i = t; i < nc; i += 256) {
        unsigned n = cand[cur][i];
        unsigned d = (unsigned)(keys[n] & 255ULL);
        if (d >= sel) {
          unsigned pp = atomicAdd(&s_cnt, 1u);
          idxout[(size_t)bhc * NW + pp] = n;
          atomicAdd(&cnt[(size_t)(b * NS + n) * NH + h], 1.0f);
        }
      }
    } else {
      int nxt = cur ^ 1;
      for (unsigned i = t; i < nc; i += 256) {
        unsigned n = cand[cur][i];
        unsigned d = (unsigned)((keys[n] >> sh) & 255ULL);
        if (d > sel) {
          unsigned pp = atomicAdd(&s_cnt, 1u);
          idxout[(size_t)bhc * NW + pp] = n;
          atomicAdd(&cnt[(size_t)(b * NS + n) * NH + h], 1.0f);
        } else if (d == sel) {
          unsigned pp = atomicAdd(&s_cc[nxt], 1u);
          cand[nxt][pp] = (unsigned short)n;
        }
      }
      __syncthreads();
      cur = nxt;
    }
  }
}

// ---------------- bucket attention (float4 LDS, stride AP=68) ----------------
// Accumulation order per output element identical to the scalar version
// (d ascending in QK, x ascending in PV) -> value-preserving.
__global__ __launch_bounds__(256) void attn_kernel(
    const float* __restrict__ q, const float* __restrict__ k, const float* __restrict__ v,
    const int* __restrict__ idxb, const int* __restrict__ value, const float* __restrict__ cnt,
    float* __restrict__ obuf) {
  __shared__ float qs[NW * AP];
  __shared__ float ks[NW * AP];
  __shared__ float sc[NW * AP];
  __shared__ int idxs[NW];
  __shared__ float kmv[NW];
  __shared__ float cinv[NW];
  int bhc = blockIdx.x;
  int h = (bhc >> 6) & (NH - 1);
  int b = bhc >> 9;
  int t = threadIdx.x;
  if (t < NW) {
    int n = idxb[(size_t)bhc * NW + t];
    idxs[t] = n;
    kmv[t] = (value[b * NS + n] != 0) ? 1.f : 0.f;
    cinv[t] = 1.0f / fmaxf(cnt[(size_t)(b * NS + n) * NH + h], 1.0f);
  }
  __syncthreads();
#pragma unroll
  for (int j = 0; j < 4; j++) {
    int p = t + j * 256;
    int w = p >> 4, d4 = p & 15;
    size_t src = (size_t)(b * NS + idxs[w]) * NE + h * ND + 4 * d4;
    *(float4*)&qs[w * AP + 4 * d4] = *(const float4*)(q + src);
    *(float4*)&ks[w * AP + 4 * d4] = *(const float4*)(k + src);
  }
  __syncthreads();
#pragma unroll
  for (int j = 0; j < 16; j++) {
    int p = t + j * 256;
    int w = p >> 6, x = p & (NW - 1);
    float dot = 0.f;
#pragma unroll
    for (int i = 0; i < 16; i++) {
      float4 a = *(const float4*)&qs[w * AP + 4 * i];
      float4 bb = *(const float4*)&ks[x * AP + 4 * i];
      dot += a.x * bb.x;
      dot += a.y * bb.y;
      dot += a.z * bb.z;
      dot += a.w * bb.w;
    }
    bool allowed = (idxs[w] >= idxs[x]) && (kmv[x] != 0.f);
    sc[w * AP + x] = allowed ? dot * 0.125f : -1e9f;
  }
  __syncthreads();
  if (t < NW) {
    float mx = -3.4e38f;
    for (int x = 0; x < NW; x++) mx = fmaxf(mx, sc[t * AP + x]);
    float sum = 0.f;
    for (int x = 0; x < NW; x++) {
      float e = expf(sc[t * AP + x] - mx);
      sc[t * AP + x] = e;
      sum += e;
    }
    float inv = cinv[t] / sum;
    for (int x = 0; x < NW; x++) sc[t * AP + x] *= inv;
  }
  __syncthreads();
#pragma unroll
  for (int j = 0; j < 4; j++) {
    int p = t + j * 256;
    int w = p >> 4, d4 = p & 15;
    size_t src = (size_t)(b * NS + idxs[w]) * NE + h * ND + 4 * d4;
    *(float4*)&ks[w * AP + 4 * d4] = *(const float4*)(v + src);
  }
  __syncthreads();
#pragma unroll
  for (int j = 0; j < 4; j++) {
    int p = t + j * 256;
    int w = p >> 4, d4 = p & 15;
    float4 o4 = make_float4(0.f, 0.f, 0.f, 0.f);
    for (int x = 0; x < NW; x++) {
      float s = sc[w * AP + x];
      float4 kv = *(const float4*)&ks[x * AP + 4 * d4];
      o4.x += s * kv.x;
      o4.y += s * kv.y;
      o4.z += s * kv.z;
      o4.w += s * kv.w;
    }
    *(float4*)&qs[w * AP + 4 * d4] = o4;
  }
  __syncthreads();
  for (int p = t; p < NW * ND; p += 256) {
    int w = p >> 6, d = p & (ND - 1);
    atomicAdd(&obuf[(size_t)(b * NS + idxs[w]) * NE + h * ND + d], qs[w * AP + d]);
  }
}

// ---------------- head ----------------
__global__ __launch_bounds__(256) void head_kernel(
    const float* __restrict__ x, const void* __restrict__ hw, void* __restrict__ out, int f32) {
  int gw = (blockIdx.x * 256 + threadIdx.x) >> 6;
  int lane = threadIdx.x & 63;
  if (gw >= NTOK * NVOC) return;
  int row = gw / NVOC, vv = gw % NVOC;
  const float* xr = x + (size_t)row * NE;
  float acc = 0.f;
  for (int e = lane; e < NE; e += 64) acc += xr[e] * ldw(hw, (size_t)vv * NE + e, f32);
#pragma unroll
  for (int o = 32; o; o >>= 1) acc += __shfl_down(acc, o);
  if (lane == 0) {
    if (f32) ((float*)out)[(size_t)row * NVOC + vv] = acc;
    else ((bf16*)out)[(size_t)row * NVOC + vv] = __float2bfloat16(acc);
  }
}

extern "C" void kernel_launch(void* const* d_in, const int* in_sizes, int n_in,
                              void* d_out, int out_size, void* d_ws, size_t ws_size,
                              hipStream_t stream) {
  const int* value = (const int*)d_in[0];
  const int* depth = (const int*)d_in[1];
  const int* pos = (const int*)d_in[2];
  const void* sos = d_in[3];
  const void* tok_emb = d_in[4];
  const void* depth_emb = d_in[5];
  const void* pos_emb = d_in[6];
  const void* ln1_s = d_in[7];
  const void* ln1_b = d_in[8];
  const void* Wq = d_in[9];
  const void* Wk = d_in[10];
  const void* Wv = d_in[11];
  const void* Wo = d_in[12];
  const void* means = d_in[13];
  const void* ln2_s = d_in[14];
  const void* ln2_b = d_in[15];
  const void* W1 = d_in[16];
  const void* b1 = d_in[17];
  const void* W2 = d_in[18];
  const void* b2 = d_in[19];
  const void* head_w = d_in[20];
  (void)n_in;

  int f32 = (in_sizes[4] != 17408) ? 1 : 0;

  const size_t NX = (size_t)NTOK * NE;
  const size_t NEED = 170917896ULL;
  if (ws_size < NEED) {
    float val = (float)(unsigned)(ws_size >> 20) * 1000.0f;
    fill_out_kernel<<<(out_size + 255) / 256, 256, 0, stream>>>((float*)d_out, out_size, val);
    return;
  }

  float* xbuf = (float*)d_ws;
  float* hbuf = xbuf + NX;       // LN1 out / qT / attn accumulator (time-shared)
  float* qbuf = hbuf + NX;
  float* kbuf = qbuf + NX;
  float* vbuf = kbuf + NX;
  double* mndbuf = (double*)(vbuf + NX);
  double* rqdbuf = mndbuf + (size_t)NL * NH * NC * ND;
  float* cntbuf = (float*)(rqdbuf + (size_t)NTOK * NH);
  int* idxbuf = (int*)(cntbuf + (size_t)NTOK * NH);
  float* mid = kbuf;             // FFN mid: spans kbuf+vbuf (64 MiB) for 8192-token chunks

  mnd_kernel<<<NL * NH * NC, 64, 0, stream>>>(means, mndbuf, f32);
  embed_kernel<<<(int)((NX + 255) / 256), 256, 0, stream>>>(
      value, depth, pos, sos, tok_emb, depth_emb, pos_emb, xbuf, f32);

  dim3 g512(NE / 128, NTOK / 128);
  dim3 gkv(8, NTOK / 128);
  const int CH = 8192;
  dim3 gW1(NF / 128, CH / 128);              // (16, 64)
  dim3 gW2(NE / 128, CH / 128);              // (4, 64)

  if (f32) {
    const float* Wqf = (const float*)Wq;
    const float* Wkf = (const float*)Wk;
    const float* Wvf = (const float*)Wv;
    const float* Wof = (const float*)Wo;
    const float* W1f = (const float*)W1;
    const float* W2f = (const float*)W2;
    const float* b1f = (const float*)b1;
    const float* b2f = (const float*)b2;
    for (int l = 0; l < NL; l++) {
      size_t o_w = (size_t)l * NE * NE;
      size_t o_w1 = (size_t)l * NE * NF;
      size_t o_w2 = (size_t)l * NF * NE;
      size_t o_e = (size_t)l * NE;
      size_t o_f = (size_t)l * NF;

      ln_kernel<<<NTOK / 4, 256, 0, stream>>>(xbuf, ln1_s, ln1_b, o_e, hbuf, 1);
      // q: 6-product (routing-critical, 2^-24); k,v: 3-product (no discrete risk)
      gemm_mfma_kernel<0, 1><<<g512, 256, 0, stream>>>(hbuf, Wqf + o_w, NE, nullptr, nullptr,
                                                       qbuf, NE, NE);
      gemm_kv_mfma<<<gkv, 256, 0, stream>>>(hbuf, Wkf, Wvf, o_w, kbuf, vbuf);

      qt_kernel<<<NB * NH * 64, 256, 0, stream>>>(qbuf, hbuf, rqdbuf);
      zero_kernel<<<(NTOK * NH) / 256, 256, 0, stream>>>(cntbuf, NTOK * NH);
      route_kernel<<<NB * NH * NC, 256, 0, stream>>>(
          hbuf, mndbuf + (size_t)l * NH * NC * ND, rqdbuf, idxbuf, cntbuf);

      zero_kernel<<<(int)((NX + 255) / 256), 256, 0, stream>>>(hbuf, (int)NX);
      attn_kernel<<<NB * NH * NC, 256, 0, stream>>>(qbuf, kbuf, vbuf, idxbuf, value, cntbuf, hbuf);
      gemm_mfma_kernel<0, 0><<<g512, 256, 0, stream>>>(hbuf, Wof + o_w, NE, nullptr, xbuf,
                                                       xbuf, NE, NE);

      ln_kernel<<<NTOK / 4, 256, 0, stream>>>(xbuf, ln2_s, ln2_b, o_e, qbuf, 1);
      // FFN: 2 token-chunks of 8192; mid (8192x2048 fp32 = 64 MiB) spans kbuf+vbuf
      for (int mc = 0; mc < NTOK / CH; mc++) {
        const float* hch = qbuf + (size_t)mc * CH * NE;
        float* xch = xbuf + (size_t)mc * CH * NE;
        gemm_mfma_kernel<1, 0><<<gW1, 256, 0, stream>>>(hch, W1f + o_w1, NF, b1f + o_f,
                                                        nullptr, mid, NF, NE);
        gemm_mfma_kernel<0, 0><<<gW2, 256, 0, stream>>>(mid, W2f + o_w2, NE, b2f + o_e,
                                                        xch, xch, NE, NF);
      }
    }
  } else {
    dim3 gqkvv(12, NTOK / 128);
    for (int l = 0; l < NL; l++) {
      size_t o_w = (size_t)l * NE * NE;
      size_t o_w1 = (size_t)l * NE * NF;
      size_t o_w2 = (size_t)l * NF * NE;
      size_t o_e = (size_t)l * NE;
      size_t o_f = (size_t)l * NF;

      ln_kernel<<<NTOK / 4, 256, 0, stream>>>(xbuf, ln1_s, ln1_b, o_e, hbuf, 0);
      gemm_qkv_kernel<<<gqkvv, 256, 0, stream>>>(hbuf, Wq, Wk, Wv, o_w, qbuf, kbuf, vbuf, 0);

      qt_kernel<<<NB * NH * 64, 256, 0, stream>>>(qbuf, hbuf, rqdbuf);
      zero_kernel<<<(NTOK * NH) / 256, 256, 0, stream>>>(cntbuf, NTOK * NH);
      route_kernel<<<NB * NH * NC, 256, 0, stream>>>(
          hbuf, mndbuf + (size_t)l * NH * NC * ND, rqdbuf, idxbuf, cntbuf);

      zero_kernel<<<(int)((NX + 255) / 256), 256, 0, stream>>>(hbuf, (int)NX);
      attn_kernel<<<NB * NH * NC, 256, 0, stream>>>(qbuf, kbuf, vbuf, idxbuf, value, cntbuf, hbuf);
      gemm_kernel<0><<<g512, 256, 0, stream>>>(hbuf, Wo, o_w, NE, nullptr, 0, xbuf,
                                               xbuf, NE, NE, 0);

      ln_kernel<<<NTOK / 4, 256, 0, stream>>>(xbuf, ln2_s, ln2_b, o_e, qbuf, 0);
      for (int ch = 0; ch < NTOK / CH; ch++) {
        const float* hch = qbuf + (size_t)ch * CH * NE;
        float* xch = xbuf + (size_t)ch * CH * NE;
        gemm_kernel<1><<<gW1, 256, 0, stream>>>(hch, W1, o_w1, NF, b1, o_f, nullptr,
                                                mid, NF, NE, 0);
        gemm_kernel<0><<<gW2, 256, 0, stream>>>(mid, W2, o_w2, NE, b2, o_e, xch,
                                                xch, NE, NF, 0);
      }
    }
  }

  head_kernel<<<(NTOK * NVOC * 64 + 255) / 256, 256, 0, stream>>>(xbuf, head_w, d_out, f32);
}

// Round 13
// 3658.757 us; speedup vs baseline: 1.6370x; 1.0348x over previous
//
#include <hip/hip_runtime.h>
#include <hip/hip_bf16.h>
#include <math.h>

typedef __hip_bfloat16 bf16;
typedef __attribute__((ext_vector_type(2))) float f2v;
typedef __attribute__((ext_vector_type(8))) short bf16x8;
typedef __attribute__((ext_vector_type(4))) float f32x4;

#define NB 4
#define NS 4096
#define NE 512
#define NH 8
#define NL 4
#define NA 3
#define ND 64
#define NC 64
#define NW 64
#define NF 2048
#define NVOC 17
#define NTOK (NB * NS)   // 16384
#define AP 68            // attn LDS row stride (floats)

__device__ __forceinline__ float b2f(bf16 v) { return __bfloat162float(v); }
__device__ __forceinline__ float u2f(unsigned short u) { return __uint_as_float((unsigned)u << 16); }
__device__ __forceinline__ float ldw(const void* p, size_t i, int f32) {
  return f32 ? ((const float*)p)[i] : b2f(((const bf16*)p)[i]);
}
__device__ __forceinline__ unsigned short f2bf(float f) {   // RNE fp32->bf16
  unsigned u = __float_as_uint(f);
  return (unsigned short)((u + 0x7FFFu + ((u >> 16) & 1u)) >> 16);
}

// ---------------- diagnostic fill (ws_size too small) ----------------
__global__ __launch_bounds__(256) void fill_out_kernel(float* __restrict__ out, int n, float val) {
  int i = blockIdx.x * 256 + threadIdx.x;
  if (i < n) out[i] = val;
}

// ---------------- zero fill ----------------
__global__ __launch_bounds__(256) void zero_kernel(float* __restrict__ p, int n) {
  int i = blockIdx.x * 256 + threadIdx.x;
  if (i < n) p[i] = 0.f;
}

// ---------------- embeddings + shift-right ----------------
__global__ __launch_bounds__(256) void embed_kernel(
    const int* __restrict__ value, const int* __restrict__ depth, const int* __restrict__ pos,
    const void* __restrict__ sos, const void* __restrict__ tok_emb,
    const void* __restrict__ depth_emb, const void* __restrict__ pos_emb,
    float* __restrict__ x, int f32) {
  int i = blockIdx.x * 256 + threadIdx.x;
  if (i >= NTOK * NE) return;
  int e = i & (NE - 1);
  int bs = i >> 9;
  int s = bs & (NS - 1);
  int b = bs >> 12;
  float v;
  if (s == 0) {
    v = ldw(sos, e, f32);
  } else {
    int src = b * NS + (s - 1);
    float acc = ldw(tok_emb, (size_t)value[src] * NE + e, f32)
              + ldw(depth_emb, (size_t)depth[src] * NE + e, f32);
#pragma unroll
    for (int a = 0; a < NA; a++)
      acc += ldw(pos_emb, ((size_t)a * 65 + pos[src * NA + a]) * NE + e, f32);
    v = acc;
  }
  x[i] = v;
}

// ---------------- layer norm, one wave per row ----------------
__global__ __launch_bounds__(256) void ln_kernel(
    const float* __restrict__ x, const void* __restrict__ gam, const void* __restrict__ bet,
    size_t off, float* __restrict__ out, int f32) {
  int row = blockIdx.x * 4 + (threadIdx.x >> 6);
  int lane = threadIdx.x & 63;
  const float* xr = x + (size_t)row * NE;
  float v[8];
#pragma unroll
  for (int i = 0; i < 8; i++) v[i] = xr[lane + i * 64];
  float s = 0.f;
#pragma unroll
  for (int i = 0; i < 8; i++) s += v[i];
#pragma unroll
  for (int o = 32; o; o >>= 1) s += __shfl_xor(s, o);
  float m = s * (1.0f / NE);
  float sq = 0.f;
#pragma unroll
  for (int i = 0; i < 8; i++) { float d = v[i] - m; sq += d * d; }
#pragma unroll
  for (int o = 32; o; o >>= 1) sq += __shfl_xor(sq, o);
  float rs = 1.0f / sqrtf(sq * (1.0f / NE) + 1e-5f);
  float* orow = out + (size_t)row * NE;
#pragma unroll
  for (int i = 0; i < 8; i++) {
    int e = lane + i * 64;
    orow[e] = (v[i] - m) * rs * ldw(gam, off + e, f32) + ldw(bet, off + e, f32);
  }
}

// ---------------- fp32 vector GEMM core (bf16-input fallback path) ----------------
template <int ACT>
__device__ __forceinline__ void gemm_body(
    const float* __restrict__ A, const void* __restrict__ Bw, size_t bwoff, int ldb,
    const void* bias, size_t biasoff, const float* resid, float* C,
    int N, int K, int f32, int bm, int bn) {
  __shared__ float As[32][132];
  __shared__ float Bs[32][132];
  int tid = threadIdx.x;
  int ty = tid >> 4, tx = tid & 15;
  f2v acc2[8][4];
#pragma unroll
  for (int i = 0; i < 8; i++)
#pragma unroll
    for (int j = 0; j < 4; j++) acc2[i][j] = (f2v){0.f, 0.f};
  int arow = tid >> 1;
  int acol = (tid & 1) << 4;
  int brow = tid >> 3;
  int bcol = (tid & 7) << 4;

  const float* Aptr = A + (size_t)(bm + arow) * K + acol;
  float4 pa[4];
  float4 pb[4];
  uint4 pbu[2];
#pragma unroll
  for (int j = 0; j < 4; j++) pa[j] = *(const float4*)(Aptr + 4 * j);
  {
    size_t boff = bwoff + (size_t)brow * ldb + bn + bcol;
    if (f32) {
#pragma unroll
      for (int j = 0; j < 4; j++) pb[j] = *(const float4*)((const float*)Bw + boff + 4 * j);
    } else {
      pbu[0] = *(const uint4*)((const bf16*)Bw + boff);
      pbu[1] = *(const uint4*)((const bf16*)Bw + boff + 8);
    }
  }

  for (int k0 = 0; k0 < K; k0 += 32) {
#pragma unroll
    for (int j = 0; j < 4; j++) {
      As[acol + 4 * j + 0][arow] = pa[j].x;
      As[acol + 4 * j + 1][arow] = pa[j].y;
      As[acol + 4 * j + 2][arow] = pa[j].z;
      As[acol + 4 * j + 3][arow] = pa[j].w;
    }
    if (f32) {
#pragma unroll
      for (int j = 0; j < 4; j++) {
        Bs[brow][bcol + 4 * j + 0] = pb[j].x;
        Bs[brow][bcol + 4 * j + 1] = pb[j].y;
        Bs[brow][bcol + 4 * j + 2] = pb[j].z;
        Bs[brow][bcol + 4 * j + 3] = pb[j].w;
      }
    } else {
      union { uint4 u; unsigned short s[8]; } r0, r1;
      r0.u = pbu[0]; r1.u = pbu[1];
#pragma unroll
      for (int j = 0; j < 8; j++) Bs[brow][bcol + j] = u2f(r0.s[j]);
#pragma unroll
      for (int j = 0; j < 8; j++) Bs[brow][bcol + 8 + j] = u2f(r1.s[j]);
    }
    __syncthreads();
    if (k0 + 32 < K) {
#pragma unroll
      for (int j = 0; j < 4; j++) pa[j] = *(const float4*)(Aptr + k0 + 32 + 4 * j);
      size_t boff = bwoff + (size_t)(k0 + 32 + brow) * ldb + bn + bcol;
      if (f32) {
#pragma unroll
        for (int j = 0; j < 4; j++) pb[j] = *(const float4*)((const float*)Bw + boff + 4 * j);
      } else {
        pbu[0] = *(const uint4*)((const bf16*)Bw + boff);
        pbu[1] = *(const uint4*)((const bf16*)Bw + boff + 8);
      }
    }
#pragma unroll
    for (int kk = 0; kk < 32; kk++) {
      float4 aA = *(const float4*)&As[kk][ty << 3];
      float4 aB = *(const float4*)&As[kk][(ty << 3) + 4];
      float4 bA = *(const float4*)&Bs[kk][tx << 2];
      float4 bB = *(const float4*)&Bs[kk][64 + (tx << 2)];
      float av[8] = {aA.x, aA.y, aA.z, aA.w, aB.x, aB.y, aB.z, aB.w};
      f2v bv[4];
      bv[0] = (f2v){bA.x, bA.y};
      bv[1] = (f2v){bA.z, bA.w};
      bv[2] = (f2v){bB.x, bB.y};
      bv[3] = (f2v){bB.z, bB.w};
#pragma unroll
      for (int i = 0; i < 8; i++)
#pragma unroll
        for (int j = 0; j < 4; j++)
          acc2[i][j] += bv[j] * av[i];
    }
    __syncthreads();
  }
#pragma unroll
  for (int i = 0; i < 8; i++) {
    int row = bm + (ty << 3) + i;
    int c0 = bn + (tx << 2);
    int c1 = bn + 64 + (tx << 2);
    const float* ap = (const float*)&acc2[i][0];
    float o0[4], o1[4];
#pragma unroll
    for (int j = 0; j < 4; j++) { o0[j] = ap[j]; o1[j] = ap[4 + j]; }
    if (bias) {
#pragma unroll
      for (int j = 0; j < 4; j++) {
        o0[j] += ldw(bias, biasoff + c0 + j, f32);
        o1[j] += ldw(bias, biasoff + c1 + j, f32);
      }
    }
    if (ACT == 1) {
#pragma unroll
      for (int j = 0; j < 4; j++) {
        float t0 = 0.7978845608028654f * (o0[j] + 0.044715f * o0[j] * o0[j] * o0[j]);
        o0[j] = 0.5f * o0[j] * (1.0f + tanhf(t0));
        float t1 = 0.7978845608028654f * (o1[j] + 0.044715f * o1[j] * o1[j] * o1[j]);
        o1[j] = 0.5f * o1[j] * (1.0f + tanhf(t1));
      }
    }
    size_t p0 = (size_t)row * N + c0;
    size_t p1 = (size_t)row * N + c1;
    if (resid) {
      float4 r0 = *(const float4*)(resid + p0);
      float4 r1 = *(const float4*)(resid + p1);
      o0[0] += r0.x; o0[1] += r0.y; o0[2] += r0.z; o0[3] += r0.w;
      o1[0] += r1.x; o1[1] += r1.y; o1[2] += r1.z; o1[3] += r1.w;
    }
    *(float4*)(C + p0) = make_float4(o0[0], o0[1], o0[2], o0[3]);
    *(float4*)(C + p1) = make_float4(o1[0], o1[1], o1[2], o1[3]);
  }
}

template <int ACT>
__global__ __launch_bounds__(256) void gemm_kernel(
    const float* __restrict__ A, const void* __restrict__ Bw, size_t bwoff, int ldb,
    const void* bias, size_t biasoff, const float* resid, float* C,
    int N, int K, int f32) {
  gemm_body<ACT>(A, Bw, bwoff, ldb, bias, biasoff, resid, C, N, K,
                 f32, blockIdx.y << 7, blockIdx.x << 7);
}

__global__ __launch_bounds__(256) void gemm_qkv_kernel(
    const float* __restrict__ A,
    const void* __restrict__ Wq, const void* __restrict__ Wk, const void* __restrict__ Wv,
    size_t bwoff, float* __restrict__ Cq, float* __restrict__ Ck, float* __restrict__ Cv,
    int f32) {
  int sel = blockIdx.x >> 2;
  const void* Bw = (sel == 0) ? Wq : ((sel == 1) ? Wk : Wv);
  float* C = (sel == 0) ? Cq : ((sel == 1) ? Ck : Cv);
  gemm_body<0>(A, Bw, bwoff, NE, nullptr, 0, nullptr, C, NE, NE,
               f32, blockIdx.y << 7, (blockIdx.x & 3) << 7);
}

// ---------------- MFMA GEMM for fp32 A x fp32 W ----------------
// FULL=1: 3-way splits, 6 products ~2^-24. q only. FULL=0: 2-way, 3 products ~2^-18.
// ATOMIC=1: partial-K contribution atomicAdd'ed into C (C pre-holds residual; bias
// passed non-null only for the k-slice that should add it). ACT must be 0 with ATOMIC.
// Layout = round-7 measured best: [128][40] planes; B staged Bx[n][k'] with chunk
// swizzle k' = k ^ (((n>>4)&3)<<3); frag read at chunk (lg^ni)&3 recovers k-chunk lg.
template <int ACT, int FULL, int ATOMIC>
__device__ __forceinline__ void mfma_body(
    const float* __restrict__ A, int ldak, const float* __restrict__ Bw, int ldb,
    const float* __restrict__ bias, const float* __restrict__ resid, float* __restrict__ C,
    int N, int klen, int bm, int bn) {
  __shared__ unsigned short Ah[128][40];
  __shared__ unsigned short Am[128][40];
  __shared__ unsigned short Al[FULL ? 128 : 1][40];
  __shared__ unsigned short Bh[128][40];
  __shared__ unsigned short Bm[128][40];
  __shared__ unsigned short Bl[FULL ? 128 : 1][40];
  int t = threadIdx.x;
  int arow = t >> 1;
  int akc = (t & 1) << 4;
  const float* Ap = A + (size_t)(bm + arow) * ldak + akc;
  int bkr = t >> 3;
  int bcg = t & 7;
  const float* Bp = Bw + (size_t)bkr * ldb + bn + bcg * 16;
  int bkpos = bkr ^ ((bcg & 3) << 3);

  float4 pa[4], pb[4];
#pragma unroll
  for (int j = 0; j < 4; j++) pa[j] = *(const float4*)(Ap + 4 * j);
#pragma unroll
  for (int j = 0; j < 4; j++) pb[j] = *(const float4*)(Bp + 4 * j);

  int lane = t & 63;
  int wid = t >> 6;
  int wr = wid >> 1, wc = wid & 1;
  int lr = lane & 15, lg = lane >> 4;

  f32x4 acc[4][4];
#pragma unroll
  for (int i = 0; i < 4; i++)
#pragma unroll
    for (int j = 0; j < 4; j++) acc[i][j] = (f32x4){0.f, 0.f, 0.f, 0.f};

  for (int k0 = 0; k0 < klen; k0 += 32) {
    {
      unsigned hs[8], ms[8], ls[8];
#pragma unroll
      for (int j = 0; j < 4; j++) {
        const float* pf = (const float*)&pa[j];
#pragma unroll
        for (int e = 0; e < 2; e++) {
          float a0 = pf[2 * e], a1 = pf[2 * e + 1];
          unsigned short h0 = f2bf(a0), h1 = f2bf(a1);
          float r0 = a0 - u2f(h0), r1 = a1 - u2f(h1);
          unsigned short m0 = f2bf(r0), m1 = f2bf(r1);
          hs[2 * j + e] = (unsigned)h0 | ((unsigned)h1 << 16);
          ms[2 * j + e] = (unsigned)m0 | ((unsigned)m1 << 16);
          if (FULL) {
            float s0 = r0 - u2f(m0), s1 = r1 - u2f(m1);
            unsigned short l0 = f2bf(s0), l1 = f2bf(s1);
            ls[2 * j + e] = (unsigned)l0 | ((unsigned)l1 << 16);
          }
        }
      }
      *(uint4*)&Ah[arow][akc]     = make_uint4(hs[0], hs[1], hs[2], hs[3]);
      *(uint4*)&Ah[arow][akc + 8] = make_uint4(hs[4], hs[5], hs[6], hs[7]);
      *(uint4*)&Am[arow][akc]     = make_uint4(ms[0], ms[1], ms[2], ms[3]);
      *(uint4*)&Am[arow][akc + 8] = make_uint4(ms[4], ms[5], ms[6], ms[7]);
      if (FULL) {
        *(uint4*)&Al[arow][akc]     = make_uint4(ls[0], ls[1], ls[2], ls[3]);
        *(uint4*)&Al[arow][akc + 8] = make_uint4(ls[4], ls[5], ls[6], ls[7]);
      }
    }
    {
#pragma unroll
      for (int j = 0; j < 4; j++) {
        const float* pf = (const float*)&pb[j];
#pragma unroll
        for (int e = 0; e < 4; e++) {
          float a = pf[e];
          unsigned short h = f2bf(a);
          float r = a - u2f(h);
          unsigned short m = f2bf(r);
          int nn = bcg * 16 + 4 * j + e;
          Bh[nn][bkpos] = h;
          Bm[nn][bkpos] = m;
          if (FULL) {
            float s = r - u2f(m);
            Bl[nn][bkpos] = f2bf(s);
          }
        }
      }
    }
    __syncthreads();
    if (k0 + 32 < klen) {
#pragma unroll
      for (int j = 0; j < 4; j++) pa[j] = *(const float4*)(Ap + k0 + 32 + 4 * j);
      const float* Bn = Bp + (size_t)(k0 + 32) * ldb;
#pragma unroll
      for (int j = 0; j < 4; j++) pb[j] = *(const float4*)(Bn + 4 * j);
    }
    bf16x8 fbh[4], fbm[4], fbl[4];
#pragma unroll
    for (int ni = 0; ni < 4; ni++) {
      int rb = wc * 64 + ni * 16 + lr;
      int cb = ((lg ^ ni) & 3) * 8;
      fbh[ni] = *(const bf16x8*)&Bh[rb][cb];
      fbm[ni] = *(const bf16x8*)&Bm[rb][cb];
      if (FULL) fbl[ni] = *(const bf16x8*)&Bl[rb][cb];
    }
#pragma unroll
    for (int mi = 0; mi < 4; mi++) {
      int ar = wr * 64 + mi * 16 + lr;
      bf16x8 fh = *(const bf16x8*)&Ah[ar][lg * 8];
      bf16x8 fm = *(const bf16x8*)&Am[ar][lg * 8];
      bf16x8 fl;
      if (FULL) fl = *(const bf16x8*)&Al[ar][lg * 8];
#pragma unroll
      for (int ni = 0; ni < 4; ni++) {
        f32x4 a = acc[mi][ni];
        a = __builtin_amdgcn_mfma_f32_16x16x32_bf16(fh, fbh[ni], a, 0, 0, 0);
        a = __builtin_amdgcn_mfma_f32_16x16x32_bf16(fh, fbm[ni], a, 0, 0, 0);
        a = __builtin_amdgcn_mfma_f32_16x16x32_bf16(fm, fbh[ni], a, 0, 0, 0);
        if (FULL) {
          a = __builtin_amdgcn_mfma_f32_16x16x32_bf16(fm, fbm[ni], a, 0, 0, 0);
          a = __builtin_amdgcn_mfma_f32_16x16x32_bf16(fh, fbl[ni], a, 0, 0, 0);
          a = __builtin_amdgcn_mfma_f32_16x16x32_bf16(fl, fbh[ni], a, 0, 0, 0);
        }
        acc[mi][ni] = a;
      }
    }
    __syncthreads();
  }
#pragma unroll
  for (int mi = 0; mi < 4; mi++) {
#pragma unroll
    for (int ni = 0; ni < 4; ni++) {
      int col = bn + wc * 64 + ni * 16 + lr;
      int rbase = bm + wr * 64 + mi * 16 + lg * 4;
      float bv = bias ? bias[col] : 0.f;
      const float* av = (const float*)&acc[mi][ni];
#pragma unroll
      for (int r = 0; r < 4; r++) {
        float o = av[r] + bv;
        size_t p = (size_t)(rbase + r) * N + col;
        if (ATOMIC) {
          atomicAdd(&C[p], o);
        } else {
          if (ACT == 1) {
            float t0 = 0.7978845608028654f * (o + 0.044715f * o * o * o);
            o = 0.5f * o * (1.0f + tanhf(t0));
          }
          if (resid) o += resid[p];
          C[p] = o;
        }
      }
    }
  }
}

template <int ACT, int FULL>
__global__ __launch_bounds__(256) void gemm_mfma_kernel(
    const float* __restrict__ A, const float* __restrict__ Bw, int ldb,
    const float* __restrict__ bias, const float* __restrict__ resid, float* __restrict__ C,
    int N, int K) {
  mfma_body<ACT, FULL, 0>(A, K, Bw, ldb, bias, resid, C, N, K,
                          blockIdx.y << 7, blockIdx.x << 7);
}

// split-K MFMA (3-product): blockIdx.z = K-slice; partials atomicAdd'ed into C
// (C pre-holds residual); bias added only by slice 0.
__global__ __launch_bounds__(256) void gemm_mfma_splitk_kernel(
    const float* __restrict__ A, int ldak, const float* __restrict__ Bw, int ldb,
    const float* __restrict__ bias, float* __restrict__ C, int N, int klen) {
  int kbase = blockIdx.z * klen;
  mfma_body<0, 0, 1>(A + kbase, ldak, Bw + (size_t)kbase * ldb, ldb,
                     (kbase == 0) ? bias : nullptr, nullptr, C, N, klen,
                     blockIdx.y << 7, blockIdx.x << 7);
}

// fused k/v MFMA (3-product): blockIdx.x in [0,8): sel = x>>2, col block x&3
__global__ __launch_bounds__(256) void gemm_kv_mfma(
    const float* __restrict__ A, const float* __restrict__ Wk, const float* __restrict__ Wv,
    size_t off, float* __restrict__ Ck, float* __restrict__ Cv) {
  int sel = blockIdx.x >> 2;
  const float* Bw = sel ? Wv : Wk;
  float* C = sel ? Cv : Ck;
  mfma_body<0, 0, 0>(A, NE, Bw + off, NE, nullptr, nullptr, C, NE, NE,
                     blockIdx.y << 7, (blockIdx.x & 3) << 7);
}

// ---------------- q transpose + fused rq: qT[b][h][d][n], rqd[b][h][n] ----------------
__global__ __launch_bounds__(256) void qt_kernel(const float* __restrict__ q, float* __restrict__ qT,
                                                 double* __restrict__ rqd) {
  __shared__ float tile[64][65];
  int bid = blockIdx.x;
  int st = bid & 63;
  int bh = bid >> 6;
  int b = bh >> 3, h = bh & 7;
  int s0 = st * 64;
  int t = threadIdx.x;
#pragma unroll
  for (int k = 0; k < 16; k++) {
    int idx = t + k * 256;
    int sl = idx >> 6, dl = idx & 63;
    tile[sl][dl] = q[(size_t)(b * NS + s0 + sl) * NE + h * ND + dl];
  }
  __syncthreads();
#pragma unroll
  for (int k = 0; k < 16; k++) {
    int idx = t + k * 256;
    int dl = idx >> 6, sl = idx & 63;
    qT[((size_t)bh * 64 + dl) * NS + s0 + sl] = tile[sl][dl];
  }
  int w = t >> 6, lane = t & 63;
#pragma unroll
  for (int i = 0; i < 16; i++) {
    int tok = w * 16 + i;
    double v = (double)tile[tok][lane];
    double ss = v * v;
#pragma unroll
    for (int o = 32; o; o >>= 1) ss += __shfl_xor(ss, o);
    if (lane == 0) rqd[((size_t)bh << 12) | (s0 + tok)] = 1.0 / (sqrt(ss) + 1e-8);
  }
}

// ---------------- normalized means in fp64 ----------------
__global__ __launch_bounds__(64) void mnd_kernel(const void* __restrict__ means,
                                                 double* __restrict__ mnd, int f32) {
  __shared__ double s[64];
  int vblk = blockIdx.x;
  int d = threadIdx.x;
  double m = (double)ldw(means, (size_t)vblk * ND + d, f32);
  s[d] = m * m;
  __syncthreads();
  for (int st = 32; st; st >>= 1) { if (d < st) s[d] += s[d + st]; __syncthreads(); }
  mnd[(size_t)vblk * ND + d] = m / (sqrt(s[0]) + 1e-8);
}

// ---------------- routing: fp64 dists (coalesced qT) + exact top-64 + fused cnt ----------------
__global__ __launch_bounds__(256) void route_kernel(
    const float* __restrict__ qT, const double* __restrict__ mnd,
    const double* __restrict__ rqd, int* __restrict__ idxout, float* __restrict__ cnt) {
  __shared__ unsigned long long keys[NS];
  __shared__ double mc[ND];
  __shared__ unsigned hist[256];
  __shared__ unsigned short cand[2][NS];
  __shared__ unsigned s_rem, s_cnt, s_sel, s_cc[2];
  int bid = blockIdx.x;
  int h = bid & 7;
  int b = (bid >> 3) & 3;
  int c = bid >> 5;
  int bhc = ((b * NH + h) * NC) + c;
  int t = threadIdx.x;
  if (t < ND) mc[t] = mnd[((size_t)h * NC + c) * ND + t];
  hist[t] = 0u;
  if (t == 0) { s_rem = NW; s_cnt = 0u; s_cc[0] = 0u; s_cc[1] = 0u; }
  __syncthreads();
  const float* qTb = qT + (size_t)(b * NH + h) * 64 * NS;
  const double* rqb = rqd + ((size_t)(b * NH + h) << 12);
  for (int i = 0; i < 16; i += 4) {
    int n0 = t + i * 256, n1 = n0 + 256, n2 = n0 + 512, n3 = n0 + 768;
    double a0 = 0.0, a1 = 0.0, a2 = 0.0, a3 = 0.0;
#pragma unroll 8
    for (int d = 0; d < 64; d++) {
      const float* row = qTb + (size_t)d * NS;
      double m = mc[d];
      a0 += (double)row[n0] * m;
      a1 += (double)row[n1] * m;
      a2 += (double)row[n2] * m;
      a3 += (double)row[n3] * m;
    }
    double dv[4] = {a0 * rqb[n0], a1 * rqb[n1], a2 * rqb[n2], a3 * rqb[n3]};
    int nn[4] = {n0, n1, n2, n3};
#pragma unroll
    for (int j = 0; j < 4; j++) {
      long long sb = __double_as_longlong(dv[j]);
      unsigned long long u = (unsigned long long)sb;
      u = (sb < 0) ? ~u : (u | 0x8000000000000000ULL);
      keys[nn[j]] = (u & 0xFFFFFFFFFFFFF000ULL) | (unsigned long long)(NS - 1 - nn[j]);
    }
  }
  __syncthreads();
  {
    unsigned lastd = 0xFFFFFFFFu, lcnt = 0u;
    for (int n = t; n < NS; n += 256) {
      unsigned d = (unsigned)(keys[n] >> 56);
      if (d == lastd) { lcnt++; }
      else { if (lcnt) atomicAdd(&hist[lastd], lcnt); lastd = d; lcnt = 1u; }
    }
    if (lcnt) atomicAdd(&hist[lastd], lcnt);
  }
  __syncthreads();
  if (t < 64) {
    unsigned h0 = hist[4 * t + 0], h1 = hist[4 * t + 1];
    unsigned h2 = hist[4 * t + 2], h3 = hist[4 * t + 3];
    hist[4 * t + 0] = 0u; hist[4 * t + 1] = 0u; hist[4 * t + 2] = 0u; hist[4 * t + 3] = 0u;
    unsigned t3 = h3, t2 = h2 + h3, t1 = h1 + t2, t0 = h0 + t1;
    unsigned s = t0;
#pragma unroll
    for (int off = 1; off < 64; off <<= 1) {
      unsigned v = __shfl_down(s, off);
      if (t + off < 64) s += v;
    }
    unsigned E = s - t0;
    unsigned rem = s_rem;
    unsigned sf0 = t0 + E, sf1 = t1 + E, sf2 = t2 + E, sf3 = t3 + E, sf4 = E;
    if (sf0 >= rem && sf1 < rem) { s_sel = 4u * t + 0u; s_rem = rem - sf1; }
    if (sf1 >= rem && sf2 < rem) { s_sel = 4u * t + 1u; s_rem = rem - sf2; }
    if (sf2 >= rem && sf3 < rem) { s_sel = 4u * t + 2u; s_rem = rem - sf3; }
    if (sf3 >= rem && sf4 < rem) { s_sel = 4u * t + 3u; s_rem = rem - sf4; }
  }
  __syncthreads();
  {
    unsigned sel = s_sel;
    for (int n = t; n < NS; n += 256) {
      unsigned d = (unsigned)(keys[n] >> 56);
      if (d > sel) {
        unsigned p = atomicAdd(&s_cnt, 1u);
        idxout[(size_t)bhc * NW + p] = n;
        atomicAdd(&cnt[(size_t)(b * NS + n) * NH + h], 1.0f);
      } else if (d == sel) {
        unsigned p = atomicAdd(&s_cc[0], 1u);
        cand[0][p] = (unsigned short)n;
      }
    }
  }
  __syncthreads();
  int cur = 0;
  for (int p = 6; p >= 0; p--) {
    int sh = p * 8;
    unsigned nc = s_cc[cur];
    for (unsigned i = t; i < nc; i += 256) {
      unsigned d = (unsigned)((keys[cand[cur][i]] >> sh) & 255ULL);
      atomicAdd(&hist[d], 1u);
    }
    __syncthreads();
    if (t < 64) {
      unsigned h0 = hist[4 * t + 0], h1 = hist[4 * t + 1];
      unsigned h2 = hist[4 * t + 2], h3 = hist[4 * t + 3];
      hist[4 * t + 0] = 0u; hist[4 * t + 1] = 0u; hist[4 * t + 2] = 0u; hist[4 * t + 3] = 0u;
      unsigned t3 = h3, t2 = h2 + h3, t1 = h1 + t2, t0 = h0 + t1;
      unsigned s = t0;
#pragma unroll
      for (int off = 1; off < 64; off <<= 1) {
        unsigned v = __shfl_down(s, off);
        if (t + off < 64) s += v;
      }
      unsigned E = s - t0;
      unsigned rem = s_rem;
      unsigned sf0 = t0 + E, sf1 = t1 + E, sf2 = t2 + E, sf3 = t3 + E, sf4 = E;
      if (sf0 >= rem && sf1 < rem) { s_sel = 4u * t + 0u; s_rem = rem - sf1; }
      if (sf1 >= rem && sf2 < rem) { s_sel = 4u * t + 1u; s_rem = rem - sf2; }
      if (sf2 >= rem && sf3 < rem) { s_sel = 4u * t + 2u; s_rem = rem - sf3; }
      if (sf3 >= rem && sf4 < rem) { s_sel = 4u * t + 3u; s_rem = rem - sf4; }
      if (t == 0) s_cc[cur ^ 1] = 0u;
    }
    __syncthreads();
    unsigned sel = s_sel;
    if (p == 0) {
      for (unsigned i = t; i < nc; i += 256) {
        unsigned n = cand[cur][i];
        unsigned d = (unsigned)(keys[n] & 255ULL);
        if (d >= sel) {
          unsigned pp = atomicAdd(&s_cnt, 1u);
          idxout[(size_t)bhc * NW + pp] = n;
          atomicAdd(&cnt[(size_t)(b * NS + n) * NH + h], 1.0f);
        }
      }
    } else {
      int nxt = cur ^ 1;
      for (unsigned i = t; i < nc; i += 256) {
        unsigned n = cand[cur][i];
        unsigned d = (unsigned)((keys[n] >> sh) & 255ULL);
        if (d > sel) {
          unsigned pp = atomicAdd(&s_cnt, 1u);
          idxout[(size_t)bhc * NW + pp] = n;
          atomicAdd(&cnt[(size_t)(b * NS + n) * NH + h], 1.0f);
        } else if (d == sel) {
          unsigned pp = atomicAdd(&s_cc[nxt], 1u);
          cand[nxt][pp] = (unsigned short)n;
        }
      }
      __syncthreads();
      cur = nxt;
    }
  }
}

// ---------------- bucket attention (float4 LDS, stride AP=68) ----------------
__global__ __launch_bounds__(256) void attn_kernel(
    const float* __restrict__ q, const float* __restrict__ k, const float* __restrict__ v,
    const int* __restrict__ idxb, const int* __restrict__ value, const float* __restrict__ cnt,
    float* __restrict__ obuf) {
  __shared__ float qs[NW * AP];
  __shared__ float ks[NW * AP];
  __shared__ float sc[NW * AP];
  __shared__ int idxs[NW];
  __shared__ float kmv[NW];
  __shared__ float cinv[NW];
  int bhc = blockIdx.x;
  int h = (bhc >> 6) & (NH - 1);
  int b = bhc >> 9;
  int t = threadIdx.x;
  if (t < NW) {
    int n = idxb[(size_t)bhc * NW + t];
    idxs[t] = n;
    kmv[t] = (value[b * NS + n] != 0) ? 1.f : 0.f;
    cinv[t] = 1.0f / fmaxf(cnt[(size_t)(b * NS + n) * NH + h], 1.0f);
  }
  __syncthreads();
#pragma unroll
  for (int j = 0; j < 4; j++) {
    int p = t + j * 256;
    int w = p >> 4, d4 = p & 15;
    size_t src = (size_t)(b * NS + idxs[w]) * NE + h * ND + 4 * d4;
    *(float4*)&qs[w * AP + 4 * d4] = *(const float4*)(q + src);
    *(float4*)&ks[w * AP + 4 * d4] = *(const float4*)(k + src);
  }
  __syncthreads();
#pragma unroll
  for (int j = 0; j < 16; j++) {
    int p = t + j * 256;
    int w = p >> 6, x = p & (NW - 1);
    float dot = 0.f;
#pragma unroll
    for (int i = 0; i < 16; i++) {
      float4 a = *(const float4*)&qs[w * AP + 4 * i];
      float4 bb = *(const float4*)&ks[x * AP + 4 * i];
      dot += a.x * bb.x;
      dot += a.y * bb.y;
      dot += a.z * bb.z;
      dot += a.w * bb.w;
    }
    bool allowed = (idxs[w] >= idxs[x]) && (kmv[x] != 0.f);
    sc[w * AP + x] = allowed ? dot * 0.125f : -1e9f;
  }
  __syncthreads();
  if (t < NW) {
    float mx = -3.4e38f;
    for (int x = 0; x < NW; x++) mx = fmaxf(mx, sc[t * AP + x]);
    float sum = 0.f;
    for (int x = 0; x < NW; x++) {
      float e = expf(sc[t * AP + x] - mx);
      sc[t * AP + x] = e;
      sum += e;
    }
    float inv = cinv[t] / sum;
    for (int x = 0; x < NW; x++) sc[t * AP + x] *= inv;
  }
  __syncthreads();
#pragma unroll
  for (int j = 0; j < 4; j++) {
    int p = t + j * 256;
    int w = p >> 4, d4 = p & 15;
    size_t src = (size_t)(b * NS + idxs[w]) * NE + h * ND + 4 * d4;
    *(float4*)&ks[w * AP + 4 * d4] = *(const float4*)(v + src);
  }
  __syncthreads();
#pragma unroll
  for (int j = 0; j < 4; j++) {
    int p = t + j * 256;
    int w = p >> 4, d4 = p & 15;
    float4 o4 = make_float4(0.f, 0.f, 0.f, 0.f);
    for (int x = 0; x < NW; x++) {
      float s = sc[w * AP + x];
      float4 kv = *(const float4*)&ks[x * AP + 4 * d4];
      o4.x += s * kv.x;
      o4.y += s * kv.y;
      o4.z += s * kv.z;
      o4.w += s * kv.w;
    }
    *(float4*)&qs[w * AP + 4 * d4] = o4;
  }
  __syncthreads();
  for (int p = t; p < NW * ND; p += 256) {
    int w = p >> 6, d = p & (ND - 1);
    atomicAdd(&obuf[(size_t)(b * NS + idxs[w]) * NE + h * ND + d], qs[w * AP + d]);
  }
}

// ---------------- head ----------------
__global__ __launch_bounds__(256) void head_kernel(
    const float* __restrict__ x, const void* __restrict__ hw, void* __restrict__ out, int f32) {
  int gw = (blockIdx.x * 256 + threadIdx.x) >> 6;
  int lane = threadIdx.x & 63;
  if (gw >= NTOK * NVOC) return;
  int row = gw / NVOC, vv = gw % NVOC;
  const float* xr = x + (size_t)row * NE;
  float acc = 0.f;
  for (int e = lane; e < NE; e += 64) acc += xr[e] * ldw(hw, (size_t)vv * NE + e, f32);
#pragma unroll
  for (int o = 32; o; o >>= 1) acc += __shfl_down(acc, o);
  if (lane == 0) {
    if (f32) ((float*)out)[(size_t)row * NVOC + vv] = acc;
    else ((bf16*)out)[(size_t)row * NVOC + vv] = __float2bfloat16(acc);
  }
}

extern "C" void kernel_launch(void* const* d_in, const int* in_sizes, int n_in,
                              void* d_out, int out_size, void* d_ws, size_t ws_size,
                              hipStream_t stream) {
  const int* value = (const int*)d_in[0];
  const int* depth = (const int*)d_in[1];
  const int* pos = (const int*)d_in[2];
  const void* sos = d_in[3];
  const void* tok_emb = d_in[4];
  const void* depth_emb = d_in[5];
  const void* pos_emb = d_in[6];
  const void* ln1_s = d_in[7];
  const void* ln1_b = d_in[8];
  const void* Wq = d_in[9];
  const void* Wk = d_in[10];
  const void* Wv = d_in[11];
  const void* Wo = d_in[12];
  const void* means = d_in[13];
  const void* ln2_s = d_in[14];
  const void* ln2_b = d_in[15];
  const void* W1 = d_in[16];
  const void* b1 = d_in[17];
  const void* W2 = d_in[18];
  const void* b2 = d_in[19];
  const void* head_w = d_in[20];
  (void)n_in;

  int f32 = (in_sizes[4] != 17408) ? 1 : 0;

  const size_t NX = (size_t)NTOK * NE;
  const size_t NEED = 170917896ULL;
  if (ws_size < NEED) {
    float val = (float)(unsigned)(ws_size >> 20) * 1000.0f;
    fill_out_kernel<<<(out_size + 255) / 256, 256, 0, stream>>>((float*)d_out, out_size, val);
    return;
  }

  float* xbuf = (float*)d_ws;
  float* hbuf = xbuf + NX;       // LN1 out / qT / attn accumulator (time-shared)
  float* qbuf = hbuf + NX;
  float* kbuf = qbuf + NX;
  float* vbuf = kbuf + NX;
  double* mndbuf = (double*)(vbuf + NX);
  double* rqdbuf = mndbuf + (size_t)NL * NH * NC * ND;
  float* cntbuf = (float*)(rqdbuf + (size_t)NTOK * NH);
  int* idxbuf = (int*)(cntbuf + (size_t)NTOK * NH);
  float* mid = kbuf;             // FFN mid: spans kbuf+vbuf (64 MiB) for 8192-token chunks

  mnd_kernel<<<NL * NH * NC, 64, 0, stream>>>(means, mndbuf, f32);
  embed_kernel<<<(int)((NX + 255) / 256), 256, 0, stream>>>(
      value, depth, pos, sos, tok_emb, depth_emb, pos_emb, xbuf, f32);

  dim3 g512(NE / 128, NTOK / 128);
  dim3 gkv(8, NTOK / 128);
  const int CH = 8192;
  dim3 gW1(NF / 128, CH / 128);              // (16, 64)
  dim3 gW2(NE / 128, CH / 128, 4);           // (4, 64, 4) split-K: 1024 blocks

  if (f32) {
    const float* Wqf = (const float*)Wq;
    const float* Wkf = (const float*)Wk;
    const float* Wvf = (const float*)Wv;
    const float* Wof = (const float*)Wo;
    const float* W1f = (const float*)W1;
    const float* W2f = (const float*)W2;
    const float* b1f = (const float*)b1;
    const float* b2f = (const float*)b2;
    for (int l = 0; l < NL; l++) {
      size_t o_w = (size_t)l * NE * NE;
      size_t o_w1 = (size_t)l * NE * NF;
      size_t o_w2 = (size_t)l * NF * NE;
      size_t o_e = (size_t)l * NE;
      size_t o_f = (size_t)l * NF;

      ln_kernel<<<NTOK / 4, 256, 0, stream>>>(xbuf, ln1_s, ln1_b, o_e, hbuf, 1);
      // q: 6-product (routing-critical, 2^-24); k,v: 3-product (no discrete risk)
      gemm_mfma_kernel<0, 1><<<g512, 256, 0, stream>>>(hbuf, Wqf + o_w, NE, nullptr, nullptr,
                                                       qbuf, NE, NE);
      gemm_kv_mfma<<<gkv, 256, 0, stream>>>(hbuf, Wkf, Wvf, o_w, kbuf, vbuf);

      qt_kernel<<<NB * NH * 64, 256, 0, stream>>>(qbuf, hbuf, rqdbuf);
      zero_kernel<<<(NTOK * NH) / 256, 256, 0, stream>>>(cntbuf, NTOK * NH);
      route_kernel<<<NB * NH * NC, 256, 0, stream>>>(
          hbuf, mndbuf + (size_t)l * NH * NC * ND, rqdbuf, idxbuf, cntbuf);

      zero_kernel<<<(int)((NX + 255) / 256), 256, 0, stream>>>(hbuf, (int)NX);
      attn_kernel<<<NB * NH * NC, 256, 0, stream>>>(qbuf, kbuf, vbuf, idxbuf, value, cntbuf, hbuf);
      gemm_mfma_kernel<0, 0><<<g512, 256, 0, stream>>>(hbuf, Wof + o_w, NE, nullptr, xbuf,
                                                       xbuf, NE, NE);

      ln_kernel<<<NTOK / 4, 256, 0, stream>>>(xbuf, ln2_s, ln2_b, o_e, qbuf, 1);
      // FFN: 2 token-chunks of 8192; W1 normal; W2 split-K=4 atomicAdd into xbuf
      for (int mc = 0; mc < NTOK / CH; mc++) {
        const float* hch = qbuf + (size_t)mc * CH * NE;
        float* xch = xbuf + (size_t)mc * CH * NE;
        gemm_mfma_kernel<1, 0><<<gW1, 256, 0, stream>>>(hch, W1f + o_w1, NF, b1f + o_f,
                                                        nullptr, mid, NF, NE);
        gemm_mfma_splitk_kernel<<<gW2, 256, 0, stream>>>(mid, NF, W2f + o_w2, NE,
                                                         b2f + o_e, xch, NE, 512);
      }
    }
  } else {
    dim3 gqkvv(12, NTOK / 128);
    dim3 gW2v(NE / 128, CH / 128);
    for (int l = 0; l < NL; l++) {
      size_t o_w = (size_t)l * NE * NE;
      size_t o_w1 = (size_t)l * NE * NF;
      size_t o_w2 = (size_t)l * NF * NE;
      size_t o_e = (size_t)l * NE;
      size_t o_f = (size_t)l * NF;

      ln_kernel<<<NTOK / 4, 256, 0, stream>>>(xbuf, ln1_s, ln1_b, o_e, hbuf, 0);
      gemm_qkv_kernel<<<gqkvv, 256, 0, stream>>>(hbuf, Wq, Wk, Wv, o_w, qbuf, kbuf, vbuf, 0);

      qt_kernel<<<NB * NH * 64, 256, 0, stream>>>(qbuf, hbuf, rqdbuf);
      zero_kernel<<<(NTOK * NH) / 256, 256, 0, stream>>>(cntbuf, NTOK * NH);
      route_kernel<<<NB * NH * NC, 256, 0, stream>>>(
          hbuf, mndbuf + (size_t)l * NH * NC * ND, rqdbuf, idxbuf, cntbuf);

      zero_kernel<<<(int)((NX + 255) / 256), 256, 0, stream>>>(hbuf, (int)NX);
      attn_kernel<<<NB * NH * NC, 256, 0, stream>>>(qbuf, kbuf, vbuf, idxbuf, value, cntbuf, hbuf);
      gemm_kernel<0><<<g512, 256, 0, stream>>>(hbuf, Wo, o_w, NE, nullptr, 0, xbuf,
                                               xbuf, NE, NE, 0);

      ln_kernel<<<NTOK / 4, 256, 0, stream>>>(xbuf, ln2_s, ln2_b, o_e, qbuf, 0);
      for (int ch = 0; ch < NTOK / CH; ch++) {
        const float* hch = qbuf + (size_t)ch * CH * NE;
        float* xch = xbuf + (size_t)ch * CH * NE;
        gemm_kernel<1><<<gW1, 256, 0, stream>>>(hch, W1, o_w1, NF, b1, o_f, nullptr,
                                                mid, NF, NE, 0);
        gemm_kernel<0><<<gW2v, 256, 0, stream>>>(mid, W2, o_w2, NE, b2, o_e, xch,
                                                 xch, NE, NF, 0);
      }
    }
  }

  head_kernel<<<(NTOK * NVOC * 64 + 255) / 256, 256, 0, stream>>>(xbuf, head_w, d_out, f32);
}

// Round 14
// 3651.118 us; speedup vs baseline: 1.6404x; 1.0021x over previous
//
#include <hip/hip_runtime.h>
#include <hip/hip_bf16.h>
#include <math.h>

typedef __hip_bfloat16 bf16;
typedef __attribute__((ext_vector_type(2))) float f2v;
typedef __attribute__((ext_vector_type(8))) short bf16x8;
typedef __attribute__((ext_vector_type(4))) float f32x4;

#define NB 4
#define NS 4096
#define NE 512
#define NH 8
#define NL 4
#define NA 3
#define ND 64
#define NC 64
#define NW 64
#define NF 2048
#define NVOC 17
#define NTOK (NB * NS)   // 16384
#define AP 68            // attn LDS row stride (floats)

__device__ __forceinline__ float b2f(bf16 v) { return __bfloat162float(v); }
__device__ __forceinline__ float u2f(unsigned short u) { return __uint_as_float((unsigned)u << 16); }
__device__ __forceinline__ float ldw(const void* p, size_t i, int f32) {
  return f32 ? ((const float*)p)[i] : b2f(((const bf16*)p)[i]);
}
__device__ __forceinline__ unsigned short f2bf(float f) {   // RNE fp32->bf16
  unsigned u = __float_as_uint(f);
  return (unsigned short)((u + 0x7FFFu + ((u >> 16) & 1u)) >> 16);
}

// ---------------- diagnostic fill (ws_size too small) ----------------
__global__ __launch_bounds__(256) void fill_out_kernel(float* __restrict__ out, int n, float val) {
  int i = blockIdx.x * 256 + threadIdx.x;
  if (i < n) out[i] = val;
}

// ---------------- zero fill ----------------
__global__ __launch_bounds__(256) void zero_kernel(float* __restrict__ p, int n) {
  int i = blockIdx.x * 256 + threadIdx.x;
  if (i < n) p[i] = 0.f;
}

// ---------------- embeddings + shift-right ----------------
__global__ __launch_bounds__(256) void embed_kernel(
    const int* __restrict__ value, const int* __restrict__ depth, const int* __restrict__ pos,
    const void* __restrict__ sos, const void* __restrict__ tok_emb,
    const void* __restrict__ depth_emb, const void* __restrict__ pos_emb,
    float* __restrict__ x, int f32) {
  int i = blockIdx.x * 256 + threadIdx.x;
  if (i >= NTOK * NE) return;
  int e = i & (NE - 1);
  int bs = i >> 9;
  int s = bs & (NS - 1);
  int b = bs >> 12;
  float v;
  if (s == 0) {
    v = ldw(sos, e, f32);
  } else {
    int src = b * NS + (s - 1);
    float acc = ldw(tok_emb, (size_t)value[src] * NE + e, f32)
              + ldw(depth_emb, (size_t)depth[src] * NE + e, f32);
#pragma unroll
    for (int a = 0; a < NA; a++)
      acc += ldw(pos_emb, ((size_t)a * 65 + pos[src * NA + a]) * NE + e, f32);
    v = acc;
  }
  x[i] = v;
}

// ---------------- layer norm, one wave per row ----------------
__global__ __launch_bounds__(256) void ln_kernel(
    const float* __restrict__ x, const void* __restrict__ gam, const void* __restrict__ bet,
    size_t off, float* __restrict__ out, int f32) {
  int row = blockIdx.x * 4 + (threadIdx.x >> 6);
  int lane = threadIdx.x & 63;
  const float* xr = x + (size_t)row * NE;
  float v[8];
#pragma unroll
  for (int i = 0; i < 8; i++) v[i] = xr[lane + i * 64];
  float s = 0.f;
#pragma unroll
  for (int i = 0; i < 8; i++) s += v[i];
#pragma unroll
  for (int o = 32; o; o >>= 1) s += __shfl_xor(s, o);
  float m = s * (1.0f / NE);
  float sq = 0.f;
#pragma unroll
  for (int i = 0; i < 8; i++) { float d = v[i] - m; sq += d * d; }
#pragma unroll
  for (int o = 32; o; o >>= 1) sq += __shfl_xor(sq, o);
  float rs = 1.0f / sqrtf(sq * (1.0f / NE) + 1e-5f);
  float* orow = out + (size_t)row * NE;
#pragma unroll
  for (int i = 0; i < 8; i++) {
    int e = lane + i * 64;
    orow[e] = (v[i] - m) * rs * ldw(gam, off + e, f32) + ldw(bet, off + e, f32);
  }
}

// ---------------- fp32 vector GEMM core (bf16-input fallback path) ----------------
template <int ACT>
__device__ __forceinline__ void gemm_body(
    const float* __restrict__ A, const void* __restrict__ Bw, size_t bwoff, int ldb,
    const void* bias, size_t biasoff, const float* resid, float* C,
    int N, int K, int f32, int bm, int bn) {
  __shared__ float As[32][132];
  __shared__ float Bs[32][132];
  int tid = threadIdx.x;
  int ty = tid >> 4, tx = tid & 15;
  f2v acc2[8][4];
#pragma unroll
  for (int i = 0; i < 8; i++)
#pragma unroll
    for (int j = 0; j < 4; j++) acc2[i][j] = (f2v){0.f, 0.f};
  int arow = tid >> 1;
  int acol = (tid & 1) << 4;
  int brow = tid >> 3;
  int bcol = (tid & 7) << 4;

  const float* Aptr = A + (size_t)(bm + arow) * K + acol;
  float4 pa[4];
  float4 pb[4];
  uint4 pbu[2];
#pragma unroll
  for (int j = 0; j < 4; j++) pa[j] = *(const float4*)(Aptr + 4 * j);
  {
    size_t boff = bwoff + (size_t)brow * ldb + bn + bcol;
    if (f32) {
#pragma unroll
      for (int j = 0; j < 4; j++) pb[j] = *(const float4*)((const float*)Bw + boff + 4 * j);
    } else {
      pbu[0] = *(const uint4*)((const bf16*)Bw + boff);
      pbu[1] = *(const uint4*)((const bf16*)Bw + boff + 8);
    }
  }

  for (int k0 = 0; k0 < K; k0 += 32) {
#pragma unroll
    for (int j = 0; j < 4; j++) {
      As[acol + 4 * j + 0][arow] = pa[j].x;
      As[acol + 4 * j + 1][arow] = pa[j].y;
      As[acol + 4 * j + 2][arow] = pa[j].z;
      As[acol + 4 * j + 3][arow] = pa[j].w;
    }
    if (f32) {
#pragma unroll
      for (int j = 0; j < 4; j++) {
        Bs[brow][bcol + 4 * j + 0] = pb[j].x;
        Bs[brow][bcol + 4 * j + 1] = pb[j].y;
        Bs[brow][bcol + 4 * j + 2] = pb[j].z;
        Bs[brow][bcol + 4 * j + 3] = pb[j].w;
      }
    } else {
      union { uint4 u; unsigned short s[8]; } r0, r1;
      r0.u = pbu[0]; r1.u = pbu[1];
#pragma unroll
      for (int j = 0; j < 8; j++) Bs[brow][bcol + j] = u2f(r0.s[j]);
#pragma unroll
      for (int j = 0; j < 8; j++) Bs[brow][bcol + 8 + j] = u2f(r1.s[j]);
    }
    __syncthreads();
    if (k0 + 32 < K) {
#pragma unroll
      for (int j = 0; j < 4; j++) pa[j] = *(const float4*)(Aptr + k0 + 32 + 4 * j);
      size_t boff = bwoff + (size_t)(k0 + 32 + brow) * ldb + bn + bcol;
      if (f32) {
#pragma unroll
        for (int j = 0; j < 4; j++) pb[j] = *(const float4*)((const float*)Bw + boff + 4 * j);
      } else {
        pbu[0] = *(const uint4*)((const bf16*)Bw + boff);
        pbu[1] = *(const uint4*)((const bf16*)Bw + boff + 8);
      }
    }
#pragma unroll
    for (int kk = 0; kk < 32; kk++) {
      float4 aA = *(const float4*)&As[kk][ty << 3];
      float4 aB = *(const float4*)&As[kk][(ty << 3) + 4];
      float4 bA = *(const float4*)&Bs[kk][tx << 2];
      float4 bB = *(const float4*)&Bs[kk][64 + (tx << 2)];
      float av[8] = {aA.x, aA.y, aA.z, aA.w, aB.x, aB.y, aB.z, aB.w};
      f2v bv[4];
      bv[0] = (f2v){bA.x, bA.y};
      bv[1] = (f2v){bA.z, bA.w};
      bv[2] = (f2v){bB.x, bB.y};
      bv[3] = (f2v){bB.z, bB.w};
#pragma unroll
      for (int i = 0; i < 8; i++)
#pragma unroll
        for (int j = 0; j < 4; j++)
          acc2[i][j] += bv[j] * av[i];
    }
    __syncthreads();
  }
#pragma unroll
  for (int i = 0; i < 8; i++) {
    int row = bm + (ty << 3) + i;
    int c0 = bn + (tx << 2);
    int c1 = bn + 64 + (tx << 2);
    const float* ap = (const float*)&acc2[i][0];
    float o0[4], o1[4];
#pragma unroll
    for (int j = 0; j < 4; j++) { o0[j] = ap[j]; o1[j] = ap[4 + j]; }
    if (bias) {
#pragma unroll
      for (int j = 0; j < 4; j++) {
        o0[j] += ldw(bias, biasoff + c0 + j, f32);
        o1[j] += ldw(bias, biasoff + c1 + j, f32);
      }
    }
    if (ACT == 1) {
#pragma unroll
      for (int j = 0; j < 4; j++) {
        float t0 = 0.7978845608028654f * (o0[j] + 0.044715f * o0[j] * o0[j] * o0[j]);
        o0[j] = 0.5f * o0[j] * (1.0f + tanhf(t0));
        float t1 = 0.7978845608028654f * (o1[j] + 0.044715f * o1[j] * o1[j] * o1[j]);
        o1[j] = 0.5f * o1[j] * (1.0f + tanhf(t1));
      }
    }
    size_t p0 = (size_t)row * N + c0;
    size_t p1 = (size_t)row * N + c1;
    if (resid) {
      float4 r0 = *(const float4*)(resid + p0);
      float4 r1 = *(const float4*)(resid + p1);
      o0[0] += r0.x; o0[1] += r0.y; o0[2] += r0.z; o0[3] += r0.w;
      o1[0] += r1.x; o1[1] += r1.y; o1[2] += r1.z; o1[3] += r1.w;
    }
    *(float4*)(C + p0) = make_float4(o0[0], o0[1], o0[2], o0[3]);
    *(float4*)(C + p1) = make_float4(o1[0], o1[1], o1[2], o1[3]);
  }
}

template <int ACT>
__global__ __launch_bounds__(256) void gemm_kernel(
    const float* __restrict__ A, const void* __restrict__ Bw, size_t bwoff, int ldb,
    const void* bias, size_t biasoff, const float* resid, float* C,
    int N, int K, int f32) {
  gemm_body<ACT>(A, Bw, bwoff, ldb, bias, biasoff, resid, C, N, K,
                 f32, blockIdx.y << 7, blockIdx.x << 7);
}

__global__ __launch_bounds__(256) void gemm_qkv_kernel(
    const float* __restrict__ A,
    const void* __restrict__ Wq, const void* __restrict__ Wk, const void* __restrict__ Wv,
    size_t bwoff, float* __restrict__ Cq, float* __restrict__ Ck, float* __restrict__ Cv,
    int f32) {
  int sel = blockIdx.x >> 2;
  const void* Bw = (sel == 0) ? Wq : ((sel == 1) ? Wk : Wv);
  float* C = (sel == 0) ? Cq : ((sel == 1) ? Ck : Cv);
  gemm_body<0>(A, Bw, bwoff, NE, nullptr, 0, nullptr, C, NE, NE,
               f32, blockIdx.y << 7, (blockIdx.x & 3) << 7);
}

// ---------------- MFMA GEMM for fp32 A x fp32 W ----------------
// FULL=1: 3-way splits, 6 products ~2^-24. q only. FULL=0: 2-way, 3 products ~2^-18.
// ATOMIC=1: partial-K contribution atomicAdd'ed into C.
// Layout = round-7 measured best: [128][40] planes; B staged Bx[n][k'] with chunk
// swizzle k' = k ^ (((n>>4)&3)<<3); frag read at chunk (lg^ni)&3 recovers k-chunk lg.
template <int ACT, int FULL, int ATOMIC>
__device__ __forceinline__ void mfma_body(
    const float* __restrict__ A, int ldak, const float* __restrict__ Bw, int ldb,
    const float* __restrict__ bias, const float* __restrict__ resid, float* __restrict__ C,
    int N, int klen, int bm, int bn) {
  __shared__ unsigned short Ah[128][40];
  __shared__ unsigned short Am[128][40];
  __shared__ unsigned short Al[FULL ? 128 : 1][40];
  __shared__ unsigned short Bh[128][40];
  __shared__ unsigned short Bm[128][40];
  __shared__ unsigned short Bl[FULL ? 128 : 1][40];
  int t = threadIdx.x;
  int arow = t >> 1;
  int akc = (t & 1) << 4;
  const float* Ap = A + (size_t)(bm + arow) * ldak + akc;
  int bkr = t >> 3;
  int bcg = t & 7;
  const float* Bp = Bw + (size_t)bkr * ldb + bn + bcg * 16;
  int bkpos = bkr ^ ((bcg & 3) << 3);

  float4 pa[4], pb[4];
#pragma unroll
  for (int j = 0; j < 4; j++) pa[j] = *(const float4*)(Ap + 4 * j);
#pragma unroll
  for (int j = 0; j < 4; j++) pb[j] = *(const float4*)(Bp + 4 * j);

  int lane = t & 63;
  int wid = t >> 6;
  int wr = wid >> 1, wc = wid & 1;
  int lr = lane & 15, lg = lane >> 4;

  f32x4 acc[4][4];
#pragma unroll
  for (int i = 0; i < 4; i++)
#pragma unroll
    for (int j = 0; j < 4; j++) acc[i][j] = (f32x4){0.f, 0.f, 0.f, 0.f};

  for (int k0 = 0; k0 < klen; k0 += 32) {
    {
      unsigned hs[8], ms[8], ls[8];
#pragma unroll
      for (int j = 0; j < 4; j++) {
        const float* pf = (const float*)&pa[j];
#pragma unroll
        for (int e = 0; e < 2; e++) {
          float a0 = pf[2 * e], a1 = pf[2 * e + 1];
          unsigned short h0 = f2bf(a0), h1 = f2bf(a1);
          float r0 = a0 - u2f(h0), r1 = a1 - u2f(h1);
          unsigned short m0 = f2bf(r0), m1 = f2bf(r1);
          hs[2 * j + e] = (unsigned)h0 | ((unsigned)h1 << 16);
          ms[2 * j + e] = (unsigned)m0 | ((unsigned)m1 << 16);
          if (FULL) {
            float s0 = r0 - u2f(m0), s1 = r1 - u2f(m1);
            unsigned short l0 = f2bf(s0), l1 = f2bf(s1);
            ls[2 * j + e] = (unsigned)l0 | ((unsigned)l1 << 16);
          }
        }
      }
      *(uint4*)&Ah[arow][akc]     = make_uint4(hs[0], hs[1], hs[2], hs[3]);
      *(uint4*)&Ah[arow][akc + 8] = make_uint4(hs[4], hs[5], hs[6], hs[7]);
      *(uint4*)&Am[arow][akc]     = make_uint4(ms[0], ms[1], ms[2], ms[3]);
      *(uint4*)&Am[arow][akc + 8] = make_uint4(ms[4], ms[5], ms[6], ms[7]);
      if (FULL) {
        *(uint4*)&Al[arow][akc]     = make_uint4(ls[0], ls[1], ls[2], ls[3]);
        *(uint4*)&Al[arow][akc + 8] = make_uint4(ls[4], ls[5], ls[6], ls[7]);
      }
    }
    {
#pragma unroll
      for (int j = 0; j < 4; j++) {
        const float* pf = (const float*)&pb[j];
#pragma unroll
        for (int e = 0; e < 4; e++) {
          float a = pf[e];
          unsigned short h = f2bf(a);
          float r = a - u2f(h);
          unsigned short m = f2bf(r);
          int nn = bcg * 16 + 4 * j + e;
          Bh[nn][bkpos] = h;
          Bm[nn][bkpos] = m;
          if (FULL) {
            float s = r - u2f(m);
            Bl[nn][bkpos] = f2bf(s);
          }
        }
      }
    }
    __syncthreads();
    if (k0 + 32 < klen) {
#pragma unroll
      for (int j = 0; j < 4; j++) pa[j] = *(const float4*)(Ap + k0 + 32 + 4 * j);
      const float* Bn = Bp + (size_t)(k0 + 32) * ldb;
#pragma unroll
      for (int j = 0; j < 4; j++) pb[j] = *(const float4*)(Bn + 4 * j);
    }
    bf16x8 fbh[4], fbm[4], fbl[4];
#pragma unroll
    for (int ni = 0; ni < 4; ni++) {
      int rb = wc * 64 + ni * 16 + lr;
      int cb = ((lg ^ ni) & 3) * 8;
      fbh[ni] = *(const bf16x8*)&Bh[rb][cb];
      fbm[ni] = *(const bf16x8*)&Bm[rb][cb];
      if (FULL) fbl[ni] = *(const bf16x8*)&Bl[rb][cb];
    }
#pragma unroll
    for (int mi = 0; mi < 4; mi++) {
      int ar = wr * 64 + mi * 16 + lr;
      bf16x8 fh = *(const bf16x8*)&Ah[ar][lg * 8];
      bf16x8 fm = *(const bf16x8*)&Am[ar][lg * 8];
      bf16x8 fl;
      if (FULL) fl = *(const bf16x8*)&Al[ar][lg * 8];
#pragma unroll
      for (int ni = 0; ni < 4; ni++) {
        f32x4 a = acc[mi][ni];
        a = __builtin_amdgcn_mfma_f32_16x16x32_bf16(fh, fbh[ni], a, 0, 0, 0);
        a = __builtin_amdgcn_mfma_f32_16x16x32_bf16(fh, fbm[ni], a, 0, 0, 0);
        a = __builtin_amdgcn_mfma_f32_16x16x32_bf16(fm, fbh[ni], a, 0, 0, 0);
        if (FULL) {
          a = __builtin_amdgcn_mfma_f32_16x16x32_bf16(fm, fbm[ni], a, 0, 0, 0);
          a = __builtin_amdgcn_mfma_f32_16x16x32_bf16(fh, fbl[ni], a, 0, 0, 0);
          a = __builtin_amdgcn_mfma_f32_16x16x32_bf16(fl, fbh[ni], a, 0, 0, 0);
        }
        acc[mi][ni] = a;
      }
    }
    __syncthreads();
  }
#pragma unroll
  for (int mi = 0; mi < 4; mi++) {
#pragma unroll
    for (int ni = 0; ni < 4; ni++) {
      int col = bn + wc * 64 + ni * 16 + lr;
      int rbase = bm + wr * 64 + mi * 16 + lg * 4;
      float bv = bias ? bias[col] : 0.f;
      const float* av = (const float*)&acc[mi][ni];
#pragma unroll
      for (int r = 0; r < 4; r++) {
        float o = av[r] + bv;
        size_t p = (size_t)(rbase + r) * N + col;
        if (ATOMIC) {
          atomicAdd(&C[p], o);
        } else {
          if (ACT == 1) {
            float t0 = 0.7978845608028654f * (o + 0.044715f * o * o * o);
            o = 0.5f * o * (1.0f + tanhf(t0));
          }
          if (resid) o += resid[p];
          C[p] = o;
        }
      }
    }
  }
}

template <int ACT, int FULL>
__global__ __launch_bounds__(256) void gemm_mfma_kernel(
    const float* __restrict__ A, const float* __restrict__ Bw, int ldb,
    const float* __restrict__ bias, const float* __restrict__ resid, float* __restrict__ C,
    int N, int K) {
  mfma_body<ACT, FULL, 0>(A, K, Bw, ldb, bias, resid, C, N, K,
                          blockIdx.y << 7, blockIdx.x << 7);
}

// split-K MFMA (3-product): blockIdx.z = K-slice; partials atomicAdd'ed into C
// (C pre-holds residual); bias added only by slice 0.
__global__ __launch_bounds__(256) void gemm_mfma_splitk_kernel(
    const float* __restrict__ A, int ldak, const float* __restrict__ Bw, int ldb,
    const float* __restrict__ bias, float* __restrict__ C, int N, int klen) {
  int kbase = blockIdx.z * klen;
  mfma_body<0, 0, 1>(A + kbase, ldak, Bw + (size_t)kbase * ldb, ldb,
                     (kbase == 0) ? bias : nullptr, nullptr, C, N, klen,
                     blockIdx.y << 7, blockIdx.x << 7);
}

// fused k/v MFMA (3-product): blockIdx.x in [0,8): sel = x>>2, col block x&3
__global__ __launch_bounds__(256) void gemm_kv_mfma(
    const float* __restrict__ A, const float* __restrict__ Wk, const float* __restrict__ Wv,
    size_t off, float* __restrict__ Ck, float* __restrict__ Cv) {
  int sel = blockIdx.x >> 2;
  const float* Bw = sel ? Wv : Wk;
  float* C = sel ? Cv : Ck;
  mfma_body<0, 0, 0>(A, NE, Bw + off, NE, nullptr, nullptr, C, NE, NE,
                     blockIdx.y << 7, (blockIdx.x & 3) << 7);
}

// ---------------- q transpose + fused rq: qT[b][h][d][n], rqd[b][h][n] ----------------
__global__ __launch_bounds__(256) void qt_kernel(const float* __restrict__ q, float* __restrict__ qT,
                                                 double* __restrict__ rqd) {
  __shared__ float tile[64][65];
  int bid = blockIdx.x;
  int st = bid & 63;
  int bh = bid >> 6;
  int b = bh >> 3, h = bh & 7;
  int s0 = st * 64;
  int t = threadIdx.x;
#pragma unroll
  for (int k = 0; k < 16; k++) {
    int idx = t + k * 256;
    int sl = idx >> 6, dl = idx & 63;
    tile[sl][dl] = q[(size_t)(b * NS + s0 + sl) * NE + h * ND + dl];
  }
  __syncthreads();
#pragma unroll
  for (int k = 0; k < 16; k++) {
    int idx = t + k * 256;
    int dl = idx >> 6, sl = idx & 63;
    qT[((size_t)bh * 64 + dl) * NS + s0 + sl] = tile[sl][dl];
  }
  int w = t >> 6, lane = t & 63;
#pragma unroll
  for (int i = 0; i < 16; i++) {
    int tok = w * 16 + i;
    double v = (double)tile[tok][lane];
    double ss = v * v;
#pragma unroll
    for (int o = 32; o; o >>= 1) ss += __shfl_xor(ss, o);
    if (lane == 0) rqd[((size_t)bh << 12) | (s0 + tok)] = 1.0 / (sqrt(ss) + 1e-8);
  }
}

// ---------------- normalized means in fp64 ----------------
__global__ __launch_bounds__(64) void mnd_kernel(const void* __restrict__ means,
                                                 double* __restrict__ mnd, int f32) {
  __shared__ double s[64];
  int vblk = blockIdx.x;
  int d = threadIdx.x;
  double m = (double)ldw(means, (size_t)vblk * ND + d, f32);
  s[d] = m * m;
  __syncthreads();
  for (int st = 32; st; st >>= 1) { if (d < st) s[d] += s[d + st]; __syncthreads(); }
  mnd[(size_t)vblk * ND + d] = m / (sqrt(s[0]) + 1e-8);
}

// ---------------- routing: fp64 dists (coalesced qT) + exact top-64 + fused cnt ----------------
// 512 threads: key values and selection identical to the 256-thread version
// (per-n fp64 accumulation order is d ascending, independent of stride).
__global__ __launch_bounds__(512) void route_kernel(
    const float* __restrict__ qT, const double* __restrict__ mnd,
    const double* __restrict__ rqd, int* __restrict__ idxout, float* __restrict__ cnt) {
  __shared__ unsigned long long keys[NS];
  __shared__ double mc[ND];
  __shared__ unsigned hist[256];
  __shared__ unsigned short cand[2][NS];
  __shared__ unsigned s_rem, s_cnt, s_sel, s_cc[2];
  int bid = blockIdx.x;
  int h = bid & 7;
  int b = (bid >> 3) & 3;
  int c = bid >> 5;
  int bhc = ((b * NH + h) * NC) + c;
  int t = threadIdx.x;
  if (t < ND) mc[t] = mnd[((size_t)h * NC + c) * ND + t];
  if (t < 256) hist[t] = 0u;
  if (t == 0) { s_rem = NW; s_cnt = 0u; s_cc[0] = 0u; s_cc[1] = 0u; }
  __syncthreads();
  const float* qTb = qT + (size_t)(b * NH + h) * 64 * NS;
  const double* rqb = rqd + ((size_t)(b * NH + h) << 12);
  for (int i = 0; i < 8; i += 4) {
    int n0 = t + i * 512, n1 = n0 + 512, n2 = n0 + 1024, n3 = n0 + 1536;
    double a0 = 0.0, a1 = 0.0, a2 = 0.0, a3 = 0.0;
#pragma unroll 8
    for (int d = 0; d < 64; d++) {
      const float* row = qTb + (size_t)d * NS;
      double m = mc[d];
      a0 += (double)row[n0] * m;
      a1 += (double)row[n1] * m;
      a2 += (double)row[n2] * m;
      a3 += (double)row[n3] * m;
    }
    double dv[4] = {a0 * rqb[n0], a1 * rqb[n1], a2 * rqb[n2], a3 * rqb[n3]};
    int nn[4] = {n0, n1, n2, n3};
#pragma unroll
    for (int j = 0; j < 4; j++) {
      long long sb = __double_as_longlong(dv[j]);
      unsigned long long u = (unsigned long long)sb;
      u = (sb < 0) ? ~u : (u | 0x8000000000000000ULL);
      keys[nn[j]] = (u & 0xFFFFFFFFFFFFF000ULL) | (unsigned long long)(NS - 1 - nn[j]);
    }
  }
  __syncthreads();
  {
    unsigned lastd = 0xFFFFFFFFu, lcnt = 0u;
    for (int n = t; n < NS; n += 512) {
      unsigned d = (unsigned)(keys[n] >> 56);
      if (d == lastd) { lcnt++; }
      else { if (lcnt) atomicAdd(&hist[lastd], lcnt); lastd = d; lcnt = 1u; }
    }
    if (lcnt) atomicAdd(&hist[lastd], lcnt);
  }
  __syncthreads();
  if (t < 64) {
    unsigned h0 = hist[4 * t + 0], h1 = hist[4 * t + 1];
    unsigned h2 = hist[4 * t + 2], h3 = hist[4 * t + 3];
    hist[4 * t + 0] = 0u; hist[4 * t + 1] = 0u; hist[4 * t + 2] = 0u; hist[4 * t + 3] = 0u;
    unsigned t3 = h3, t2 = h2 + h3, t1 = h1 + t2, t0 = h0 + t1;
    unsigned s = t0;
#pragma unroll
    for (int off = 1; off < 64; off <<= 1) {
      unsigned v = __shfl_down(s, off);
      if (t + off < 64) s += v;
    }
    unsigned E = s - t0;
    unsigned rem = s_rem;
    unsigned sf0 = t0 + E, sf1 = t1 + E, sf2 = t2 + E, sf3 = t3 + E, sf4 = E;
    if (sf0 >= rem && sf1 < rem) { s_sel = 4u * t + 0u; s_rem = rem - sf1; }
    if (sf1 >= rem && sf2 < rem) { s_sel = 4u * t + 1u; s_rem = rem - sf2; }
    if (sf2 >= rem && sf3 < rem) { s_sel = 4u * t + 2u; s_rem = rem - sf3; }
    if (sf3 >= rem && sf4 < rem) { s_sel = 4u * t + 3u; s_rem = rem - sf4; }
  }
  __syncthreads();
  {
    unsigned sel = s_sel;
    for (int n = t; n < NS; n += 512) {
      unsigned d = (unsigned)(keys[n] >> 56);
      if (d > sel) {
        unsigned p = atomicAdd(&s_cnt, 1u);
        idxout[(size_t)bhc * NW + p] = n;
        atomicAdd(&cnt[(size_t)(b * NS + n) * NH + h], 1.0f);
      } else if (d == sel) {
        unsigned p = atomicAdd(&s_cc[0], 1u);
        cand[0][p] = (unsigned short)n;
      }
    }
  }
  __syncthreads();
  int cur = 0;
  for (int p = 6; p >= 0; p--) {
    int sh = p * 8;
    unsigned nc = s_cc[cur];
    for (unsigned i = t; i < nc; i += 512) {
      unsigned d = (unsigned)((keys[cand[cur][i]] >> sh) & 255ULL);
      atomicAdd(&hist[d], 1u);
    }
    __syncthreads();
    if (t < 64) {
      unsigned h0 = hist[4 * t + 0], h1 = hist[4 * t + 1];
      unsigned h2 = hist[4 * t + 2], h3 = hist[4 * t + 3];
      hist[4 * t + 0] = 0u; hist[4 * t + 1] = 0u; hist[4 * t + 2] = 0u; hist[4 * t + 3] = 0u;
      unsigned t3 = h3, t2 = h2 + h3, t1 = h1 + t2, t0 = h0 + t1;
      unsigned s = t0;
#pragma unroll
      for (int off = 1; off < 64; off <<= 1) {
        unsigned v = __shfl_down(s, off);
        if (t + off < 64) s += v;
      }
      unsigned E = s - t0;
      unsigned rem = s_rem;
      unsigned sf0 = t0 + E, sf1 = t1 + E, sf2 = t2 + E, sf3 = t3 + E, sf4 = E;
      if (sf0 >= rem && sf1 < rem) { s_sel = 4u * t + 0u; s_rem = rem - sf1; }
      if (sf1 >= rem && sf2 < rem) { s_sel = 4u * t + 1u; s_rem = rem - sf2; }
      if (sf2 >= rem && sf3 < rem) { s_sel = 4u * t + 2u; s_rem = rem - sf3; }
      if (sf3 >= rem && sf4 < rem) { s_sel = 4u * t + 3u; s_rem = rem - sf4; }
      if (t == 0) s_cc[cur ^ 1] = 0u;
    }
    __syncthreads();
    unsigned sel = s_sel;
    if (p == 0) {
      for (unsigned i = t; i < nc; i += 512) {
        unsigned n = cand[cur][i];
        unsigned d = (unsigned)(keys[n] & 255ULL);
        if (d >= sel) {
          unsigned pp = atomicAdd(&s_cnt, 1u);
          idxout[(size_t)bhc * NW + pp] = n;
          atomicAdd(&cnt[(size_t)(b * NS + n) * NH + h], 1.0f);
        }
      }
    } else {
      int nxt = cur ^ 1;
      for (unsigned i = t; i < nc; i += 512) {
        unsigned n = cand[cur][i];
        unsigned d = (unsigned)((keys[n] >> sh) & 255ULL);
        if (d > sel) {
          unsigned pp = atomicAdd(&s_cnt, 1u);
          idxout[(size_t)bhc * NW + pp] = n;
          atomicAdd(&cnt[(size_t)(b * NS + n) * NH + h], 1.0f);
        } else if (d == sel) {
          unsigned pp = atomicAdd(&s_cc[nxt], 1u);
          cand[nxt][pp] = (unsigned short)n;
        }
      }
      __syncthreads();
      cur = nxt;
    }
  }
}

// ---------------- bucket attention (float4 LDS, stride AP=68) ----------------
__global__ __launch_bounds__(256) void attn_kernel(
    const float* __restrict__ q, const float* __restrict__ k, const float* __restrict__ v,
    const int* __restrict__ idxb, const int* __restrict__ value, const float* __restrict__ cnt,
    float* __restrict__ obuf) {
  __shared__ float qs[NW * AP];
  __shared__ float ks[NW * AP];
  __shared__ float sc[NW * AP];
  __shared__ int idxs[NW];
  __shared__ float kmv[NW];
  __shared__ float cinv[NW];
  int bhc = blockIdx.x;
  int h = (bhc >> 6) & (NH - 1);
  int b = bhc >> 9;
  int t = threadIdx.x;
  if (t < NW) {
    int n = idxb[(size_t)bhc * NW + t];
    idxs[t] = n;
    kmv[t] = (value[b * NS + n] != 0) ? 1.f : 0.f;
    cinv[t] = 1.0f / fmaxf(cnt[(size_t)(b * NS + n) * NH + h], 1.0f);
  }
  __syncthreads();
#pragma unroll
  for (int j = 0; j < 4; j++) {
    int p = t + j * 256;
    int w = p >> 4, d4 = p & 15;
    size_t src = (size_t)(b * NS + idxs[w]) * NE + h * ND + 4 * d4;
    *(float4*)&qs[w * AP + 4 * d4] = *(const float4*)(q + src);
    *(float4*)&ks[w * AP + 4 * d4] = *(const float4*)(k + src);
  }
  __syncthreads();
#pragma unroll
  for (int j = 0; j < 16; j++) {
    int p = t + j * 256;
    int w = p >> 6, x = p & (NW - 1);
    float dot = 0.f;
#pragma unroll
    for (int i = 0; i < 16; i++) {
      float4 a = *(const float4*)&qs[w * AP + 4 * i];
      float4 bb = *(const float4*)&ks[x * AP + 4 * i];
      dot += a.x * bb.x;
      dot += a.y * bb.y;
      dot += a.z * bb.z;
      dot += a.w * bb.w;
    }
    bool allowed = (idxs[w] >= idxs[x]) && (kmv[x] != 0.f);
    sc[w * AP + x] = allowed ? dot * 0.125f : -1e9f;
  }
  __syncthreads();
  if (t < NW) {
    float mx = -3.4e38f;
    for (int x = 0; x < NW; x++) mx = fmaxf(mx, sc[t * AP + x]);
    float sum = 0.f;
    for (int x = 0; x < NW; x++) {
      float e = expf(sc[t * AP + x] - mx);
      sc[t * AP + x] = e;
      sum += e;
    }
    float inv = cinv[t] / sum;
    for (int x = 0; x < NW; x++) sc[t * AP + x] *= inv;
  }
  __syncthreads();
#pragma unroll
  for (int j = 0; j < 4; j++) {
    int p = t + j * 256;
    int w = p >> 4, d4 = p & 15;
    size_t src = (size_t)(b * NS + idxs[w]) * NE + h * ND + 4 * d4;
    *(float4*)&ks[w * AP + 4 * d4] = *(const float4*)(v + src);
  }
  __syncthreads();
#pragma unroll
  for (int j = 0; j < 4; j++) {
    int p = t + j * 256;
    int w = p >> 4, d4 = p & 15;
    float4 o4 = make_float4(0.f, 0.f, 0.f, 0.f);
    for (int x = 0; x < NW; x++) {
      float s = sc[w * AP + x];
      float4 kv = *(const float4*)&ks[x * AP + 4 * d4];
      o4.x += s * kv.x;
      o4.y += s * kv.y;
      o4.z += s * kv.z;
      o4.w += s * kv.w;
    }
    *(float4*)&qs[w * AP + 4 * d4] = o4;
  }
  __syncthreads();
  for (int p = t; p < NW * ND; p += 256) {
    int w = p >> 6, d = p & (ND - 1);
    atomicAdd(&obuf[(size_t)(b * NS + idxs[w]) * NE + h * ND + d], qs[w * AP + d]);
  }
}

// ---------------- head ----------------
__global__ __launch_bounds__(256) void head_kernel(
    const float* __restrict__ x, const void* __restrict__ hw, void* __restrict__ out, int f32) {
  int gw = (blockIdx.x * 256 + threadIdx.x) >> 6;
  int lane = threadIdx.x & 63;
  if (gw >= NTOK * NVOC) return;
  int row = gw / NVOC, vv = gw % NVOC;
  const float* xr = x + (size_t)row * NE;
  float acc = 0.f;
  for (int e = lane; e < NE; e += 64) acc += xr[e] * ldw(hw, (size_t)vv * NE + e, f32);
#pragma unroll
  for (int o = 32; o; o >>= 1) acc += __shfl_down(acc, o);
  if (lane == 0) {
    if (f32) ((float*)out)[(size_t)row * NVOC + vv] = acc;
    else ((bf16*)out)[(size_t)row * NVOC + vv] = __float2bfloat16(acc);
  }
}

extern "C" void kernel_launch(void* const* d_in, const int* in_sizes, int n_in,
                              void* d_out, int out_size, void* d_ws, size_t ws_size,
                              hipStream_t stream) {
  const int* value = (const int*)d_in[0];
  const int* depth = (const int*)d_in[1];
  const int* pos = (const int*)d_in[2];
  const void* sos = d_in[3];
  const void* tok_emb = d_in[4];
  const void* depth_emb = d_in[5];
  const void* pos_emb = d_in[6];
  const void* ln1_s = d_in[7];
  const void* ln1_b = d_in[8];
  const void* Wq = d_in[9];
  const void* Wk = d_in[10];
  const void* Wv = d_in[11];
  const void* Wo = d_in[12];
  const void* means = d_in[13];
  const void* ln2_s = d_in[14];
  const void* ln2_b = d_in[15];
  const void* W1 = d_in[16];
  const void* b1 = d_in[17];
  const void* W2 = d_in[18];
  const void* b2 = d_in[19];
  const void* head_w = d_in[20];
  (void)n_in;

  int f32 = (in_sizes[4] != 17408) ? 1 : 0;

  const size_t NX = (size_t)NTOK * NE;
  const size_t NEED = 170917896ULL;
  if (ws_size < NEED) {
    float val = (float)(unsigned)(ws_size >> 20) * 1000.0f;
    fill_out_kernel<<<(out_size + 255) / 256, 256, 0, stream>>>((float*)d_out, out_size, val);
    return;
  }

  float* xbuf = (float*)d_ws;
  float* hbuf = xbuf + NX;       // LN1 out / qT / attn accumulator (time-shared)
  float* qbuf = hbuf + NX;
  float* kbuf = qbuf + NX;
  float* vbuf = kbuf + NX;
  double* mndbuf = (double*)(vbuf + NX);
  double* rqdbuf = mndbuf + (size_t)NL * NH * NC * ND;
  float* cntbuf = (float*)(rqdbuf + (size_t)NTOK * NH);
  int* idxbuf = (int*)(cntbuf + (size_t)NTOK * NH);
  float* mid = kbuf;             // FFN mid: spans kbuf+vbuf (64 MiB) for 8192-token chunks

  mnd_kernel<<<NL * NH * NC, 64, 0, stream>>>(means, mndbuf, f32);
  embed_kernel<<<(int)((NX + 255) / 256), 256, 0, stream>>>(
      value, depth, pos, sos, tok_emb, depth_emb, pos_emb, xbuf, f32);

  dim3 g512(NE / 128, NTOK / 128);
  dim3 gkv(8, NTOK / 128);
  const int CH = 8192;
  dim3 gW1(NF / 128, CH / 128);              // (16, 64)
  dim3 gW2(NE / 128, CH / 128, 4);           // (4, 64, 4) split-K: 1024 blocks

  if (f32) {
    const float* Wqf = (const float*)Wq;
    const float* Wkf = (const float*)Wk;
    const float* Wvf = (const float*)Wv;
    const float* Wof = (const float*)Wo;
    const float* W1f = (const float*)W1;
    const float* W2f = (const float*)W2;
    const float* b1f = (const float*)b1;
    const float* b2f = (const float*)b2;
    for (int l = 0; l < NL; l++) {
      size_t o_w = (size_t)l * NE * NE;
      size_t o_w1 = (size_t)l * NE * NF;
      size_t o_w2 = (size_t)l * NF * NE;
      size_t o_e = (size_t)l * NE;
      size_t o_f = (size_t)l * NF;

      ln_kernel<<<NTOK / 4, 256, 0, stream>>>(xbuf, ln1_s, ln1_b, o_e, hbuf, 1);
      // q: 6-product (routing-critical, 2^-24); k,v: 3-product (no discrete risk)
      gemm_mfma_kernel<0, 1><<<g512, 256, 0, stream>>>(hbuf, Wqf + o_w, NE, nullptr, nullptr,
                                                       qbuf, NE, NE);
      gemm_kv_mfma<<<gkv, 256, 0, stream>>>(hbuf, Wkf, Wvf, o_w, kbuf, vbuf);

      qt_kernel<<<NB * NH * 64, 256, 0, stream>>>(qbuf, hbuf, rqdbuf);
      zero_kernel<<<(NTOK * NH) / 256, 256, 0, stream>>>(cntbuf, NTOK * NH);
      route_kernel<<<NB * NH * NC, 512, 0, stream>>>(
          hbuf, mndbuf + (size_t)l * NH * NC * ND, rqdbuf, idxbuf, cntbuf);

      zero_kernel<<<(int)((NX + 255) / 256), 256, 0, stream>>>(hbuf, (int)NX);
      attn_kernel<<<NB * NH * NC, 256, 0, stream>>>(qbuf, kbuf, vbuf, idxbuf, value, cntbuf, hbuf);
      gemm_mfma_kernel<0, 0><<<g512, 256, 0, stream>>>(hbuf, Wof + o_w, NE, nullptr, xbuf,
                                                       xbuf, NE, NE);

      ln_kernel<<<NTOK / 4, 256, 0, stream>>>(xbuf, ln2_s, ln2_b, o_e, qbuf, 1);
      // FFN: 2 token-chunks of 8192; W1 normal; W2 split-K=4 atomicAdd into xbuf
      for (int mc = 0; mc < NTOK / CH; mc++) {
        const float* hch = qbuf + (size_t)mc * CH * NE;
        float* xch = xbuf + (size_t)mc * CH * NE;
        gemm_mfma_kernel<1, 0><<<gW1, 256, 0, stream>>>(hch, W1f + o_w1, NF, b1f + o_f,
                                                        nullptr, mid, NF, NE);
        gemm_mfma_splitk_kernel<<<gW2, 256, 0, stream>>>(mid, NF, W2f + o_w2, NE,
                                                         b2f + o_e, xch, NE, 512);
      }
    }
  } else {
    dim3 gqkvv(12, NTOK / 128);
    dim3 gW2v(NE / 128, CH / 128);
    for (int l = 0; l < NL; l++) {
      size_t o_w = (size_t)l * NE * NE;
      size_t o_w1 = (size_t)l * NE * NF;
      size_t o_w2 = (size_t)l * NF * NE;
      size_t o_e = (size_t)l * NE;
      size_t o_f = (size_t)l * NF;

      ln_kernel<<<NTOK / 4, 256, 0, stream>>>(xbuf, ln1_s, ln1_b, o_e, hbuf, 0);
      gemm_qkv_kernel<<<gqkvv, 256, 0, stream>>>(hbuf, Wq, Wk, Wv, o_w, qbuf, kbuf, vbuf, 0);

      qt_kernel<<<NB * NH * 64, 256, 0, stream>>>(qbuf, hbuf, rqdbuf);
      zero_kernel<<<(NTOK * NH) / 256, 256, 0, stream>>>(cntbuf, NTOK * NH);
      route_kernel<<<NB * NH * NC, 512, 0, stream>>>(
          hbuf, mndbuf + (size_t)l * NH * NC * ND, rqdbuf, idxbuf, cntbuf);

      zero_kernel<<<(int)((NX + 255) / 256), 256, 0, stream>>>(hbuf, (int)NX);
      attn_kernel<<<NB * NH * NC, 256, 0, stream>>>(qbuf, kbuf, vbuf, idxbuf, value, cntbuf, hbuf);
      gemm_kernel<0><<<g512, 256, 0, stream>>>(hbuf, Wo, o_w, NE, nullptr, 0, xbuf,
                                               xbuf, NE, NE, 0);

      ln_kernel<<<NTOK / 4, 256, 0, stream>>>(xbuf, ln2_s, ln2_b, o_e, qbuf, 0);
      for (int ch = 0; ch < NTOK / CH; ch++) {
        const float* hch = qbuf + (size_t)ch * CH * NE;
        float* xch = xbuf + (size_t)ch * CH * NE;
        gemm_kernel<1><<<gW1, 256, 0, stream>>>(hch, W1, o_w1, NF, b1, o_f, nullptr,
                                                mid, NF, NE, 0);
        gemm_kernel<0><<<gW2v, 256, 0, stream>>>(mid, W2, o_w2, NE, b2, o_e, xch,
                                                 xch, NE, NF, 0);
      }
    }
  }

  head_kernel<<<(NTOK * NVOC * 64 + 255) / 256, 256, 0, stream>>>(xbuf, head_w, d_out, f32);
}